// Round 1
// baseline (437.531 us; speedup 1.0000x reference)
//
#include <hip/hip_runtime.h>
#include <hip/hip_bf16.h>

// ---------------------------------------------------------------------------
// CleanDITBlock: adaLN-modulated DiT block (self-attn w/ RoPE, cross-attn, MLP)
// B=2, L=2048, S=512, D=1024, H=16, HD=64, CTX=1024, HID=4096
// ---------------------------------------------------------------------------

typedef short short8 __attribute__((ext_vector_type(8)));
typedef float f32x4 __attribute__((ext_vector_type(4)));
typedef float f32x16 __attribute__((ext_vector_type(16)));

#define DEV __device__ __forceinline__

DEV unsigned short f2b(float f) {
  __hip_bfloat16 h = __float2bfloat16(f);
  return *reinterpret_cast<unsigned short*>(&h);
}
DEV float b2f(unsigned short u) {
  unsigned int x = ((unsigned int)u) << 16;
  return __builtin_bit_cast(float, x);
}
DEV unsigned int pk2(float lo, float hi) {
  return (unsigned int)f2b(lo) | ((unsigned int)f2b(hi) << 16);
}
// lane[i]<->lane[i+32] half-swap (VALU, no LDS)
DEV void vpsw(unsigned int& a, unsigned int& b) {
  asm("v_permlane32_swap_b32 %0, %1" : "+v"(a), "+v"(b));
}

#define GLB(p) ((const __attribute__((address_space(1))) void*)(p))
#define LDSP(p) ((__attribute__((address_space(3))) void*)(p))

// ---------------------------------------------------------------------------
__global__ __launch_bounds__(256) void transpose_cast(
    const float* __restrict__ in, unsigned short* __restrict__ out, int R, int C) {
  __shared__ float tile[32][33];
  int bx = blockIdx.x * 32, by = blockIdx.y * 32;
  int tx = threadIdx.x, ty = threadIdx.y;  // 32 x 8
#pragma unroll
  for (int i = ty; i < 32; i += 8)
    tile[i][tx] = in[(size_t)(by + i) * C + bx + tx];
  __syncthreads();
#pragma unroll
  for (int i = ty; i < 32; i += 8)
    out[(size_t)(bx + i) * R + by + tx] = f2b(tile[tx][i]);
}

__global__ __launch_bounds__(256) void cast_bf16(
    const float* __restrict__ in, unsigned short* __restrict__ out, int n) {
  int i = blockIdx.x * 256 + threadIdx.x;
  if (i < n) out[i] = f2b(in[i]);
}

__global__ __launch_bounds__(256) void rope_tab(
    const float* __restrict__ rope, float* __restrict__ cosT, float* __restrict__ sinT, int n) {
  int i = blockIdx.x * 256 + threadIdx.x;
  if (i < n) {
    float v = rope[i];
    cosT[i] = cosf(v);
    sinT[i] = sinf(v);
  }
}

// ---------------------------------------------------------------------------
__global__ __launch_bounds__(256) void mods_kernel(
    const float* __restrict__ te, const unsigned short* __restrict__ wmodT,
    const float* __restrict__ bmod, float* __restrict__ mods) {
  int w = blockIdx.x * 4 + (threadIdx.x >> 6);
  int lane = threadIdx.x & 63;
  int b = w / 6144, j = w % 6144;
  const unsigned short* wr = wmodT + (size_t)j * 1024;
  const float* ter = te + (size_t)b * 1024;
  int k0 = lane * 16;
  float sum = 0.f;
#pragma unroll
  for (int u = 0; u < 2; ++u) {
    short8 wv = *(const short8*)(wr + k0 + u * 8);
#pragma unroll
    for (int e = 0; e < 8; ++e)
      sum += b2f((unsigned short)wv[e]) * ter[k0 + u * 8 + e];
  }
#pragma unroll
  for (int off = 32; off >= 1; off >>= 1) sum += __shfl_down(sum, off);
  if (lane == 0) mods[(size_t)b * 6144 + j] = sum + bmod[j];
}

// ---------------------------------------------------------------------------
__global__ __launch_bounds__(256) void ln_mod(
    const float* __restrict__ x, const float* __restrict__ mods,
    unsigned short* __restrict__ out, int scale_ofs, int shift_ofs) {
  int row = blockIdx.x;
  int b = row >> 11;
  int tid = threadIdx.x;
  const float* xr = x + (size_t)row * 1024;
  float4 v = ((const float4*)xr)[tid];
  float s = v.x + v.y + v.z + v.w;
  float ss = v.x * v.x + v.y * v.y + v.z * v.z + v.w * v.w;
#pragma unroll
  for (int off = 32; off >= 1; off >>= 1) {
    s += __shfl_down(s, off);
    ss += __shfl_down(ss, off);
  }
  __shared__ float red[8];
  int wave = tid >> 6, lane = tid & 63;
  if (lane == 0) { red[wave] = s; red[4 + wave] = ss; }
  __syncthreads();
  if (tid == 0) {
    float S = red[0] + red[1] + red[2] + red[3];
    float SS = red[4] + red[5] + red[6] + red[7];
    float mu = S * (1.f / 1024.f);
    red[0] = mu;
    red[1] = SS * (1.f / 1024.f) - mu * mu;
  }
  __syncthreads();
  float mu = red[0];
  float rs = rsqrtf(red[1] + 1e-6f);
  float vv[4] = {v.x, v.y, v.z, v.w};
  unsigned short o[4];
#pragma unroll
  for (int c = 0; c < 4; ++c) {
    int col = tid * 4 + c;
    float nv = (vv[c] - mu) * rs;
    if (scale_ofs >= 0)
      nv = nv * (1.f + mods[(size_t)b * 6144 + scale_ofs + col]) +
           mods[(size_t)b * 6144 + shift_ofs + col];
    o[c] = f2b(nv);
  }
  *(ushort4*)(&out[(size_t)row * 1024 + tid * 4]) = *(const ushort4*)o;
}

// ---------------------------------------------------------------------------
__global__ __launch_bounds__(256) void rope_apply(
    unsigned short* __restrict__ qb, unsigned short* __restrict__ kb,
    const float* __restrict__ cosT, const float* __restrict__ sinT) {
  int idx = blockIdx.x * 256 + threadIdx.x;  // over [4096][16][32]
  unsigned short* buf = blockIdx.y ? kb : qb;
  int row = idx >> 9;
  int rem = idx & 511;
  int h = rem >> 5, d = rem & 31;
  int l = row & 2047;
  size_t base = (size_t)row * 1024 + h * 64 + d;
  float x1 = b2f(buf[base]), x2 = b2f(buf[base + 32]);
  float c1 = cosT[l * 64 + d], s1 = sinT[l * 64 + d];
  float c2 = cosT[l * 64 + d + 32], s2 = sinT[l * 64 + d + 32];
  buf[base] = f2b(x1 * c1 - x2 * s1);
  buf[base + 32] = f2b(x2 * c2 + x1 * s2);
}

// ---------------------------------------------------------------------------
// Shared GEMM epilogue.  EPI: 0 bf16; 1 bias+GELU bf16; 2 f32 residual
// src + gate*(acc+bias); 3 bf16 split-store (buffer = col>>10, row stride 1024,
// buffer stride 4096*1024).
// ---------------------------------------------------------------------------
template <int EPI, int MI, int NJ>
DEV void gemm_epilogue(f32x4 (&acc)[MI][NJ], void* Cout, const float* bias,
                       const float* mods, int gate_ofs, const float* src,
                       int N, int rowsPerB, int m0, int n0, int wm, int wn,
                       int g, int r) {
#pragma unroll
  for (int i = 0; i < MI; ++i) {
#pragma unroll
    for (int j = 0; j < NJ; ++j) {
#pragma unroll
      for (int q = 0; q < 4; ++q) {
        size_t grow = (size_t)(m0 + wm + i * 16 + g * 4 + q);
        size_t gcol = (size_t)(n0 + wn + j * 16 + r);
        float v = acc[i][j][q];
        if constexpr (EPI == 0) {
          ((unsigned short*)Cout)[grow * N + gcol] = f2b(v);
        } else if constexpr (EPI == 1) {
          v += bias[gcol];
          float ge = 0.5f * v * (1.0f + erff(v * 0.70710678f));
          ((unsigned short*)Cout)[grow * N + gcol] = f2b(ge);
        } else if constexpr (EPI == 3) {
          size_t buf = gcol >> 10;
          ((unsigned short*)Cout)[buf * (4096ull * 1024) + grow * 1024 + (gcol & 1023)] = f2b(v);
        } else {
          v += bias[gcol];
          float gate = 1.0f;
          if (gate_ofs >= 0)
            gate = mods[(grow / rowsPerB) * 6144 + gate_ofs + gcol];
          ((float*)Cout)[grow * N + gcol] = src[grow * N + gcol] + gate * v;
        }
      }
    }
  }
}

// ---------------------------------------------------------------------------
// GEMM (m97): 128x128, BK=32, implicit overlap.  For >=4 blocks/CU (mlp1).
// ---------------------------------------------------------------------------
template <int EPI>
__global__ __launch_bounds__(256, 2) void gemm_bt(
    const unsigned short* __restrict__ A, const unsigned short* __restrict__ Bt,
    void* __restrict__ Cout, const float* __restrict__ bias,
    const float* __restrict__ mods, int gate_ofs, const float* __restrict__ src,
    int M, int N, int K, int rowsPerB) {
  __shared__ unsigned short As[128 * 32];
  __shared__ unsigned short Bs[128 * 32];
  const int tid = threadIdx.x;
  const int wave = tid >> 6, lane = tid & 63;
  const int g = lane >> 4, r = lane & 15;
  const int m0 = blockIdx.y * 128, n0 = blockIdx.x * 128;
  const int wm = (wave >> 1) * 64, wn = (wave & 1) * 64;
  const int srow = lane >> 2;
  const int scol = (lane & 3) * 8;

  f32x4 acc[4][4] = {};

  for (int k0 = 0; k0 < K; k0 += 32) {
    __syncthreads();
#pragma unroll
    for (int cc = 0; cc < 4; ++cc) {
      int c = wave * 4 + cc;
      int isB = c >> 3;
      int cl = c & 7;
      int row = cl * 16 + srow;
      const unsigned short* gsrc =
          isB ? (Bt + (size_t)(n0 + row) * K + k0 + scol)
              : (A + (size_t)(m0 + row) * K + k0 + scol);
      unsigned short* ldst = (isB ? Bs : As) + cl * 512;
      __builtin_amdgcn_global_load_lds(GLB(gsrc), LDSP(ldst), 16, 0, 0);
    }
    __syncthreads();

    short8 bfr[4];
#pragma unroll
    for (int j = 0; j < 4; ++j)
      bfr[j] = *(const short8*)(&Bs[(wn + j * 16 + r) * 32 + g * 8]);
#pragma unroll
    for (int i = 0; i < 4; ++i) {
      short8 af = *(const short8*)(&As[(wm + i * 16 + r) * 32 + g * 8]);
#pragma unroll
      for (int j = 0; j < 4; ++j)
        acc[i][j] = __builtin_amdgcn_mfma_f32_16x16x32_bf16(af, bfr[j], acc[i][j], 0, 0, 0);
    }
  }
  gemm_epilogue<EPI, 4, 4>(acc, Cout, bias, mods, gate_ofs, src, N, rowsPerB,
                           m0, n0, wm, wn, g, r);
}

// ---------------------------------------------------------------------------
// GEMM (pipelined 128x128): BK=64, 4 LDS bufs, depth-3, counted vmcnt.
// For ~3 blocks/CU grids (QKV).  XCD-grouped decode via mshift.
// ---------------------------------------------------------------------------
template <int EPI>
__global__ __launch_bounds__(256) void gemm_pipe(
    const unsigned short* __restrict__ A, const unsigned short* __restrict__ Bt,
    void* __restrict__ Cout, const float* __restrict__ bias,
    const float* __restrict__ mods, int gate_ofs, const float* __restrict__ src,
    int M, int N, int K, int rowsPerB, int mshift) {
  __shared__ unsigned short lds[4 * 16384];
  const int tid = threadIdx.x;
  const int wave = tid >> 6, lane = tid & 63;
  const int g = lane >> 4, r = lane & 15;
  const int flat = blockIdx.x;
  const int xcd = flat & 7, idx = flat >> 3;
  const int mt = xcd * (1 << mshift) + (idx & ((1 << mshift) - 1));
  const int nt = idx >> mshift;
  const int m0 = mt * 128, n0 = nt * 128;
  const int wm = (wave >> 1) * 64, wn = (wave & 1) * 64;
  const int srow8 = lane >> 3;
  const int sck = (lane & 7) ^ srow8;

  f32x4 acc[4][4] = {};

  auto stage = [&](int t, int bufi) {
    const int k0 = t * 64;
#pragma unroll
    for (int i = 0; i < 8; ++i) {
      int u = wave * 8 + i;
      int isB = u >> 4;
      int uu = u & 15;
      int rl = uu * 8 + srow8;
      const unsigned short* gsrc =
          (isB ? (Bt + (size_t)(n0 + rl) * K) : (A + (size_t)(m0 + rl) * K)) +
          k0 + sck * 8;
      unsigned short* dst = (unsigned short*)lds + bufi * 16384 + isB * 8192 + uu * 512;
      __builtin_amdgcn_global_load_lds(GLB(gsrc), LDSP(dst), 16, 0, 0);
    }
  };

  const int nt_k = K / 64;
  stage(0, 0);
  stage(1, 1);
  stage(2, 2);

  for (int t = 0; t < nt_k; ++t) {
    int rem = nt_k - t;
    if (rem >= 3) {
      asm volatile("s_waitcnt vmcnt(16)" ::: "memory");
    } else if (rem == 2) {
      asm volatile("s_waitcnt vmcnt(8)" ::: "memory");
    } else {
      asm volatile("s_waitcnt vmcnt(0)" ::: "memory");
    }
    __builtin_amdgcn_sched_barrier(0);
    __builtin_amdgcn_s_barrier();
    __builtin_amdgcn_sched_barrier(0);
    if (t + 3 < nt_k) stage(t + 3, (t + 3) & 3);

    const unsigned short* Ab = (const unsigned short*)lds + (t & 3) * 16384;
    const unsigned short* Bb = Ab + 8192;
#pragma unroll
    for (int ks = 0; ks < 2; ++ks) {
      short8 bfr[4];
#pragma unroll
      for (int j = 0; j < 4; ++j) {
        int row = wn + j * 16 + r;
        bfr[j] = *(const short8*)&Bb[row * 64 + ((g + ks * 4) ^ (r & 7)) * 8];
      }
#pragma unroll
      for (int i = 0; i < 4; ++i) {
        int row = wm + i * 16 + r;
        short8 af = *(const short8*)&Ab[row * 64 + ((g + ks * 4) ^ (r & 7)) * 8];
#pragma unroll
        for (int j = 0; j < 4; ++j)
          acc[i][j] = __builtin_amdgcn_mfma_f32_16x16x32_bf16(af, bfr[j], acc[i][j], 0, 0, 0);
      }
    }
  }
  gemm_epilogue<EPI, 4, 4>(acc, Cout, bias, mods, gate_ofs, src, N, rowsPerB,
                           m0, n0, wm, wn, g, r);
}

// ---------------------------------------------------------------------------
// GEMM (64x128 tile, 2-blocks/CU): 4 waves of 32x64, BK=64, 3 LDS bufs (72KB),
// depth-2 counted vmcnt(6).  Grid = (M/64)*(N/128); nt = flat % ntn puts one
// B-panel per XCD when ntn==8.  For the grid-256-at-128x128 GEMMs.
// ---------------------------------------------------------------------------
template <int EPI>
__global__ __launch_bounds__(256) void gemm_p2(
    const unsigned short* __restrict__ A, const unsigned short* __restrict__ Bt,
    void* __restrict__ Cout, const float* __restrict__ bias,
    const float* __restrict__ mods, int gate_ofs, const float* __restrict__ src,
    int M, int N, int K, int rowsPerB, int ntn) {
  __shared__ unsigned short lds[3 * 12288];  // per buf: A 64x64 (8KB) | B 128x64 (16KB)
  const int tid = threadIdx.x;
  const int wave = tid >> 6, lane = tid & 63;
  const int g = lane >> 4, r = lane & 15;
  const int flat = blockIdx.x;
  const int nt = flat % ntn, mt = flat / ntn;
  const int m0 = mt * 64, n0 = nt * 128;
  const int wm = (wave >> 1) * 32, wn = (wave & 1) * 64;
  const int srow8 = lane >> 3;
  const int sck = (lane & 7) ^ srow8;

  f32x4 acc[2][4] = {};

  auto stage = [&](int t, int bufi) {
    const int k0 = t * 64;
    unsigned short* base = (unsigned short*)lds + bufi * 12288;
#pragma unroll
    for (int i = 0; i < 2; ++i) {  // A units: 8 of 64 rows
      int u = wave * 2 + i;
      int rl = u * 8 + srow8;
      const unsigned short* gsrc = A + (size_t)(m0 + rl) * K + k0 + sck * 8;
      __builtin_amdgcn_global_load_lds(GLB(gsrc), LDSP(base + u * 512), 16, 0, 0);
    }
#pragma unroll
    for (int i = 0; i < 4; ++i) {  // B units: 16 of 128 rows
      int u = wave * 4 + i;
      int rl = u * 8 + srow8;
      const unsigned short* gsrc = Bt + (size_t)(n0 + rl) * K + k0 + sck * 8;
      __builtin_amdgcn_global_load_lds(GLB(gsrc), LDSP(base + 4096 + u * 512), 16, 0, 0);
    }
  };

  const int ntk = K / 64;
  stage(0, 0);
  stage(1, 1);
  int cbuf = 0, sbuf = 2;

  for (int t = 0; t < ntk; ++t) {
    if (t < ntk - 1) {
      asm volatile("s_waitcnt vmcnt(6)" ::: "memory");
    } else {
      asm volatile("s_waitcnt vmcnt(0)" ::: "memory");
    }
    __builtin_amdgcn_sched_barrier(0);
    __builtin_amdgcn_s_barrier();
    __builtin_amdgcn_sched_barrier(0);
    if (t + 2 < ntk) {
      stage(t + 2, sbuf);
      sbuf = (sbuf == 2) ? 0 : sbuf + 1;
    }

    const unsigned short* Ab = (const unsigned short*)lds + cbuf * 12288;
    const unsigned short* Bb = Ab + 4096;
#pragma unroll
    for (int ks = 0; ks < 2; ++ks) {
      short8 bfr[4];
#pragma unroll
      for (int j = 0; j < 4; ++j) {
        int row = wn + j * 16 + r;
        bfr[j] = *(const short8*)&Bb[row * 64 + ((g + ks * 4) ^ (r & 7)) * 8];
      }
#pragma unroll
      for (int i = 0; i < 2; ++i) {
        int row = wm + i * 16 + r;
        short8 af = *(const short8*)&Ab[row * 64 + ((g + ks * 4) ^ (r & 7)) * 8];
#pragma unroll
        for (int j = 0; j < 4; ++j)
          acc[i][j] = __builtin_amdgcn_mfma_f32_16x16x32_bf16(af, bfr[j], acc[i][j], 0, 0, 0);
      }
    }
    cbuf = (cbuf == 2) ? 0 : cbuf + 1;
  }
  gemm_epilogue<EPI, 2, 4>(acc, Cout, bias, mods, gate_ofs, src, N, rowsPerB,
                           m0, n0, wm, wn, g, r);
}

// ---------------------------------------------------------------------------
// Flash attention v5 (occupancy-doubled): 4 waves, 64 q/block, wave (p,qh)
// owns q-half qh (32 rows) and kv-parity p (KVBLK=32 tiles).  Grid doubles to
// B*H*(Lq/64)=1024 -> 4 blocks/CU -> 16 waves/CU (VGPR cap) vs 8 before.
// Same verified machinery as v4: swapped 32x32x16 MFMA (S^T = K.Q^T), ones-MFMA
// row-sum, defer-max (T13), cvt_pk+permlane32_swap P-pack, XOR swizzles.
// Wave-pair (p=0/1, same qh) merges online-softmax state via LDS at the end.
// LDS 32KB: K[2 ibuf][2 par][32x64] (16KB) | V^T[2 ibuf][2 par][64x32] (16KB).
// ---------------------------------------------------------------------------
__global__ __launch_bounds__(256, 4) void flash3(
    const unsigned short* __restrict__ Q, const unsigned short* __restrict__ Kv,
    const unsigned short* __restrict__ Vv, unsigned short* __restrict__ O,
    int Lk, float c1) {
  __shared__ unsigned short lds[16384];  // 32KB
  const int tid = threadIdx.x, wave = tid >> 6, lane = tid & 63;
  const int hi = lane >> 5, lq = lane & 31;
  const int qh = wave & 1, p = wave >> 1;
  const int flat = blockIdx.x;
  const int xcd = flat & 7, rr = flat >> 3;
  const int gl = rr >> 5, qt = rr & 31;
  const int g = xcd * 4 + gl;
  const int h = g & 15, b = g >> 4;
  const int Lq = 2048, D = 1024;

  const unsigned short* Qbase =
      Q + ((size_t)b * Lq + qt * 64 + qh * 32 + lq) * D + h * 64;
  const unsigned short* Kbase = Kv + (size_t)b * Lk * D + h * 64;
  const unsigned short* Vbase = Vv + (size_t)b * Lk * D + h * 64;

  short8 qf[4];
#pragma unroll
  for (int kb = 0; kb < 4; ++kb)
    qf[kb] = *(const short8*)(Qbase + kb * 16 + hi * 8);

  const short8 ones = {0x3F80, 0x3F80, 0x3F80, 0x3F80, 0x3F80, 0x3F80, 0x3F80, 0x3F80};

  // staging roles (tid-flat, independent of wave compute role)
  const int kr0 = tid >> 3, kc0 = tid & 7;   // K stage: row in [0,32), chunk
  const int kch0 = (kc0 ^ (kr0 & 7) ^ (kr0 >> 3)) & 7;  // pre-swizzled global chunk
  const int kvp = tid >> 3, db = tid & 7;    // V stage: kv-pair, d-block
  const int vpar = kvp >> 4;                 // kv parity of this thread's V rows
  const int kvl = kvp & 15;                  // local kv-pair within parity tile

  // kt-invariant V^T write byte-offsets within a parity buffer (64B rows)
  int vby[8];
#pragma unroll
  for (int e = 0; e < 8; ++e) {
    int d = db * 8 + e;
    vby[e] = d * 64 + ((kvl * 4) ^ ((((e ^ db)) & 3) << 4));
  }

  const int f0 = (lq & 7) ^ (lq >> 3);
  const int swz0 = f0 << 4;        // K read swizzle (128B rows)
  const int vsw = (f0 & 3) << 4;   // V^T read swizzle (64B rows); same for d and d+32

  float m_run = -3.0e38f;
  f32x16 o0 = {}, o1 = {}, lacc = {};
  short8 vr0, vr1;

  {  // prologue: stage iteration 0 into ibuf 0
    const unsigned short* v0 = Vbase + (size_t)(2 * kvp) * D + db * 8;
    vr0 = *(const short8*)v0;
    vr1 = *(const short8*)(v0 + D);
    const unsigned short* s0 = Kbase + (size_t)kr0 * D + kch0 * 8;
    const unsigned short* s1 = Kbase + (size_t)(kr0 + 32) * D + kch0 * 8;
    __builtin_amdgcn_global_load_lds(GLB(s0), LDSP(&lds[wave * 512]), 16, 0, 0);
    __builtin_amdgcn_global_load_lds(GLB(s1), LDSP(&lds[2048 + wave * 512]), 16, 0, 0);
    char* vt = (char*)lds + 16384 + vpar * 4096;
#pragma unroll
    for (int e = 0; e < 8; ++e)
      *(unsigned int*)(vt + vby[e]) =
          (unsigned int)(unsigned short)vr0[e] |
          ((unsigned int)(unsigned short)vr1[e] << 16);
  }
  __syncthreads();

  const int nit = Lk / 64;  // 64 kv rows per iteration (32 per parity)
  int cb = 0;
  for (int it = 0; it < nit; ++it) {
    const bool pf = (it + 1 < nit);
    if (pf) {  // issue next-iteration loads early
      const unsigned short* v0 = Vbase + (size_t)((it + 1) * 64 + 2 * kvp) * D + db * 8;
      vr0 = *(const short8*)v0;
      vr1 = *(const short8*)(v0 + D);
      const int nb = cb ^ 1;
      const unsigned short* s0 = Kbase + (size_t)((it + 1) * 64 + kr0) * D + kch0 * 8;
      const unsigned short* s1 = Kbase + (size_t)((it + 1) * 64 + kr0 + 32) * D + kch0 * 8;
      __builtin_amdgcn_global_load_lds(GLB(s0), LDSP(&lds[nb * 4096 + wave * 512]), 16, 0, 0);
      __builtin_amdgcn_global_load_lds(GLB(s1), LDSP(&lds[nb * 4096 + 2048 + wave * 512]), 16, 0, 0);
    }

    // ---- S^T = K_p · Q^T  (32 kv x 32 q) ----
    f32x16 sa = {};
    {
      const unsigned short* K0 = &lds[cb * 4096 + p * 2048];
#pragma unroll
      for (int ks = 0; ks < 4; ++ks) {
        int lo = ks * 32 + hi * 16;
        short8 a0 = *(const short8*)&K0[lq * 64 + ((lo ^ swz0) >> 1)];
        sa = __builtin_amdgcn_mfma_f32_32x32x16_bf16(a0, qf[ks], sa, 0, 0, 0);
      }
    }

    // ---- online softmax: tree max + permlane; defer-max rescale ----
    float pm = fmaxf(fmaxf(fmaxf(sa[0], sa[1]), fmaxf(sa[2], sa[3])),
                     fmaxf(fmaxf(sa[4], sa[5]), fmaxf(sa[6], sa[7])));
    pm = fmaxf(pm, fmaxf(fmaxf(fmaxf(sa[8], sa[9]), fmaxf(sa[10], sa[11])),
                         fmaxf(fmaxf(sa[12], sa[13]), fmaxf(sa[14], sa[15]))));
    {
      unsigned int ua = __builtin_bit_cast(unsigned int, pm), ub = ua;
      vpsw(ua, ub);
      pm = fmaxf(__builtin_bit_cast(float, ua), __builtin_bit_cast(float, ub));
    }
    if (__any((pm - m_run) * c1 > 8.0f)) {
      float mnew = fmaxf(m_run, pm);
      float alpha = exp2f((m_run - mnew) * c1);
      lacc[0] *= alpha;
#pragma unroll
      for (int i = 0; i < 16; ++i) { o0[i] *= alpha; o1[i] *= alpha; }
      m_run = mnew;
    }
    float mc = m_run * c1;
#pragma unroll
    for (int i = 0; i < 16; ++i) sa[i] = exp2f(sa[i] * c1 - mc);

    // ---- P^T B-fragments via permlane32_swap ----
    short8 pbf[2];
#pragma unroll
    for (int kb = 0; kb < 2; ++kb) {
      int bb = kb * 8;
      unsigned int u0 = pk2(sa[bb + 0], sa[bb + 1]), u1 = pk2(sa[bb + 2], sa[bb + 3]);
      unsigned int u2 = pk2(sa[bb + 4], sa[bb + 5]), u3 = pk2(sa[bb + 6], sa[bb + 7]);
      vpsw(u0, u2);
      vpsw(u1, u3);
      union { unsigned int u[4]; short8 s; } fr;
      fr.u[0] = u0; fr.u[1] = u1; fr.u[2] = u2; fr.u[3] = u3;
      pbf[kb] = fr.s;
    }

    // ---- write prefetched V (transposed+swizzled) into next ibuf ----
    if (pf) {
      char* vt = (char*)lds + 16384 + (cb ^ 1) * 8192 + vpar * 4096;
#pragma unroll
      for (int e = 0; e < 8; ++e)
        *(unsigned int*)(vt + vby[e]) =
            (unsigned int)(unsigned short)vr0[e] |
            ((unsigned int)(unsigned short)vr1[e] << 16);
    }

    // ---- O^T += V^T · P^T ; row-sum via ones-MFMA (lacc[0] = l_run) ----
    {
      const unsigned short* V0 = &lds[8192 + cb * 4096 + p * 2048];
#pragma unroll
      for (int kb = 0; kb < 2; ++kb) {
        int lo = kb * 32 + hi * 16;
        short8 vf0 = *(const short8*)&V0[lq * 32 + ((lo ^ vsw) >> 1)];
        short8 vf1 = *(const short8*)&V0[(lq + 32) * 32 + ((lo ^ vsw) >> 1)];
        o0 = __builtin_amdgcn_mfma_f32_32x32x16_bf16(vf0, pbf[kb], o0, 0, 0, 0);
        o1 = __builtin_amdgcn_mfma_f32_32x32x16_bf16(vf1, pbf[kb], o1, 0, 0, 0);
        lacc = __builtin_amdgcn_mfma_f32_32x32x16_bf16(ones, pbf[kb], lacc, 0, 0, 0);
      }
    }

    __syncthreads();
    cb ^= 1;
  }

  // ---- merge wave-pair (p=0 <-> p=1, same qh) via LDS, then store ----
  const float m_own = m_run, l_own = lacc[0];
  float* ex = (float*)lds;
  if (p == 1) {
    ex[qh * 64 + lane] = m_own;
    ex[128 + qh * 64 + lane] = l_own;
    float* ob = ex + 256 + qh * 2048;
#pragma unroll
    for (int t = 0; t < 16; ++t) {
      ob[t * 64 + lane] = o0[t];
      ob[(16 + t) * 64 + lane] = o1[t];
    }
  }
  __syncthreads();
  if (p == 0) {
    float m1v = ex[qh * 64 + lane];
    float l1v = ex[128 + qh * 64 + lane];
    float mM = fmaxf(m_own, m1v);
    float a0s = exp2f((m_own - mM) * c1);
    float a1s = exp2f((m1v - mM) * c1);
    float rl = 1.0f / (a0s * l_own + a1s * l1v);
    const float* ob = ex + 256 + qh * 2048;
#pragma unroll
    for (int t = 0; t < 16; ++t) {
      o0[t] = (a0s * o0[t] + a1s * ob[t * 64 + lane]) * rl;
      o1[t] = (a0s * o1[t] + a1s * ob[(16 + t) * 64 + lane]) * rl;
    }

    // bounce through LDS (disjoint region, bytes 17408+), coalesced store
    unsigned short* os = (unsigned short*)lds + 8704 + qh * 2048;
#pragma unroll
    for (int t = 0; t < 2; ++t) {
#pragma unroll
      for (int c = 0; c < 4; ++c) {
        int dbase = 32 * t + 8 * c + 4 * hi;
        float v0 = (t ? o1[4 * c + 0] : o0[4 * c + 0]);
        float v1 = (t ? o1[4 * c + 1] : o0[4 * c + 1]);
        float v2 = (t ? o1[4 * c + 2] : o0[4 * c + 2]);
        float v3 = (t ? o1[4 * c + 3] : o0[4 * c + 3]);
        int by0 = lq * 128 + ((dbase * 2) ^ ((lq & 7) << 4));
        int by1 = lq * 128 + (((dbase + 2) * 2) ^ ((lq & 7) << 4));
        *(unsigned int*)((char*)os + by0) = pk2(v0, v1);
        *(unsigned int*)((char*)os + by1) = pk2(v2, v3);
      }
    }
    int q2 = lane >> 1;
    unsigned short* orow =
        O + ((size_t)b * Lq + qt * 64 + qh * 32 + q2) * D + h * 64;
#pragma unroll
    for (int j = 0; j < 4; ++j) {
      int j2 = (lane & 1) * 4 + j;
      int byr = q2 * 128 + ((j2 * 16) ^ ((q2 & 7) << 4));
      short8 vv = *(const short8*)((char*)os + byr);
      *(short8*)(orow + j2 * 8) = vv;
    }
  }
}

// ---------------------------------------------------------------------------
// Host orchestration
// ---------------------------------------------------------------------------
extern "C" void kernel_launch(void* const* d_in, const int* in_sizes, int n_in,
                              void* d_out, int out_size, void* d_ws, size_t ws_size,
                              hipStream_t stream) {
  (void)in_sizes; (void)n_in; (void)out_size; (void)ws_size;
  const float* x_in = (const float*)d_in[0];
  const float* te   = (const float*)d_in[1];
  const float* ctx  = (const float*)d_in[2];
  const float* rope = (const float*)d_in[3];
  const float* wmod = (const float*)d_in[4];
  const float* bmod = (const float*)d_in[5];
  const float* wqs  = (const float*)d_in[6];
  const float* wks  = (const float*)d_in[7];
  const float* wvs  = (const float*)d_in[8];
  const float* wos  = (const float*)d_in[9];
  const float* bos  = (const float*)d_in[10];
  const float* wqc  = (const float*)d_in[11];
  const float* wkc  = (const float*)d_in[12];
  const float* wvc  = (const float*)d_in[13];
  const float* woc  = (const float*)d_in[14];
  const float* boc  = (const float*)d_in[15];
  const float* w1   = (const float*)d_in[16];
  const float* b1   = (const float*)d_in[17];
  const float* w2   = (const float*)d_in[18];
  const float* b2   = (const float*)d_in[19];
  float* out = (float*)d_out;

  char* w = (char*)d_ws;
  size_t o = 0;
  auto alloc = [&](size_t bytes) {
    char* p = w + o;
    o = (o + bytes + 255) & ~(size_t)255;
    return p;
  };
  unsigned short* wmodT = (unsigned short*)alloc(6144ull * 1024 * 2);
  // wqsT/wksT/wvsT adjacent (fused QKV); wkcT/wvcT adjacent (fused cross-KV).
  unsigned short* wqsT  = (unsigned short*)alloc(1024ull * 1024 * 2);
  unsigned short* wksT  = (unsigned short*)alloc(1024ull * 1024 * 2);
  unsigned short* wvsT  = (unsigned short*)alloc(1024ull * 1024 * 2);
  unsigned short* wosT  = (unsigned short*)alloc(1024ull * 1024 * 2);
  unsigned short* wqcT  = (unsigned short*)alloc(1024ull * 1024 * 2);
  unsigned short* wkcT  = (unsigned short*)alloc(1024ull * 1024 * 2);
  unsigned short* wvcT  = (unsigned short*)alloc(1024ull * 1024 * 2);
  unsigned short* wocT  = (unsigned short*)alloc(1024ull * 1024 * 2);
  unsigned short* w1T   = (unsigned short*)alloc(4096ull * 1024 * 2);
  unsigned short* w2T   = (unsigned short*)alloc(1024ull * 4096 * 2);
  float* modsb = (float*)alloc(2ull * 6144 * 4);
  float* cosT  = (float*)alloc(2048ull * 64 * 4);
  float* sinT  = (float*)alloc(2048ull * 64 * 4);
  unsigned short* nx   = (unsigned short*)alloc(4096ull * 1024 * 2);
  unsigned short* ctxb = (unsigned short*)alloc(1024ull * 1024 * 2);
  // qb/kb/vb adjacent: EPI3 buffer stride = 4096*1024 elems.
  unsigned short* qb = (unsigned short*)alloc(4096ull * 1024 * 2);
  unsigned short* kb = (unsigned short*)alloc(4096ull * 1024 * 2);
  unsigned short* vb = (unsigned short*)alloc(4096ull * 1024 * 2);
  unsigned short* ao = (unsigned short*)alloc(4096ull * 1024 * 2);
  float* xw = (float*)alloc(4096ull * 1024 * 4);
  unsigned short* hbuf = qb;  // reuse qb..ao contiguous 32MB for MLP hidden

  const float c1 = 0.125f * 1.4426950408889634f;  // scale * log2(e)

  dim3 tb(32, 8);
  transpose_cast<<<dim3(6144 / 32, 1024 / 32), tb, 0, stream>>>(wmod, wmodT, 1024, 6144);
  transpose_cast<<<dim3(32, 32), tb, 0, stream>>>(wqs, wqsT, 1024, 1024);
  transpose_cast<<<dim3(32, 32), tb, 0, stream>>>(wks, wksT, 1024, 1024);
  transpose_cast<<<dim3(32, 32), tb, 0, stream>>>(wvs, wvsT, 1024, 1024);
  transpose_cast<<<dim3(32, 32), tb, 0, stream>>>(wos, wosT, 1024, 1024);
  transpose_cast<<<dim3(32, 32), tb, 0, stream>>>(wqc, wqcT, 1024, 1024);
  transpose_cast<<<dim3(32, 32), tb, 0, stream>>>(wkc, wkcT, 1024, 1024);
  transpose_cast<<<dim3(32, 32), tb, 0, stream>>>(wvc, wvcT, 1024, 1024);
  transpose_cast<<<dim3(32, 32), tb, 0, stream>>>(woc, wocT, 1024, 1024);
  transpose_cast<<<dim3(4096 / 32, 1024 / 32), tb, 0, stream>>>(w1, w1T, 1024, 4096);
  transpose_cast<<<dim3(1024 / 32, 4096 / 32), tb, 0, stream>>>(w2, w2T, 4096, 1024);

  cast_bf16<<<4096, 256, 0, stream>>>(ctx, ctxb, 1024 * 1024);
  rope_tab<<<512, 256, 0, stream>>>(rope, cosT, sinT, 2048 * 64);
  mods_kernel<<<3072, 256, 0, stream>>>(te, wmodT, bmod, modsb);

  // --- self-attention ---
  ln_mod<<<4096, 256, 0, stream>>>(x_in, modsb, nx, 1024, 0);
  gemm_pipe<3><<<768, 256, 0, stream>>>(nx, wqsT, qb, nullptr, nullptr, -1, nullptr, 4096, 3072, 1024, 2048, 2);
  rope_apply<<<dim3(8192, 2), 256, 0, stream>>>(qb, kb, cosT, sinT);
  flash3<<<1024, 256, 0, stream>>>(qb, kb, vb, ao, 2048, c1);
  gemm_p2<2><<<512, 256, 0, stream>>>(ao, wosT, xw, bos, modsb, 2048, x_in, 4096, 1024, 1024, 2048, 8);

  // --- cross-attention ---
  ln_mod<<<4096, 256, 0, stream>>>(xw, modsb, nx, -1, -1);
  gemm_p2<0><<<512, 256, 0, stream>>>(nx, wqcT, qb, nullptr, nullptr, -1, nullptr, 4096, 1024, 1024, 2048, 8);
  gemm_p2<3><<<256, 256, 0, stream>>>(ctxb, wkcT, kb, nullptr, nullptr, -1, nullptr, 1024, 2048, 1024, 512, 16);
  flash3<<<1024, 256, 0, stream>>>(qb, kb, vb, ao, 512, c1);
  gemm_p2<2><<<512, 256, 0, stream>>>(ao, wocT, xw, boc, modsb, -1, xw, 4096, 1024, 1024, 2048, 8);

  // --- MLP ---
  ln_mod<<<4096, 256, 0, stream>>>(xw, modsb, nx, 4096, 3072);
  gemm_bt<1><<<dim3(32, 32), 256, 0, stream>>>(nx, w1T, hbuf, b1, nullptr, -1, nullptr, 4096, 4096, 1024, 2048);
  gemm_p2<2><<<512, 256, 0, stream>>>(hbuf, w2T, out, b2, modsb, 5120, xw, 4096, 1024, 4096, 2048, 8);
}

// Round 2
// 435.427 us; speedup vs baseline: 1.0048x; 1.0048x over previous
//
#include <hip/hip_runtime.h>
#include <hip/hip_bf16.h>

// ---------------------------------------------------------------------------
// CleanDITBlock: adaLN-modulated DiT block (self-attn w/ RoPE, cross-attn, MLP)
// B=2, L=2048, S=512, D=1024, H=16, HD=64, CTX=1024, HID=4096
// ---------------------------------------------------------------------------

typedef short short8 __attribute__((ext_vector_type(8)));
typedef float f32x4 __attribute__((ext_vector_type(4)));
typedef float f32x16 __attribute__((ext_vector_type(16)));

#define DEV __device__ __forceinline__

DEV unsigned short f2b(float f) {
  __hip_bfloat16 h = __float2bfloat16(f);
  return *reinterpret_cast<unsigned short*>(&h);
}
DEV float b2f(unsigned short u) {
  unsigned int x = ((unsigned int)u) << 16;
  return __builtin_bit_cast(float, x);
}
DEV unsigned int pk2(float lo, float hi) {
  return (unsigned int)f2b(lo) | ((unsigned int)f2b(hi) << 16);
}
// lane[i]<->lane[i+32] half-swap (VALU, no LDS)
DEV void vpsw(unsigned int& a, unsigned int& b) {
  asm("v_permlane32_swap_b32 %0, %1" : "+v"(a), "+v"(b));
}

#define GLB(p) ((const __attribute__((address_space(1))) void*)(p))
#define LDSP(p) ((__attribute__((address_space(3))) void*)(p))

// ---------------------------------------------------------------------------
__global__ __launch_bounds__(256) void transpose_cast(
    const float* __restrict__ in, unsigned short* __restrict__ out, int R, int C) {
  __shared__ float tile[32][33];
  int bx = blockIdx.x * 32, by = blockIdx.y * 32;
  int tx = threadIdx.x, ty = threadIdx.y;  // 32 x 8
#pragma unroll
  for (int i = ty; i < 32; i += 8)
    tile[i][tx] = in[(size_t)(by + i) * C + bx + tx];
  __syncthreads();
#pragma unroll
  for (int i = ty; i < 32; i += 8)
    out[(size_t)(bx + i) * R + by + tx] = f2b(tile[tx][i]);
}

__global__ __launch_bounds__(256) void cast_bf16(
    const float* __restrict__ in, unsigned short* __restrict__ out, int n) {
  int i = blockIdx.x * 256 + threadIdx.x;
  if (i < n) out[i] = f2b(in[i]);
}

__global__ __launch_bounds__(256) void rope_tab(
    const float* __restrict__ rope, float* __restrict__ cosT, float* __restrict__ sinT, int n) {
  int i = blockIdx.x * 256 + threadIdx.x;
  if (i < n) {
    float v = rope[i];
    cosT[i] = cosf(v);
    sinT[i] = sinf(v);
  }
}

// ---------------------------------------------------------------------------
__global__ __launch_bounds__(256) void mods_kernel(
    const float* __restrict__ te, const unsigned short* __restrict__ wmodT,
    const float* __restrict__ bmod, float* __restrict__ mods) {
  int w = blockIdx.x * 4 + (threadIdx.x >> 6);
  int lane = threadIdx.x & 63;
  int b = w / 6144, j = w % 6144;
  const unsigned short* wr = wmodT + (size_t)j * 1024;
  const float* ter = te + (size_t)b * 1024;
  int k0 = lane * 16;
  float sum = 0.f;
#pragma unroll
  for (int u = 0; u < 2; ++u) {
    short8 wv = *(const short8*)(wr + k0 + u * 8);
#pragma unroll
    for (int e = 0; e < 8; ++e)
      sum += b2f((unsigned short)wv[e]) * ter[k0 + u * 8 + e];
  }
#pragma unroll
  for (int off = 32; off >= 1; off >>= 1) sum += __shfl_down(sum, off);
  if (lane == 0) mods[(size_t)b * 6144 + j] = sum + bmod[j];
}

// ---------------------------------------------------------------------------
__global__ __launch_bounds__(256) void ln_mod(
    const float* __restrict__ x, const float* __restrict__ mods,
    unsigned short* __restrict__ out, int scale_ofs, int shift_ofs) {
  int row = blockIdx.x;
  int b = row >> 11;
  int tid = threadIdx.x;
  const float* xr = x + (size_t)row * 1024;
  float4 v = ((const float4*)xr)[tid];
  float s = v.x + v.y + v.z + v.w;
  float ss = v.x * v.x + v.y * v.y + v.z * v.z + v.w * v.w;
#pragma unroll
  for (int off = 32; off >= 1; off >>= 1) {
    s += __shfl_down(s, off);
    ss += __shfl_down(ss, off);
  }
  __shared__ float red[8];
  int wave = tid >> 6, lane = tid & 63;
  if (lane == 0) { red[wave] = s; red[4 + wave] = ss; }
  __syncthreads();
  if (tid == 0) {
    float S = red[0] + red[1] + red[2] + red[3];
    float SS = red[4] + red[5] + red[6] + red[7];
    float mu = S * (1.f / 1024.f);
    red[0] = mu;
    red[1] = SS * (1.f / 1024.f) - mu * mu;
  }
  __syncthreads();
  float mu = red[0];
  float rs = rsqrtf(red[1] + 1e-6f);
  float vv[4] = {v.x, v.y, v.z, v.w};
  unsigned short o[4];
#pragma unroll
  for (int c = 0; c < 4; ++c) {
    int col = tid * 4 + c;
    float nv = (vv[c] - mu) * rs;
    if (scale_ofs >= 0)
      nv = nv * (1.f + mods[(size_t)b * 6144 + scale_ofs + col]) +
           mods[(size_t)b * 6144 + shift_ofs + col];
    o[c] = f2b(nv);
  }
  *(ushort4*)(&out[(size_t)row * 1024 + tid * 4]) = *(const ushort4*)o;
}

// ---------------------------------------------------------------------------
__global__ __launch_bounds__(256) void rope_apply(
    unsigned short* __restrict__ qb, unsigned short* __restrict__ kb,
    const float* __restrict__ cosT, const float* __restrict__ sinT) {
  int idx = blockIdx.x * 256 + threadIdx.x;  // over [4096][16][32]
  unsigned short* buf = blockIdx.y ? kb : qb;
  int row = idx >> 9;
  int rem = idx & 511;
  int h = rem >> 5, d = rem & 31;
  int l = row & 2047;
  size_t base = (size_t)row * 1024 + h * 64 + d;
  float x1 = b2f(buf[base]), x2 = b2f(buf[base + 32]);
  float c1 = cosT[l * 64 + d], s1 = sinT[l * 64 + d];
  float c2 = cosT[l * 64 + d + 32], s2 = sinT[l * 64 + d + 32];
  buf[base] = f2b(x1 * c1 - x2 * s1);
  buf[base + 32] = f2b(x2 * c2 + x1 * s2);
}

// ---------------------------------------------------------------------------
// Shared GEMM epilogue.  EPI: 0 bf16; 1 bias+GELU bf16; 2 f32 residual
// src + gate*(acc+bias); 3 bf16 split-store (buffer = col>>10, row stride 1024,
// buffer stride 4096*1024).
// ---------------------------------------------------------------------------
template <int EPI, int MI, int NJ>
DEV void gemm_epilogue(f32x4 (&acc)[MI][NJ], void* Cout, const float* bias,
                       const float* mods, int gate_ofs, const float* src,
                       int N, int rowsPerB, int m0, int n0, int wm, int wn,
                       int g, int r) {
#pragma unroll
  for (int i = 0; i < MI; ++i) {
#pragma unroll
    for (int j = 0; j < NJ; ++j) {
#pragma unroll
      for (int q = 0; q < 4; ++q) {
        size_t grow = (size_t)(m0 + wm + i * 16 + g * 4 + q);
        size_t gcol = (size_t)(n0 + wn + j * 16 + r);
        float v = acc[i][j][q];
        if constexpr (EPI == 0) {
          ((unsigned short*)Cout)[grow * N + gcol] = f2b(v);
        } else if constexpr (EPI == 1) {
          v += bias[gcol];
          float ge = 0.5f * v * (1.0f + erff(v * 0.70710678f));
          ((unsigned short*)Cout)[grow * N + gcol] = f2b(ge);
        } else if constexpr (EPI == 3) {
          size_t buf = gcol >> 10;
          ((unsigned short*)Cout)[buf * (4096ull * 1024) + grow * 1024 + (gcol & 1023)] = f2b(v);
        } else {
          v += bias[gcol];
          float gate = 1.0f;
          if (gate_ofs >= 0)
            gate = mods[(grow / rowsPerB) * 6144 + gate_ofs + gcol];
          ((float*)Cout)[grow * N + gcol] = src[grow * N + gcol] + gate * v;
        }
      }
    }
  }
}

// ---------------------------------------------------------------------------
// GEMM (m97): 128x128, BK=32, implicit overlap.  For >=4 blocks/CU (mlp1).
// ---------------------------------------------------------------------------
template <int EPI>
__global__ __launch_bounds__(256, 2) void gemm_bt(
    const unsigned short* __restrict__ A, const unsigned short* __restrict__ Bt,
    void* __restrict__ Cout, const float* __restrict__ bias,
    const float* __restrict__ mods, int gate_ofs, const float* __restrict__ src,
    int M, int N, int K, int rowsPerB) {
  __shared__ unsigned short As[128 * 32];
  __shared__ unsigned short Bs[128 * 32];
  const int tid = threadIdx.x;
  const int wave = tid >> 6, lane = tid & 63;
  const int g = lane >> 4, r = lane & 15;
  const int m0 = blockIdx.y * 128, n0 = blockIdx.x * 128;
  const int wm = (wave >> 1) * 64, wn = (wave & 1) * 64;
  const int srow = lane >> 2;
  const int scol = (lane & 3) * 8;

  f32x4 acc[4][4] = {};

  for (int k0 = 0; k0 < K; k0 += 32) {
    __syncthreads();
#pragma unroll
    for (int cc = 0; cc < 4; ++cc) {
      int c = wave * 4 + cc;
      int isB = c >> 3;
      int cl = c & 7;
      int row = cl * 16 + srow;
      const unsigned short* gsrc =
          isB ? (Bt + (size_t)(n0 + row) * K + k0 + scol)
              : (A + (size_t)(m0 + row) * K + k0 + scol);
      unsigned short* ldst = (isB ? Bs : As) + cl * 512;
      __builtin_amdgcn_global_load_lds(GLB(gsrc), LDSP(ldst), 16, 0, 0);
    }
    __syncthreads();

    short8 bfr[4];
#pragma unroll
    for (int j = 0; j < 4; ++j)
      bfr[j] = *(const short8*)(&Bs[(wn + j * 16 + r) * 32 + g * 8]);
#pragma unroll
    for (int i = 0; i < 4; ++i) {
      short8 af = *(const short8*)(&As[(wm + i * 16 + r) * 32 + g * 8]);
#pragma unroll
      for (int j = 0; j < 4; ++j)
        acc[i][j] = __builtin_amdgcn_mfma_f32_16x16x32_bf16(af, bfr[j], acc[i][j], 0, 0, 0);
    }
  }
  gemm_epilogue<EPI, 4, 4>(acc, Cout, bias, mods, gate_ofs, src, N, rowsPerB,
                           m0, n0, wm, wn, g, r);
}

// ---------------------------------------------------------------------------
// GEMM (pipelined 128x128): BK=64, 4 LDS bufs, depth-3, counted vmcnt.
// For ~3 blocks/CU grids (QKV).  XCD-grouped decode via mshift.
// ---------------------------------------------------------------------------
template <int EPI>
__global__ __launch_bounds__(256) void gemm_pipe(
    const unsigned short* __restrict__ A, const unsigned short* __restrict__ Bt,
    void* __restrict__ Cout, const float* __restrict__ bias,
    const float* __restrict__ mods, int gate_ofs, const float* __restrict__ src,
    int M, int N, int K, int rowsPerB, int mshift) {
  __shared__ unsigned short lds[4 * 16384];
  const int tid = threadIdx.x;
  const int wave = tid >> 6, lane = tid & 63;
  const int g = lane >> 4, r = lane & 15;
  const int flat = blockIdx.x;
  const int xcd = flat & 7, idx = flat >> 3;
  const int mt = xcd * (1 << mshift) + (idx & ((1 << mshift) - 1));
  const int nt = idx >> mshift;
  const int m0 = mt * 128, n0 = nt * 128;
  const int wm = (wave >> 1) * 64, wn = (wave & 1) * 64;
  const int srow8 = lane >> 3;
  const int sck = (lane & 7) ^ srow8;

  f32x4 acc[4][4] = {};

  auto stage = [&](int t, int bufi) {
    const int k0 = t * 64;
#pragma unroll
    for (int i = 0; i < 8; ++i) {
      int u = wave * 8 + i;
      int isB = u >> 4;
      int uu = u & 15;
      int rl = uu * 8 + srow8;
      const unsigned short* gsrc =
          (isB ? (Bt + (size_t)(n0 + rl) * K) : (A + (size_t)(m0 + rl) * K)) +
          k0 + sck * 8;
      unsigned short* dst = (unsigned short*)lds + bufi * 16384 + isB * 8192 + uu * 512;
      __builtin_amdgcn_global_load_lds(GLB(gsrc), LDSP(dst), 16, 0, 0);
    }
  };

  const int nt_k = K / 64;
  stage(0, 0);
  stage(1, 1);
  stage(2, 2);

  for (int t = 0; t < nt_k; ++t) {
    int rem = nt_k - t;
    if (rem >= 3) {
      asm volatile("s_waitcnt vmcnt(16)" ::: "memory");
    } else if (rem == 2) {
      asm volatile("s_waitcnt vmcnt(8)" ::: "memory");
    } else {
      asm volatile("s_waitcnt vmcnt(0)" ::: "memory");
    }
    __builtin_amdgcn_sched_barrier(0);
    __builtin_amdgcn_s_barrier();
    __builtin_amdgcn_sched_barrier(0);
    if (t + 3 < nt_k) stage(t + 3, (t + 3) & 3);

    const unsigned short* Ab = (const unsigned short*)lds + (t & 3) * 16384;
    const unsigned short* Bb = Ab + 8192;
#pragma unroll
    for (int ks = 0; ks < 2; ++ks) {
      short8 bfr[4];
#pragma unroll
      for (int j = 0; j < 4; ++j) {
        int row = wn + j * 16 + r;
        bfr[j] = *(const short8*)&Bb[row * 64 + ((g + ks * 4) ^ (r & 7)) * 8];
      }
#pragma unroll
      for (int i = 0; i < 4; ++i) {
        int row = wm + i * 16 + r;
        short8 af = *(const short8*)&Ab[row * 64 + ((g + ks * 4) ^ (r & 7)) * 8];
#pragma unroll
        for (int j = 0; j < 4; ++j)
          acc[i][j] = __builtin_amdgcn_mfma_f32_16x16x32_bf16(af, bfr[j], acc[i][j], 0, 0, 0);
      }
    }
  }
  gemm_epilogue<EPI, 4, 4>(acc, Cout, bias, mods, gate_ofs, src, N, rowsPerB,
                           m0, n0, wm, wn, g, r);
}

// ---------------------------------------------------------------------------
// GEMM (64x128 tile, 2-blocks/CU): 4 waves of 32x64, BK=64, 3 LDS bufs (72KB),
// depth-2 counted vmcnt(6).  Grid = (M/64)*(N/128); nt = flat % ntn puts one
// B-panel per XCD when ntn==8.  For the grid-256-at-128x128 GEMMs.
// ---------------------------------------------------------------------------
template <int EPI>
__global__ __launch_bounds__(256) void gemm_p2(
    const unsigned short* __restrict__ A, const unsigned short* __restrict__ Bt,
    void* __restrict__ Cout, const float* __restrict__ bias,
    const float* __restrict__ mods, int gate_ofs, const float* __restrict__ src,
    int M, int N, int K, int rowsPerB, int ntn) {
  __shared__ unsigned short lds[3 * 12288];  // per buf: A 64x64 (8KB) | B 128x64 (16KB)
  const int tid = threadIdx.x;
  const int wave = tid >> 6, lane = tid & 63;
  const int g = lane >> 4, r = lane & 15;
  const int flat = blockIdx.x;
  const int nt = flat % ntn, mt = flat / ntn;
  const int m0 = mt * 64, n0 = nt * 128;
  const int wm = (wave >> 1) * 32, wn = (wave & 1) * 64;
  const int srow8 = lane >> 3;
  const int sck = (lane & 7) ^ srow8;

  f32x4 acc[2][4] = {};

  auto stage = [&](int t, int bufi) {
    const int k0 = t * 64;
    unsigned short* base = (unsigned short*)lds + bufi * 12288;
#pragma unroll
    for (int i = 0; i < 2; ++i) {  // A units: 8 of 64 rows
      int u = wave * 2 + i;
      int rl = u * 8 + srow8;
      const unsigned short* gsrc = A + (size_t)(m0 + rl) * K + k0 + sck * 8;
      __builtin_amdgcn_global_load_lds(GLB(gsrc), LDSP(base + u * 512), 16, 0, 0);
    }
#pragma unroll
    for (int i = 0; i < 4; ++i) {  // B units: 16 of 128 rows
      int u = wave * 4 + i;
      int rl = u * 8 + srow8;
      const unsigned short* gsrc = Bt + (size_t)(n0 + rl) * K + k0 + sck * 8;
      __builtin_amdgcn_global_load_lds(GLB(gsrc), LDSP(base + 4096 + u * 512), 16, 0, 0);
    }
  };

  const int ntk = K / 64;
  stage(0, 0);
  stage(1, 1);
  int cbuf = 0, sbuf = 2;

  for (int t = 0; t < ntk; ++t) {
    if (t < ntk - 1) {
      asm volatile("s_waitcnt vmcnt(6)" ::: "memory");
    } else {
      asm volatile("s_waitcnt vmcnt(0)" ::: "memory");
    }
    __builtin_amdgcn_sched_barrier(0);
    __builtin_amdgcn_s_barrier();
    __builtin_amdgcn_sched_barrier(0);
    if (t + 2 < ntk) {
      stage(t + 2, sbuf);
      sbuf = (sbuf == 2) ? 0 : sbuf + 1;
    }

    const unsigned short* Ab = (const unsigned short*)lds + cbuf * 12288;
    const unsigned short* Bb = Ab + 4096;
#pragma unroll
    for (int ks = 0; ks < 2; ++ks) {
      short8 bfr[4];
#pragma unroll
      for (int j = 0; j < 4; ++j) {
        int row = wn + j * 16 + r;
        bfr[j] = *(const short8*)&Bb[row * 64 + ((g + ks * 4) ^ (r & 7)) * 8];
      }
#pragma unroll
      for (int i = 0; i < 2; ++i) {
        int row = wm + i * 16 + r;
        short8 af = *(const short8*)&Ab[row * 64 + ((g + ks * 4) ^ (r & 7)) * 8];
#pragma unroll
        for (int j = 0; j < 4; ++j)
          acc[i][j] = __builtin_amdgcn_mfma_f32_16x16x32_bf16(af, bfr[j], acc[i][j], 0, 0, 0);
      }
    }
    cbuf = (cbuf == 2) ? 0 : cbuf + 1;
  }
  gemm_epilogue<EPI, 2, 4>(acc, Cout, bias, mods, gate_ofs, src, N, rowsPerB,
                           m0, n0, wm, wn, g, r);
}

// ---------------------------------------------------------------------------
// Flash attention v6: occupancy-doubled (64 q/block, kv-parity wave split,
// grid B*H*(Lq/64)=1024 -> 4 blocks/CU) with v4's PROVEN LDS layouts:
//   K  [2 ibuf][64 rows][128B]  kch0/kch1 pre-swizzle, read swz = swz0^(p<<6)
//   V^T [2 ibuf][64 d][64 kv]   joint tile, full 3-bit XOR swizzle (128B rows)
// v5's 64B-row V^T halved the swizzle space -> 4-way bank conflicts (2.31M);
// this restores the 128B-row pattern (~2-way, free) at identical 32KB LDS.
// Wave-pair (p=0/1, same qh) merges online-softmax state via LDS at the end.
// ---------------------------------------------------------------------------
__global__ __launch_bounds__(256, 4) void flash3(
    const unsigned short* __restrict__ Q, const unsigned short* __restrict__ Kv,
    const unsigned short* __restrict__ Vv, unsigned short* __restrict__ O,
    int Lk, float c1) {
  __shared__ unsigned short lds[16384];  // 32KB: K 2x8KB | V^T 2x8KB
  const int tid = threadIdx.x, wave = tid >> 6, lane = tid & 63;
  const int hi = lane >> 5, lq = lane & 31;
  const int qh = wave & 1, p = wave >> 1;
  const int flat = blockIdx.x;
  const int xcd = flat & 7, rr = flat >> 3;
  const int gl = rr >> 5, qt = rr & 31;
  const int g = xcd * 4 + gl;
  const int h = g & 15, b = g >> 4;
  const int Lq = 2048, D = 1024;

  const unsigned short* Qbase =
      Q + ((size_t)b * Lq + qt * 64 + qh * 32 + lq) * D + h * 64;
  const unsigned short* Kbase = Kv + (size_t)b * Lk * D + h * 64;
  const unsigned short* Vbase = Vv + (size_t)b * Lk * D + h * 64;

  short8 qf[4];
#pragma unroll
  for (int kb = 0; kb < 4; ++kb)
    qf[kb] = *(const short8*)(Qbase + kb * 16 + hi * 8);

  const short8 ones = {0x3F80, 0x3F80, 0x3F80, 0x3F80, 0x3F80, 0x3F80, 0x3F80, 0x3F80};

  // staging roles (tid-flat, independent of wave compute role) — v4 pattern
  const int kr0 = tid >> 3, kc0 = tid & 7;   // K stage: row in [0,32), chunk
  const int kch0 = (kc0 ^ (kr0 & 7) ^ (kr0 >> 3)) & 7;
  const int kch1 = kch0 ^ 4;                 // rows 32..63: f(row) ^= 4
  const int kvp = tid >> 3, db = tid & 7;    // V stage: kv-pair in [0,32), d-block

  // kt-invariant V^T write byte-offsets (128B rows, 3-bit XOR) — v4 pattern
  int vby[8];
#pragma unroll
  for (int e = 0; e < 8; ++e) {
    int d = db * 8 + e;
    vby[e] = d * 128 + ((kvp * 4) ^ (((e ^ db) & 7) << 4));
  }

  const int f0 = (lq & 7) ^ (lq >> 3);
  const int swz0 = f0 << 4;
  const int swz1 = swz0 ^ 64;
  const int swzp = swz0 ^ (p << 6);          // K read swizzle for this wave's rows
  const int krow = (p * 32 + lq) * 64;       // K read row base (shorts)

  float m_run = -3.0e38f;
  f32x16 o0 = {}, o1 = {}, lacc = {};
  short8 vr0, vr1;

  {  // prologue: stage iteration 0 into ibuf 0
    const unsigned short* v0 = Vbase + (size_t)(2 * kvp) * D + db * 8;
    vr0 = *(const short8*)v0;
    vr1 = *(const short8*)(v0 + D);
    const unsigned short* s0 = Kbase + (size_t)kr0 * D + kch0 * 8;
    const unsigned short* s1 = Kbase + (size_t)(kr0 + 32) * D + kch1 * 8;
    __builtin_amdgcn_global_load_lds(GLB(s0), LDSP(&lds[wave * 512]), 16, 0, 0);
    __builtin_amdgcn_global_load_lds(GLB(s1), LDSP(&lds[2048 + wave * 512]), 16, 0, 0);
    char* vt = (char*)lds + 16384;
#pragma unroll
    for (int e = 0; e < 8; ++e)
      *(unsigned int*)(vt + vby[e]) =
          (unsigned int)(unsigned short)vr0[e] |
          ((unsigned int)(unsigned short)vr1[e] << 16);
  }
  __syncthreads();

  const int nit = Lk / 64;  // 64 kv rows per iteration (32 per parity)
  int cb = 0;
  for (int it = 0; it < nit; ++it) {
    const bool pf = (it + 1 < nit);
    if (pf) {  // issue next-iteration loads early
      const unsigned short* v0 = Vbase + (size_t)((it + 1) * 64 + 2 * kvp) * D + db * 8;
      vr0 = *(const short8*)v0;
      vr1 = *(const short8*)(v0 + D);
      const int nb = cb ^ 1;
      const unsigned short* s0 = Kbase + (size_t)((it + 1) * 64 + kr0) * D + kch0 * 8;
      const unsigned short* s1 = Kbase + (size_t)((it + 1) * 64 + kr0 + 32) * D + kch1 * 8;
      __builtin_amdgcn_global_load_lds(GLB(s0), LDSP(&lds[nb * 4096 + wave * 512]), 16, 0, 0);
      __builtin_amdgcn_global_load_lds(GLB(s1), LDSP(&lds[nb * 4096 + 2048 + wave * 512]), 16, 0, 0);
    }

    // ---- S^T = K_p · Q^T  (32 kv x 32 q) ----
    f32x16 sa = {};
    {
      const unsigned short* K0 = &lds[cb * 4096];
#pragma unroll
      for (int ks = 0; ks < 4; ++ks) {
        int lo = ks * 32 + hi * 16;
        short8 a0 = *(const short8*)&K0[krow + ((lo ^ swzp) >> 1)];
        sa = __builtin_amdgcn_mfma_f32_32x32x16_bf16(a0, qf[ks], sa, 0, 0, 0);
      }
    }

    // ---- online softmax: tree max + permlane; defer-max rescale ----
    float pm = fmaxf(fmaxf(fmaxf(sa[0], sa[1]), fmaxf(sa[2], sa[3])),
                     fmaxf(fmaxf(sa[4], sa[5]), fmaxf(sa[6], sa[7])));
    pm = fmaxf(pm, fmaxf(fmaxf(fmaxf(sa[8], sa[9]), fmaxf(sa[10], sa[11])),
                         fmaxf(fmaxf(sa[12], sa[13]), fmaxf(sa[14], sa[15]))));
    {
      unsigned int ua = __builtin_bit_cast(unsigned int, pm), ub = ua;
      vpsw(ua, ub);
      pm = fmaxf(__builtin_bit_cast(float, ua), __builtin_bit_cast(float, ub));
    }
    if (__any((pm - m_run) * c1 > 8.0f)) {
      float mnew = fmaxf(m_run, pm);
      float alpha = exp2f((m_run - mnew) * c1);
      lacc[0] *= alpha;
#pragma unroll
      for (int i = 0; i < 16; ++i) { o0[i] *= alpha; o1[i] *= alpha; }
      m_run = mnew;
    }
    float mc = m_run * c1;
#pragma unroll
    for (int i = 0; i < 16; ++i) sa[i] = exp2f(sa[i] * c1 - mc);

    // ---- P^T B-fragments via permlane32_swap ----
    short8 pbf[2];
#pragma unroll
    for (int kb = 0; kb < 2; ++kb) {
      int bb = kb * 8;
      unsigned int u0 = pk2(sa[bb + 0], sa[bb + 1]), u1 = pk2(sa[bb + 2], sa[bb + 3]);
      unsigned int u2 = pk2(sa[bb + 4], sa[bb + 5]), u3 = pk2(sa[bb + 6], sa[bb + 7]);
      vpsw(u0, u2);
      vpsw(u1, u3);
      union { unsigned int u[4]; short8 s; } fr;
      fr.u[0] = u0; fr.u[1] = u1; fr.u[2] = u2; fr.u[3] = u3;
      pbf[kb] = fr.s;
    }

    // ---- write prefetched V (transposed+swizzled) into next ibuf ----
    if (pf) {
      char* vt = (char*)lds + 16384 + (cb ^ 1) * 8192;
#pragma unroll
      for (int e = 0; e < 8; ++e)
        *(unsigned int*)(vt + vby[e]) =
            (unsigned int)(unsigned short)vr0[e] |
            ((unsigned int)(unsigned short)vr1[e] << 16);
    }

    // ---- O^T += V^T · P^T ; row-sum via ones-MFMA (lacc[0] = l_run) ----
    {
      const unsigned short* V0 = &lds[8192 + cb * 4096];
#pragma unroll
      for (int kb = 0; kb < 2; ++kb) {
        int lo2 = (p * 2 + kb) * 32 + hi * 16;  // this wave's kv chunks
        short8 vf0 = *(const short8*)&V0[lq * 64 + ((lo2 ^ swz0) >> 1)];
        short8 vf1 = *(const short8*)&V0[(32 + lq) * 64 + ((lo2 ^ swz1) >> 1)];
        o0 = __builtin_amdgcn_mfma_f32_32x32x16_bf16(vf0, pbf[kb], o0, 0, 0, 0);
        o1 = __builtin_amdgcn_mfma_f32_32x32x16_bf16(vf1, pbf[kb], o1, 0, 0, 0);
        lacc = __builtin_amdgcn_mfma_f32_32x32x16_bf16(ones, pbf[kb], lacc, 0, 0, 0);
      }
    }

    __syncthreads();
    cb ^= 1;
  }

  // ---- merge wave-pair (p=0 <-> p=1, same qh) via LDS, then store ----
  const float m_own = m_run, l_own = lacc[0];
  float* ex = (float*)lds;
  if (p == 1) {
    ex[qh * 64 + lane] = m_own;
    ex[128 + qh * 64 + lane] = l_own;
    float* ob = ex + 256 + qh * 2048;
#pragma unroll
    for (int t = 0; t < 16; ++t) {
      ob[t * 64 + lane] = o0[t];
      ob[(16 + t) * 64 + lane] = o1[t];
    }
  }
  __syncthreads();
  if (p == 0) {
    float m1v = ex[qh * 64 + lane];
    float l1v = ex[128 + qh * 64 + lane];
    float mM = fmaxf(m_own, m1v);
    float a0s = exp2f((m_own - mM) * c1);
    float a1s = exp2f((m1v - mM) * c1);
    float rl = 1.0f / (a0s * l_own + a1s * l1v);
    const float* ob = ex + 256 + qh * 2048;
#pragma unroll
    for (int t = 0; t < 16; ++t) {
      o0[t] = (a0s * o0[t] + a1s * ob[t * 64 + lane]) * rl;
      o1[t] = (a0s * o1[t] + a1s * ob[(16 + t) * 64 + lane]) * rl;
    }

    // bounce through LDS (disjoint region, bytes 17408+), coalesced store
    unsigned short* os = (unsigned short*)lds + 8704 + qh * 2048;
#pragma unroll
    for (int t = 0; t < 2; ++t) {
#pragma unroll
      for (int c = 0; c < 4; ++c) {
        int dbase = 32 * t + 8 * c + 4 * hi;
        float v0 = (t ? o1[4 * c + 0] : o0[4 * c + 0]);
        float v1 = (t ? o1[4 * c + 1] : o0[4 * c + 1]);
        float v2 = (t ? o1[4 * c + 2] : o0[4 * c + 2]);
        float v3 = (t ? o1[4 * c + 3] : o0[4 * c + 3]);
        int by0 = lq * 128 + ((dbase * 2) ^ ((lq & 7) << 4));
        int by1 = lq * 128 + (((dbase + 2) * 2) ^ ((lq & 7) << 4));
        *(unsigned int*)((char*)os + by0) = pk2(v0, v1);
        *(unsigned int*)((char*)os + by1) = pk2(v2, v3);
      }
    }
    int q2 = lane >> 1;
    unsigned short* orow =
        O + ((size_t)b * Lq + qt * 64 + qh * 32 + q2) * D + h * 64;
#pragma unroll
    for (int j = 0; j < 4; ++j) {
      int j2 = (lane & 1) * 4 + j;
      int byr = q2 * 128 + ((j2 * 16) ^ ((q2 & 7) << 4));
      short8 vv = *(const short8*)((char*)os + byr);
      *(short8*)(orow + j2 * 8) = vv;
    }
  }
}

// ---------------------------------------------------------------------------
// Host orchestration
// ---------------------------------------------------------------------------
extern "C" void kernel_launch(void* const* d_in, const int* in_sizes, int n_in,
                              void* d_out, int out_size, void* d_ws, size_t ws_size,
                              hipStream_t stream) {
  (void)in_sizes; (void)n_in; (void)out_size; (void)ws_size;
  const float* x_in = (const float*)d_in[0];
  const float* te   = (const float*)d_in[1];
  const float* ctx  = (const float*)d_in[2];
  const float* rope = (const float*)d_in[3];
  const float* wmod = (const float*)d_in[4];
  const float* bmod = (const float*)d_in[5];
  const float* wqs  = (const float*)d_in[6];
  const float* wks  = (const float*)d_in[7];
  const float* wvs  = (const float*)d_in[8];
  const float* wos  = (const float*)d_in[9];
  const float* bos  = (const float*)d_in[10];
  const float* wqc  = (const float*)d_in[11];
  const float* wkc  = (const float*)d_in[12];
  const float* wvc  = (const float*)d_in[13];
  const float* woc  = (const float*)d_in[14];
  const float* boc  = (const float*)d_in[15];
  const float* w1   = (const float*)d_in[16];
  const float* b1   = (const float*)d_in[17];
  const float* w2   = (const float*)d_in[18];
  const float* b2   = (const float*)d_in[19];
  float* out = (float*)d_out;

  char* w = (char*)d_ws;
  size_t o = 0;
  auto alloc = [&](size_t bytes) {
    char* p = w + o;
    o = (o + bytes + 255) & ~(size_t)255;
    return p;
  };
  unsigned short* wmodT = (unsigned short*)alloc(6144ull * 1024 * 2);
  // wqsT/wksT/wvsT adjacent (fused QKV); wkcT/wvcT adjacent (fused cross-KV).
  unsigned short* wqsT  = (unsigned short*)alloc(1024ull * 1024 * 2);
  unsigned short* wksT  = (unsigned short*)alloc(1024ull * 1024 * 2);
  unsigned short* wvsT  = (unsigned short*)alloc(1024ull * 1024 * 2);
  unsigned short* wosT  = (unsigned short*)alloc(1024ull * 1024 * 2);
  unsigned short* wqcT  = (unsigned short*)alloc(1024ull * 1024 * 2);
  unsigned short* wkcT  = (unsigned short*)alloc(1024ull * 1024 * 2);
  unsigned short* wvcT  = (unsigned short*)alloc(1024ull * 1024 * 2);
  unsigned short* wocT  = (unsigned short*)alloc(1024ull * 1024 * 2);
  unsigned short* w1T   = (unsigned short*)alloc(4096ull * 1024 * 2);
  unsigned short* w2T   = (unsigned short*)alloc(1024ull * 4096 * 2);
  float* modsb = (float*)alloc(2ull * 6144 * 4);
  float* cosT  = (float*)alloc(2048ull * 64 * 4);
  float* sinT  = (float*)alloc(2048ull * 64 * 4);
  unsigned short* nx   = (unsigned short*)alloc(4096ull * 1024 * 2);
  unsigned short* ctxb = (unsigned short*)alloc(1024ull * 1024 * 2);
  // qb/kb/vb adjacent: EPI3 buffer stride = 4096*1024 elems.
  unsigned short* qb = (unsigned short*)alloc(4096ull * 1024 * 2);
  unsigned short* kb = (unsigned short*)alloc(4096ull * 1024 * 2);
  unsigned short* vb = (unsigned short*)alloc(4096ull * 1024 * 2);
  unsigned short* ao = (unsigned short*)alloc(4096ull * 1024 * 2);
  float* xw = (float*)alloc(4096ull * 1024 * 4);
  unsigned short* hbuf = qb;  // reuse qb..ao contiguous 32MB for MLP hidden

  const float c1 = 0.125f * 1.4426950408889634f;  // scale * log2(e)

  dim3 tb(32, 8);
  transpose_cast<<<dim3(6144 / 32, 1024 / 32), tb, 0, stream>>>(wmod, wmodT, 1024, 6144);
  transpose_cast<<<dim3(32, 32), tb, 0, stream>>>(wqs, wqsT, 1024, 1024);
  transpose_cast<<<dim3(32, 32), tb, 0, stream>>>(wks, wksT, 1024, 1024);
  transpose_cast<<<dim3(32, 32), tb, 0, stream>>>(wvs, wvsT, 1024, 1024);
  transpose_cast<<<dim3(32, 32), tb, 0, stream>>>(wos, wosT, 1024, 1024);
  transpose_cast<<<dim3(32, 32), tb, 0, stream>>>(wqc, wqcT, 1024, 1024);
  transpose_cast<<<dim3(32, 32), tb, 0, stream>>>(wkc, wkcT, 1024, 1024);
  transpose_cast<<<dim3(32, 32), tb, 0, stream>>>(wvc, wvcT, 1024, 1024);
  transpose_cast<<<dim3(32, 32), tb, 0, stream>>>(woc, wocT, 1024, 1024);
  transpose_cast<<<dim3(4096 / 32, 1024 / 32), tb, 0, stream>>>(w1, w1T, 1024, 4096);
  transpose_cast<<<dim3(1024 / 32, 4096 / 32), tb, 0, stream>>>(w2, w2T, 4096, 1024);

  cast_bf16<<<4096, 256, 0, stream>>>(ctx, ctxb, 1024 * 1024);
  rope_tab<<<512, 256, 0, stream>>>(rope, cosT, sinT, 2048 * 64);
  mods_kernel<<<3072, 256, 0, stream>>>(te, wmodT, bmod, modsb);

  // --- self-attention ---
  ln_mod<<<4096, 256, 0, stream>>>(x_in, modsb, nx, 1024, 0);
  gemm_pipe<3><<<768, 256, 0, stream>>>(nx, wqsT, qb, nullptr, nullptr, -1, nullptr, 4096, 3072, 1024, 2048, 2);
  rope_apply<<<dim3(8192, 2), 256, 0, stream>>>(qb, kb, cosT, sinT);
  flash3<<<1024, 256, 0, stream>>>(qb, kb, vb, ao, 2048, c1);
  gemm_p2<2><<<512, 256, 0, stream>>>(ao, wosT, xw, bos, modsb, 2048, x_in, 4096, 1024, 1024, 2048, 8);

  // --- cross-attention ---
  ln_mod<<<4096, 256, 0, stream>>>(xw, modsb, nx, -1, -1);
  gemm_p2<0><<<512, 256, 0, stream>>>(nx, wqcT, qb, nullptr, nullptr, -1, nullptr, 4096, 1024, 1024, 2048, 8);
  gemm_p2<3><<<256, 256, 0, stream>>>(ctxb, wkcT, kb, nullptr, nullptr, -1, nullptr, 1024, 2048, 1024, 512, 16);
  flash3<<<1024, 256, 0, stream>>>(qb, kb, vb, ao, 512, c1);
  gemm_p2<2><<<512, 256, 0, stream>>>(ao, wocT, xw, boc, modsb, -1, xw, 4096, 1024, 1024, 2048, 8);

  // --- MLP ---
  ln_mod<<<4096, 256, 0, stream>>>(xw, modsb, nx, 4096, 3072);
  gemm_bt<1><<<dim3(32, 32), 256, 0, stream>>>(nx, w1T, hbuf, b1, nullptr, -1, nullptr, 4096, 4096, 1024, 2048);
  gemm_p2<2><<<512, 256, 0, stream>>>(hbuf, w2T, out, b2, modsb, 5120, xw, 4096, 1024, 4096, 2048, 8);
}

// Round 3
// 420.812 us; speedup vs baseline: 1.0397x; 1.0347x over previous
//
#include <hip/hip_runtime.h>
#include <hip/hip_bf16.h>

// ---------------------------------------------------------------------------
// CleanDITBlock: adaLN-modulated DiT block (self-attn w/ RoPE, cross-attn, MLP)
// B=2, L=2048, S=512, D=1024, H=16, HD=64, CTX=1024, HID=4096
// ---------------------------------------------------------------------------

typedef short short8 __attribute__((ext_vector_type(8)));
typedef float f32x4 __attribute__((ext_vector_type(4)));
typedef float f32x16 __attribute__((ext_vector_type(16)));

#define DEV __device__ __forceinline__

DEV unsigned short f2b(float f) {
  __hip_bfloat16 h = __float2bfloat16(f);
  return *reinterpret_cast<unsigned short*>(&h);
}
DEV float b2f(unsigned short u) {
  unsigned int x = ((unsigned int)u) << 16;
  return __builtin_bit_cast(float, x);
}
// single-instruction packed f32->bf16 pair (T12): D[15:0]=bf16(lo), D[31:16]=bf16(hi)
DEV unsigned int pk2(float lo, float hi) {
  unsigned int r;
  asm("v_cvt_pk_bf16_f32 %0, %1, %2" : "=v"(r) : "v"(lo), "v"(hi));
  return r;
}
// lane[i]<->lane[i+32] half-swap (VALU, no LDS)
DEV void vpsw(unsigned int& a, unsigned int& b) {
  asm("v_permlane32_swap_b32 %0, %1" : "+v"(a), "+v"(b));
}

#define GLB(p) ((const __attribute__((address_space(1))) void*)(p))
#define LDSP(p) ((__attribute__((address_space(3))) void*)(p))

// ---------------------------------------------------------------------------
__global__ __launch_bounds__(256) void transpose_cast(
    const float* __restrict__ in, unsigned short* __restrict__ out, int R, int C,
    float scale) {
  __shared__ float tile[32][33];
  int bx = blockIdx.x * 32, by = blockIdx.y * 32;
  int tx = threadIdx.x, ty = threadIdx.y;  // 32 x 8
#pragma unroll
  for (int i = ty; i < 32; i += 8)
    tile[i][tx] = in[(size_t)(by + i) * C + bx + tx];
  __syncthreads();
#pragma unroll
  for (int i = ty; i < 32; i += 8)
    out[(size_t)(bx + i) * R + by + tx] = f2b(tile[tx][i] * scale);
}

__global__ __launch_bounds__(256) void cast_bf16(
    const float* __restrict__ in, unsigned short* __restrict__ out, int n) {
  int i = blockIdx.x * 256 + threadIdx.x;
  if (i < n) out[i] = f2b(in[i]);
}

__global__ __launch_bounds__(256) void rope_tab(
    const float* __restrict__ rope, float* __restrict__ cosT, float* __restrict__ sinT, int n) {
  int i = blockIdx.x * 256 + threadIdx.x;
  if (i < n) {
    float v = rope[i];
    cosT[i] = cosf(v);
    sinT[i] = sinf(v);
  }
}

// ---------------------------------------------------------------------------
__global__ __launch_bounds__(256) void mods_kernel(
    const float* __restrict__ te, const unsigned short* __restrict__ wmodT,
    const float* __restrict__ bmod, float* __restrict__ mods) {
  int w = blockIdx.x * 4 + (threadIdx.x >> 6);
  int lane = threadIdx.x & 63;
  int b = w / 6144, j = w % 6144;
  const unsigned short* wr = wmodT + (size_t)j * 1024;
  const float* ter = te + (size_t)b * 1024;
  int k0 = lane * 16;
  float sum = 0.f;
#pragma unroll
  for (int u = 0; u < 2; ++u) {
    short8 wv = *(const short8*)(wr + k0 + u * 8);
#pragma unroll
    for (int e = 0; e < 8; ++e)
      sum += b2f((unsigned short)wv[e]) * ter[k0 + u * 8 + e];
  }
#pragma unroll
  for (int off = 32; off >= 1; off >>= 1) sum += __shfl_down(sum, off);
  if (lane == 0) mods[(size_t)b * 6144 + j] = sum + bmod[j];
}

// ---------------------------------------------------------------------------
__global__ __launch_bounds__(256) void ln_mod(
    const float* __restrict__ x, const float* __restrict__ mods,
    unsigned short* __restrict__ out, int scale_ofs, int shift_ofs) {
  int row = blockIdx.x;
  int b = row >> 11;
  int tid = threadIdx.x;
  const float* xr = x + (size_t)row * 1024;
  float4 v = ((const float4*)xr)[tid];
  float s = v.x + v.y + v.z + v.w;
  float ss = v.x * v.x + v.y * v.y + v.z * v.z + v.w * v.w;
#pragma unroll
  for (int off = 32; off >= 1; off >>= 1) {
    s += __shfl_down(s, off);
    ss += __shfl_down(ss, off);
  }
  __shared__ float red[8];
  int wave = tid >> 6, lane = tid & 63;
  if (lane == 0) { red[wave] = s; red[4 + wave] = ss; }
  __syncthreads();
  if (tid == 0) {
    float S = red[0] + red[1] + red[2] + red[3];
    float SS = red[4] + red[5] + red[6] + red[7];
    float mu = S * (1.f / 1024.f);
    red[0] = mu;
    red[1] = SS * (1.f / 1024.f) - mu * mu;
  }
  __syncthreads();
  float mu = red[0];
  float rs = rsqrtf(red[1] + 1e-6f);
  float vv[4] = {v.x, v.y, v.z, v.w};
  unsigned short o[4];
#pragma unroll
  for (int c = 0; c < 4; ++c) {
    int col = tid * 4 + c;
    float nv = (vv[c] - mu) * rs;
    if (scale_ofs >= 0)
      nv = nv * (1.f + mods[(size_t)b * 6144 + scale_ofs + col]) +
           mods[(size_t)b * 6144 + shift_ofs + col];
    o[c] = f2b(nv);
  }
  *(ushort4*)(&out[(size_t)row * 1024 + tid * 4]) = *(const ushort4*)o;
}

// ---------------------------------------------------------------------------
__global__ __launch_bounds__(256) void rope_apply(
    unsigned short* __restrict__ qb, unsigned short* __restrict__ kb,
    const float* __restrict__ cosT, const float* __restrict__ sinT) {
  int idx = blockIdx.x * 256 + threadIdx.x;  // over [4096][16][32]
  unsigned short* buf = blockIdx.y ? kb : qb;
  int row = idx >> 9;
  int rem = idx & 511;
  int h = rem >> 5, d = rem & 31;
  int l = row & 2047;
  size_t base = (size_t)row * 1024 + h * 64 + d;
  float x1 = b2f(buf[base]), x2 = b2f(buf[base + 32]);
  float c1 = cosT[l * 64 + d], s1 = sinT[l * 64 + d];
  float c2 = cosT[l * 64 + d + 32], s2 = sinT[l * 64 + d + 32];
  buf[base] = f2b(x1 * c1 - x2 * s1);
  buf[base + 32] = f2b(x2 * c2 + x1 * s2);
}

// ---------------------------------------------------------------------------
// Shared GEMM epilogue.  EPI: 0 bf16; 1 bias+GELU bf16; 2 f32 residual
// src + gate*(acc+bias); 3 bf16 split-store (buffer = col>>10, row stride 1024,
// buffer stride 4096*1024).
// ---------------------------------------------------------------------------
template <int EPI, int MI, int NJ>
DEV void gemm_epilogue(f32x4 (&acc)[MI][NJ], void* Cout, const float* bias,
                       const float* mods, int gate_ofs, const float* src,
                       int N, int rowsPerB, int m0, int n0, int wm, int wn,
                       int g, int r) {
#pragma unroll
  for (int i = 0; i < MI; ++i) {
#pragma unroll
    for (int j = 0; j < NJ; ++j) {
#pragma unroll
      for (int q = 0; q < 4; ++q) {
        size_t grow = (size_t)(m0 + wm + i * 16 + g * 4 + q);
        size_t gcol = (size_t)(n0 + wn + j * 16 + r);
        float v = acc[i][j][q];
        if constexpr (EPI == 0) {
          ((unsigned short*)Cout)[grow * N + gcol] = f2b(v);
        } else if constexpr (EPI == 1) {
          v += bias[gcol];
          float ge = 0.5f * v * (1.0f + erff(v * 0.70710678f));
          ((unsigned short*)Cout)[grow * N + gcol] = f2b(ge);
        } else if constexpr (EPI == 3) {
          size_t buf = gcol >> 10;
          ((unsigned short*)Cout)[buf * (4096ull * 1024) + grow * 1024 + (gcol & 1023)] = f2b(v);
        } else {
          v += bias[gcol];
          float gate = 1.0f;
          if (gate_ofs >= 0)
            gate = mods[(grow / rowsPerB) * 6144 + gate_ofs + gcol];
          ((float*)Cout)[grow * N + gcol] = src[grow * N + gcol] + gate * v;
        }
      }
    }
  }
}

// ---------------------------------------------------------------------------
// GEMM (m97): 128x128, BK=32, implicit overlap.  For >=4 blocks/CU (mlp1).
// ---------------------------------------------------------------------------
template <int EPI>
__global__ __launch_bounds__(256, 2) void gemm_bt(
    const unsigned short* __restrict__ A, const unsigned short* __restrict__ Bt,
    void* __restrict__ Cout, const float* __restrict__ bias,
    const float* __restrict__ mods, int gate_ofs, const float* __restrict__ src,
    int M, int N, int K, int rowsPerB) {
  __shared__ unsigned short As[128 * 32];
  __shared__ unsigned short Bs[128 * 32];
  const int tid = threadIdx.x;
  const int wave = tid >> 6, lane = tid & 63;
  const int g = lane >> 4, r = lane & 15;
  const int m0 = blockIdx.y * 128, n0 = blockIdx.x * 128;
  const int wm = (wave >> 1) * 64, wn = (wave & 1) * 64;
  const int srow = lane >> 2;
  const int scol = (lane & 3) * 8;

  f32x4 acc[4][4] = {};

  for (int k0 = 0; k0 < K; k0 += 32) {
    __syncthreads();
#pragma unroll
    for (int cc = 0; cc < 4; ++cc) {
      int c = wave * 4 + cc;
      int isB = c >> 3;
      int cl = c & 7;
      int row = cl * 16 + srow;
      const unsigned short* gsrc =
          isB ? (Bt + (size_t)(n0 + row) * K + k0 + scol)
              : (A + (size_t)(m0 + row) * K + k0 + scol);
      unsigned short* ldst = (isB ? Bs : As) + cl * 512;
      __builtin_amdgcn_global_load_lds(GLB(gsrc), LDSP(ldst), 16, 0, 0);
    }
    __syncthreads();

    short8 bfr[4];
#pragma unroll
    for (int j = 0; j < 4; ++j)
      bfr[j] = *(const short8*)(&Bs[(wn + j * 16 + r) * 32 + g * 8]);
#pragma unroll
    for (int i = 0; i < 4; ++i) {
      short8 af = *(const short8*)(&As[(wm + i * 16 + r) * 32 + g * 8]);
#pragma unroll
      for (int j = 0; j < 4; ++j)
        acc[i][j] = __builtin_amdgcn_mfma_f32_16x16x32_bf16(af, bfr[j], acc[i][j], 0, 0, 0);
    }
  }
  gemm_epilogue<EPI, 4, 4>(acc, Cout, bias, mods, gate_ofs, src, N, rowsPerB,
                           m0, n0, wm, wn, g, r);
}

// ---------------------------------------------------------------------------
// GEMM (pipelined 128x128): BK=64, 4 LDS bufs, depth-3, counted vmcnt.
// For ~3 blocks/CU grids (QKV).  XCD-grouped decode via mshift.
// ---------------------------------------------------------------------------
template <int EPI>
__global__ __launch_bounds__(256) void gemm_pipe(
    const unsigned short* __restrict__ A, const unsigned short* __restrict__ Bt,
    void* __restrict__ Cout, const float* __restrict__ bias,
    const float* __restrict__ mods, int gate_ofs, const float* __restrict__ src,
    int M, int N, int K, int rowsPerB, int mshift) {
  __shared__ unsigned short lds[4 * 16384];
  const int tid = threadIdx.x;
  const int wave = tid >> 6, lane = tid & 63;
  const int g = lane >> 4, r = lane & 15;
  const int flat = blockIdx.x;
  const int xcd = flat & 7, idx = flat >> 3;
  const int mt = xcd * (1 << mshift) + (idx & ((1 << mshift) - 1));
  const int nt = idx >> mshift;
  const int m0 = mt * 128, n0 = nt * 128;
  const int wm = (wave >> 1) * 64, wn = (wave & 1) * 64;
  const int srow8 = lane >> 3;
  const int sck = (lane & 7) ^ srow8;

  f32x4 acc[4][4] = {};

  auto stage = [&](int t, int bufi) {
    const int k0 = t * 64;
#pragma unroll
    for (int i = 0; i < 8; ++i) {
      int u = wave * 8 + i;
      int isB = u >> 4;
      int uu = u & 15;
      int rl = uu * 8 + srow8;
      const unsigned short* gsrc =
          (isB ? (Bt + (size_t)(n0 + rl) * K) : (A + (size_t)(m0 + rl) * K)) +
          k0 + sck * 8;
      unsigned short* dst = (unsigned short*)lds + bufi * 16384 + isB * 8192 + uu * 512;
      __builtin_amdgcn_global_load_lds(GLB(gsrc), LDSP(dst), 16, 0, 0);
    }
  };

  const int nt_k = K / 64;
  stage(0, 0);
  stage(1, 1);
  stage(2, 2);

  for (int t = 0; t < nt_k; ++t) {
    int rem = nt_k - t;
    if (rem >= 3) {
      asm volatile("s_waitcnt vmcnt(16)" ::: "memory");
    } else if (rem == 2) {
      asm volatile("s_waitcnt vmcnt(8)" ::: "memory");
    } else {
      asm volatile("s_waitcnt vmcnt(0)" ::: "memory");
    }
    __builtin_amdgcn_sched_barrier(0);
    __builtin_amdgcn_s_barrier();
    __builtin_amdgcn_sched_barrier(0);
    if (t + 3 < nt_k) stage(t + 3, (t + 3) & 3);

    const unsigned short* Ab = (const unsigned short*)lds + (t & 3) * 16384;
    const unsigned short* Bb = Ab + 8192;
#pragma unroll
    for (int ks = 0; ks < 2; ++ks) {
      short8 bfr[4];
#pragma unroll
      for (int j = 0; j < 4; ++j) {
        int row = wn + j * 16 + r;
        bfr[j] = *(const short8*)&Bb[row * 64 + ((g + ks * 4) ^ (r & 7)) * 8];
      }
#pragma unroll
      for (int i = 0; i < 4; ++i) {
        int row = wm + i * 16 + r;
        short8 af = *(const short8*)&Ab[row * 64 + ((g + ks * 4) ^ (r & 7)) * 8];
#pragma unroll
        for (int j = 0; j < 4; ++j)
          acc[i][j] = __builtin_amdgcn_mfma_f32_16x16x32_bf16(af, bfr[j], acc[i][j], 0, 0, 0);
      }
    }
  }
  gemm_epilogue<EPI, 4, 4>(acc, Cout, bias, mods, gate_ofs, src, N, rowsPerB,
                           m0, n0, wm, wn, g, r);
}

// ---------------------------------------------------------------------------
// GEMM (64x128 tile, 2-blocks/CU): 4 waves of 32x64, BK=64, 3 LDS bufs (72KB),
// depth-2 counted vmcnt(6).  Grid = (M/64)*(N/128); nt = flat % ntn puts one
// B-panel per XCD when ntn==8.  For the grid-256-at-128x128 GEMMs.
// ---------------------------------------------------------------------------
template <int EPI>
__global__ __launch_bounds__(256) void gemm_p2(
    const unsigned short* __restrict__ A, const unsigned short* __restrict__ Bt,
    void* __restrict__ Cout, const float* __restrict__ bias,
    const float* __restrict__ mods, int gate_ofs, const float* __restrict__ src,
    int M, int N, int K, int rowsPerB, int ntn) {
  __shared__ unsigned short lds[3 * 12288];  // per buf: A 64x64 (8KB) | B 128x64 (16KB)
  const int tid = threadIdx.x;
  const int wave = tid >> 6, lane = tid & 63;
  const int g = lane >> 4, r = lane & 15;
  const int flat = blockIdx.x;
  const int nt = flat % ntn, mt = flat / ntn;
  const int m0 = mt * 64, n0 = nt * 128;
  const int wm = (wave >> 1) * 32, wn = (wave & 1) * 64;
  const int srow8 = lane >> 3;
  const int sck = (lane & 7) ^ srow8;

  f32x4 acc[2][4] = {};

  auto stage = [&](int t, int bufi) {
    const int k0 = t * 64;
    unsigned short* base = (unsigned short*)lds + bufi * 12288;
#pragma unroll
    for (int i = 0; i < 2; ++i) {  // A units: 8 of 64 rows
      int u = wave * 2 + i;
      int rl = u * 8 + srow8;
      const unsigned short* gsrc = A + (size_t)(m0 + rl) * K + k0 + sck * 8;
      __builtin_amdgcn_global_load_lds(GLB(gsrc), LDSP(base + u * 512), 16, 0, 0);
    }
#pragma unroll
    for (int i = 0; i < 4; ++i) {  // B units: 16 of 128 rows
      int u = wave * 4 + i;
      int rl = u * 8 + srow8;
      const unsigned short* gsrc = Bt + (size_t)(n0 + rl) * K + k0 + sck * 8;
      __builtin_amdgcn_global_load_lds(GLB(gsrc), LDSP(base + 4096 + u * 512), 16, 0, 0);
    }
  };

  const int ntk = K / 64;
  stage(0, 0);
  stage(1, 1);
  int cbuf = 0, sbuf = 2;

  for (int t = 0; t < ntk; ++t) {
    if (t < ntk - 1) {
      asm volatile("s_waitcnt vmcnt(6)" ::: "memory");
    } else {
      asm volatile("s_waitcnt vmcnt(0)" ::: "memory");
    }
    __builtin_amdgcn_sched_barrier(0);
    __builtin_amdgcn_s_barrier();
    __builtin_amdgcn_sched_barrier(0);
    if (t + 2 < ntk) {
      stage(t + 2, sbuf);
      sbuf = (sbuf == 2) ? 0 : sbuf + 1;
    }

    const unsigned short* Ab = (const unsigned short*)lds + cbuf * 12288;
    const unsigned short* Bb = Ab + 4096;
#pragma unroll
    for (int ks = 0; ks < 2; ++ks) {
      short8 bfr[4];
#pragma unroll
      for (int j = 0; j < 4; ++j) {
        int row = wn + j * 16 + r;
        bfr[j] = *(const short8*)&Bb[row * 64 + ((g + ks * 4) ^ (r & 7)) * 8];
      }
#pragma unroll
      for (int i = 0; i < 2; ++i) {
        int row = wm + i * 16 + r;
        short8 af = *(const short8*)&Ab[row * 64 + ((g + ks * 4) ^ (r & 7)) * 8];
#pragma unroll
        for (int j = 0; j < 4; ++j)
          acc[i][j] = __builtin_amdgcn_mfma_f32_16x16x32_bf16(af, bfr[j], acc[i][j], 0, 0, 0);
      }
    }
    cbuf = (cbuf == 2) ? 0 : cbuf + 1;
  }
  gemm_epilogue<EPI, 2, 4>(acc, Cout, bias, mods, gate_ofs, src, N, rowsPerB,
                           m0, n0, wm, wn, g, r);
}

// ---------------------------------------------------------------------------
// Flash attention v7: v4 structure (128 q/block, 4 waves, KVBLK=64, proven
// 86 µs / 213K conflicts) + VALU cuts:
//   - pk2 -> single v_cvt_pk_bf16_f32 (was ~10 insts of software RNE per pair)
//   - softmax scale folded into weights (wqs*=c1 self / wkc*=c1 cross), so
//     the exp path is exp2(sa - m) with no per-element fma and no c1 anywhere
//   - s_setprio(1) around QK and PV MFMA clusters (T5: +4-7% attn, m191)
// Occupancy experiments (r1/r2) proved occupancy is NOT the limit; per-element
// VALU work is.  This keeps the best-known structure and cuts that work.
// ---------------------------------------------------------------------------
__global__ __launch_bounds__(256, 2) void flash2(
    const unsigned short* __restrict__ Q, const unsigned short* __restrict__ Kv,
    const unsigned short* __restrict__ Vv, unsigned short* __restrict__ O,
    int Lk) {
  __shared__ unsigned short lds[16384];
  const int tid = threadIdx.x, wave = tid >> 6, lane = tid & 63;
  const int hi = lane >> 5, lq = lane & 31;
  const int flat = blockIdx.x;
  const int xcd = flat & 7, rr = flat >> 3;
  const int gl = rr >> 4, qt = rr & 15;
  const int g = xcd * 4 + gl;
  const int h = g & 15, b = g >> 4;
  const int Lq = 2048, D = 1024;

  const unsigned short* Qbase =
      Q + ((size_t)b * Lq + qt * 128 + wave * 32 + lq) * D + h * 64;
  const unsigned short* Kbase = Kv + (size_t)b * Lk * D + h * 64;
  const unsigned short* Vbase = Vv + (size_t)b * Lk * D + h * 64;

  short8 qf[4];
#pragma unroll
  for (int kb = 0; kb < 4; ++kb)
    qf[kb] = *(const short8*)(Qbase + kb * 16 + hi * 8);

  const short8 ones = {0x3F80, 0x3F80, 0x3F80, 0x3F80, 0x3F80, 0x3F80, 0x3F80, 0x3F80};

  const int kr0 = tid >> 3, kc0 = tid & 7;   // K stage: row, chunk
  const int kvp = tid >> 3, db = tid & 7;    // V stage: kv-pair, d-block
  const int kch0 = (kc0 ^ (kr0 & 7) ^ (kr0 >> 3)) & 7;
  const int kch1 = kch0 ^ 4;
  const int f0 = (lq & 7) ^ (lq >> 3);
  const int swz0 = f0 << 4, swz1 = swz0 ^ 64;

  // kt-invariant V^T write byte-offsets (per-thread constants, reg-resident)
  int vby[8];
#pragma unroll
  for (int e = 0; e < 8; ++e) {
    int d = db * 8 + e;
    vby[e] = d * 128 + ((kvp * 4) ^ (((e ^ db) & 7) << 4));
  }

  float m_run = -3.0e38f;
  f32x16 o0 = {}, o1 = {}, lacc = {};
  short8 vr0, vr1;

  {  // prologue: stage tile 0
    const unsigned short* v0 = Vbase + (size_t)(2 * kvp) * D + db * 8;
    vr0 = *(const short8*)v0;
    vr1 = *(const short8*)(v0 + D);
    const unsigned short* s0 = Kbase + (size_t)kr0 * D + kch0 * 8;
    const unsigned short* s1 = Kbase + (size_t)(kr0 + 32) * D + kch1 * 8;
    __builtin_amdgcn_global_load_lds(GLB(s0), LDSP(&lds[wave * 512]), 16, 0, 0);
    __builtin_amdgcn_global_load_lds(GLB(s1), LDSP(&lds[2048 + wave * 512]), 16, 0, 0);
    char* vt = (char*)&lds[8192];
#pragma unroll
    for (int e = 0; e < 8; ++e)
      *(unsigned int*)(vt + vby[e]) =
          (unsigned int)(unsigned short)vr0[e] |
          ((unsigned int)(unsigned short)vr1[e] << 16);
  }
  __syncthreads();

  const int nkt = Lk / 64;
  int cb = 0;
  for (int kt = 0; kt < nkt; ++kt) {
    const bool pf = (kt + 1 < nkt);
    if (pf) {  // issue next-tile loads early
      const unsigned short* v0 = Vbase + (size_t)((kt + 1) * 64 + 2 * kvp) * D + db * 8;
      vr0 = *(const short8*)v0;
      vr1 = *(const short8*)(v0 + D);
      const int nb = (cb ^ 1) * 4096;
      const unsigned short* s0 = Kbase + (size_t)((kt + 1) * 64 + kr0) * D + kch0 * 8;
      const unsigned short* s1 = Kbase + (size_t)((kt + 1) * 64 + kr0 + 32) * D + kch1 * 8;
      __builtin_amdgcn_global_load_lds(GLB(s0), LDSP(&lds[nb + wave * 512]), 16, 0, 0);
      __builtin_amdgcn_global_load_lds(GLB(s1), LDSP(&lds[nb + 2048 + wave * 512]), 16, 0, 0);
    }

    // ---- S^T = K · Q^T ----
    f32x16 s0a = {}, s1a = {};
    {
      const unsigned short* K0 = &lds[cb * 4096];
      __builtin_amdgcn_s_setprio(1);
#pragma unroll
      for (int ks = 0; ks < 4; ++ks) {
        int lo = ks * 32 + hi * 16;
        short8 a0 = *(const short8*)&K0[lq * 64 + ((lo ^ swz0) >> 1)];
        short8 a1 = *(const short8*)&K0[(32 + lq) * 64 + ((lo ^ swz1) >> 1)];
        s0a = __builtin_amdgcn_mfma_f32_32x32x16_bf16(a0, qf[ks], s0a, 0, 0, 0);
        s1a = __builtin_amdgcn_mfma_f32_32x32x16_bf16(a1, qf[ks], s1a, 0, 0, 0);
      }
      __builtin_amdgcn_s_setprio(0);
    }

    // ---- online softmax: tree max + permlane; defer-max rescale ----
    // (scale folded into Q/K producers: sa is already in log2-domain units)
    float tm[8];
#pragma unroll
    for (int i = 0; i < 8; ++i)
      tm[i] = fmaxf(fmaxf(s0a[i], s0a[i + 8]), fmaxf(s1a[i], s1a[i + 8]));
    float pm = fmaxf(fmaxf(fmaxf(tm[0], tm[1]), fmaxf(tm[2], tm[3])),
                     fmaxf(fmaxf(tm[4], tm[5]), fmaxf(tm[6], tm[7])));
    {
      unsigned int ua = __builtin_bit_cast(unsigned int, pm), ub = ua;
      vpsw(ua, ub);
      pm = fmaxf(__builtin_bit_cast(float, ua), __builtin_bit_cast(float, ub));
    }
    if (__any(pm - m_run > 8.0f)) {
      float mnew = fmaxf(m_run, pm);
      float alpha = exp2f(m_run - mnew);
      lacc[0] *= alpha;
#pragma unroll
      for (int i = 0; i < 16; ++i) { o0[i] *= alpha; o1[i] *= alpha; }
      m_run = mnew;
    }
    float mc = m_run;
#pragma unroll
    for (int i = 0; i < 16; ++i) s0a[i] = exp2f(s0a[i] - mc);
#pragma unroll
    for (int i = 0; i < 16; ++i) s1a[i] = exp2f(s1a[i] - mc);

    // ---- P^T B-fragments via cvt_pk + permlane32_swap ----
    short8 pbf[4];
#pragma unroll
    for (int kb = 0; kb < 4; ++kb) {
      int bb = (kb & 1) * 8;
      float p0, p1, p2, p3, p4, p5, p6, p7;
      if (kb < 2) {
        p0 = s0a[bb + 0]; p1 = s0a[bb + 1]; p2 = s0a[bb + 2]; p3 = s0a[bb + 3];
        p4 = s0a[bb + 4]; p5 = s0a[bb + 5]; p6 = s0a[bb + 6]; p7 = s0a[bb + 7];
      } else {
        p0 = s1a[bb + 0]; p1 = s1a[bb + 1]; p2 = s1a[bb + 2]; p3 = s1a[bb + 3];
        p4 = s1a[bb + 4]; p5 = s1a[bb + 5]; p6 = s1a[bb + 6]; p7 = s1a[bb + 7];
      }
      unsigned int u0 = pk2(p0, p1), u1 = pk2(p2, p3);
      unsigned int u2 = pk2(p4, p5), u3 = pk2(p6, p7);
      vpsw(u0, u2);
      vpsw(u1, u3);
      union { unsigned int u[4]; short8 s; } fr;
      fr.u[0] = u0; fr.u[1] = u1; fr.u[2] = u2; fr.u[3] = u3;
      pbf[kb] = fr.s;
    }

    // ---- write prefetched V (transposed+swizzled) into next buffer ----
    if (pf) {
      char* vt = (char*)&lds[8192 + (cb ^ 1) * 4096];
#pragma unroll
      for (int e = 0; e < 8; ++e)
        *(unsigned int*)(vt + vby[e]) =
            (unsigned int)(unsigned short)vr0[e] |
            ((unsigned int)(unsigned short)vr1[e] << 16);
    }

    // ---- O^T += V^T · P^T ; row-sum via ones-MFMA (lacc[0] = l_run) ----
    {
      const unsigned short* V0 = &lds[8192 + cb * 4096];
      __builtin_amdgcn_s_setprio(1);
#pragma unroll
      for (int kb = 0; kb < 4; ++kb) {
        int lo = kb * 32 + hi * 16;
        short8 vf0 = *(const short8*)&V0[lq * 64 + ((lo ^ swz0) >> 1)];
        short8 vf1 = *(const short8*)&V0[(32 + lq) * 64 + ((lo ^ swz1) >> 1)];
        o0 = __builtin_amdgcn_mfma_f32_32x32x16_bf16(vf0, pbf[kb], o0, 0, 0, 0);
        o1 = __builtin_amdgcn_mfma_f32_32x32x16_bf16(vf1, pbf[kb], o1, 0, 0, 0);
        lacc = __builtin_amdgcn_mfma_f32_32x32x16_bf16(ones, pbf[kb], lacc, 0, 0, 0);
      }
      __builtin_amdgcn_s_setprio(0);
    }

    __syncthreads();
    cb ^= 1;
  }

  // ---- epilogue: normalize, bounce through LDS, coalesced store ----
  __syncthreads();
  float rl = 1.0f / lacc[0];
  unsigned short* os = &lds[wave * 2048];
#pragma unroll
  for (int t = 0; t < 2; ++t) {
#pragma unroll
    for (int c = 0; c < 4; ++c) {
      int dbase = 32 * t + 8 * c + 4 * hi;
      float v0 = (t ? o1[4 * c + 0] : o0[4 * c + 0]) * rl;
      float v1 = (t ? o1[4 * c + 1] : o0[4 * c + 1]) * rl;
      float v2 = (t ? o1[4 * c + 2] : o0[4 * c + 2]) * rl;
      float v3 = (t ? o1[4 * c + 3] : o0[4 * c + 3]) * rl;
      int by0 = lq * 128 + ((dbase * 2) ^ ((lq & 7) << 4));
      int by1 = lq * 128 + (((dbase + 2) * 2) ^ ((lq & 7) << 4));
      *(unsigned int*)((char*)os + by0) = pk2(v0, v1);
      *(unsigned int*)((char*)os + by1) = pk2(v2, v3);
    }
  }
  int q2 = lane >> 1;
  unsigned short* orow =
      O + ((size_t)b * Lq + qt * 128 + wave * 32 + q2) * D + h * 64;
#pragma unroll
  for (int j = 0; j < 4; ++j) {
    int j2 = (lane & 1) * 4 + j;
    int byr = q2 * 128 + ((j2 * 16) ^ ((q2 & 7) << 4));
    short8 vv = *(const short8*)((char*)os + byr);
    *(short8*)(orow + j2 * 8) = vv;
  }
}

// ---------------------------------------------------------------------------
// Host orchestration
// ---------------------------------------------------------------------------
extern "C" void kernel_launch(void* const* d_in, const int* in_sizes, int n_in,
                              void* d_out, int out_size, void* d_ws, size_t ws_size,
                              hipStream_t stream) {
  (void)in_sizes; (void)n_in; (void)out_size; (void)ws_size;
  const float* x_in = (const float*)d_in[0];
  const float* te   = (const float*)d_in[1];
  const float* ctx  = (const float*)d_in[2];
  const float* rope = (const float*)d_in[3];
  const float* wmod = (const float*)d_in[4];
  const float* bmod = (const float*)d_in[5];
  const float* wqs  = (const float*)d_in[6];
  const float* wks  = (const float*)d_in[7];
  const float* wvs  = (const float*)d_in[8];
  const float* wos  = (const float*)d_in[9];
  const float* bos  = (const float*)d_in[10];
  const float* wqc  = (const float*)d_in[11];
  const float* wkc  = (const float*)d_in[12];
  const float* wvc  = (const float*)d_in[13];
  const float* woc  = (const float*)d_in[14];
  const float* boc  = (const float*)d_in[15];
  const float* w1   = (const float*)d_in[16];
  const float* b1   = (const float*)d_in[17];
  const float* w2   = (const float*)d_in[18];
  const float* b2   = (const float*)d_in[19];
  float* out = (float*)d_out;

  char* w = (char*)d_ws;
  size_t o = 0;
  auto alloc = [&](size_t bytes) {
    char* p = w + o;
    o = (o + bytes + 255) & ~(size_t)255;
    return p;
  };
  unsigned short* wmodT = (unsigned short*)alloc(6144ull * 1024 * 2);
  // wqsT/wksT/wvsT adjacent (fused QKV); wkcT/wvcT adjacent (fused cross-KV).
  unsigned short* wqsT  = (unsigned short*)alloc(1024ull * 1024 * 2);
  unsigned short* wksT  = (unsigned short*)alloc(1024ull * 1024 * 2);
  unsigned short* wvsT  = (unsigned short*)alloc(1024ull * 1024 * 2);
  unsigned short* wosT  = (unsigned short*)alloc(1024ull * 1024 * 2);
  unsigned short* wqcT  = (unsigned short*)alloc(1024ull * 1024 * 2);
  unsigned short* wkcT  = (unsigned short*)alloc(1024ull * 1024 * 2);
  unsigned short* wvcT  = (unsigned short*)alloc(1024ull * 1024 * 2);
  unsigned short* wocT  = (unsigned short*)alloc(1024ull * 1024 * 2);
  unsigned short* w1T   = (unsigned short*)alloc(4096ull * 1024 * 2);
  unsigned short* w2T   = (unsigned short*)alloc(1024ull * 4096 * 2);
  float* modsb = (float*)alloc(2ull * 6144 * 4);
  float* cosT  = (float*)alloc(2048ull * 64 * 4);
  float* sinT  = (float*)alloc(2048ull * 64 * 4);
  unsigned short* nx   = (unsigned short*)alloc(4096ull * 1024 * 2);
  unsigned short* ctxb = (unsigned short*)alloc(1024ull * 1024 * 2);
  // qb/kb/vb adjacent: EPI3 buffer stride = 4096*1024 elems.
  unsigned short* qb = (unsigned short*)alloc(4096ull * 1024 * 2);
  unsigned short* kb = (unsigned short*)alloc(4096ull * 1024 * 2);
  unsigned short* vb = (unsigned short*)alloc(4096ull * 1024 * 2);
  unsigned short* ao = (unsigned short*)alloc(4096ull * 1024 * 2);
  float* xw = (float*)alloc(4096ull * 1024 * 4);
  unsigned short* hbuf = qb;  // reuse qb..ao contiguous 32MB for MLP hidden

  const float c1 = 0.125f * 1.4426950408889634f;  // scale * log2(e), folded into wqs/wkc

  dim3 tb(32, 8);
  transpose_cast<<<dim3(6144 / 32, 1024 / 32), tb, 0, stream>>>(wmod, wmodT, 1024, 6144, 1.0f);
  transpose_cast<<<dim3(32, 32), tb, 0, stream>>>(wqs, wqsT, 1024, 1024, c1);
  transpose_cast<<<dim3(32, 32), tb, 0, stream>>>(wks, wksT, 1024, 1024, 1.0f);
  transpose_cast<<<dim3(32, 32), tb, 0, stream>>>(wvs, wvsT, 1024, 1024, 1.0f);
  transpose_cast<<<dim3(32, 32), tb, 0, stream>>>(wos, wosT, 1024, 1024, 1.0f);
  transpose_cast<<<dim3(32, 32), tb, 0, stream>>>(wqc, wqcT, 1024, 1024, 1.0f);
  transpose_cast<<<dim3(32, 32), tb, 0, stream>>>(wkc, wkcT, 1024, 1024, c1);
  transpose_cast<<<dim3(32, 32), tb, 0, stream>>>(wvc, wvcT, 1024, 1024, 1.0f);
  transpose_cast<<<dim3(32, 32), tb, 0, stream>>>(woc, wocT, 1024, 1024, 1.0f);
  transpose_cast<<<dim3(4096 / 32, 1024 / 32), tb, 0, stream>>>(w1, w1T, 1024, 4096, 1.0f);
  transpose_cast<<<dim3(1024 / 32, 4096 / 32), tb, 0, stream>>>(w2, w2T, 4096, 1024, 1.0f);

  cast_bf16<<<4096, 256, 0, stream>>>(ctx, ctxb, 1024 * 1024);
  rope_tab<<<512, 256, 0, stream>>>(rope, cosT, sinT, 2048 * 64);
  mods_kernel<<<3072, 256, 0, stream>>>(te, wmodT, bmod, modsb);

  // --- self-attention ---
  ln_mod<<<4096, 256, 0, stream>>>(x_in, modsb, nx, 1024, 0);
  gemm_pipe<3><<<768, 256, 0, stream>>>(nx, wqsT, qb, nullptr, nullptr, -1, nullptr, 4096, 3072, 1024, 2048, 2);
  rope_apply<<<dim3(8192, 2), 256, 0, stream>>>(qb, kb, cosT, sinT);
  flash2<<<512, 256, 0, stream>>>(qb, kb, vb, ao, 2048);
  gemm_p2<2><<<512, 256, 0, stream>>>(ao, wosT, xw, bos, modsb, 2048, x_in, 4096, 1024, 1024, 2048, 8);

  // --- cross-attention ---
  ln_mod<<<4096, 256, 0, stream>>>(xw, modsb, nx, -1, -1);
  gemm_p2<0><<<512, 256, 0, stream>>>(nx, wqcT, qb, nullptr, nullptr, -1, nullptr, 4096, 1024, 1024, 2048, 8);
  gemm_p2<3><<<256, 256, 0, stream>>>(ctxb, wkcT, kb, nullptr, nullptr, -1, nullptr, 1024, 2048, 1024, 512, 16);
  flash2<<<512, 256, 0, stream>>>(qb, kb, vb, ao, 512);
  gemm_p2<2><<<512, 256, 0, stream>>>(ao, wocT, xw, boc, modsb, -1, xw, 4096, 1024, 1024, 2048, 8);

  // --- MLP ---
  ln_mod<<<4096, 256, 0, stream>>>(xw, modsb, nx, 4096, 3072);
  gemm_bt<1><<<dim3(32, 32), 256, 0, stream>>>(nx, w1T, hbuf, b1, nullptr, -1, nullptr, 4096, 4096, 1024, 2048);
  gemm_p2<2><<<512, 256, 0, stream>>>(hbuf, w2T, out, b2, modsb, 5120, xw, 4096, 1024, 4096, 2048, 8);
}

// Round 4
// 409.917 us; speedup vs baseline: 1.0674x; 1.0266x over previous
//
#include <hip/hip_runtime.h>
#include <hip/hip_bf16.h>

// ---------------------------------------------------------------------------
// CleanDITBlock: adaLN-modulated DiT block (self-attn w/ RoPE, cross-attn, MLP)
// B=2, L=2048, S=512, D=1024, H=16, HD=64, CTX=1024, HID=4096
// ---------------------------------------------------------------------------

typedef short short8 __attribute__((ext_vector_type(8)));
typedef float f32x4 __attribute__((ext_vector_type(4)));
typedef float f32x16 __attribute__((ext_vector_type(16)));

#define DEV __device__ __forceinline__

DEV unsigned short f2b(float f) {
  __hip_bfloat16 h = __float2bfloat16(f);
  return *reinterpret_cast<unsigned short*>(&h);
}
DEV float b2f(unsigned short u) {
  unsigned int x = ((unsigned int)u) << 16;
  return __builtin_bit_cast(float, x);
}
// single-instruction packed f32->bf16 pair (T12): D[15:0]=bf16(lo), D[31:16]=bf16(hi)
DEV unsigned int pk2(float lo, float hi) {
  unsigned int r;
  asm("v_cvt_pk_bf16_f32 %0, %1, %2" : "=v"(r) : "v"(lo), "v"(hi));
  return r;
}
// lane[i]<->lane[i+32] half-swap (VALU, no LDS)
DEV void vpsw(unsigned int& a, unsigned int& b) {
  asm("v_permlane32_swap_b32 %0, %1" : "+v"(a), "+v"(b));
}
// 3-input max (T17)
DEV float max3f(float a, float b, float c) {
  float r;
  asm("v_max3_f32 %0, %1, %2, %3" : "=v"(r) : "v"(a), "v"(b), "v"(c));
  return r;
}

#define GLB(p) ((const __attribute__((address_space(1))) void*)(p))
#define LDSP(p) ((__attribute__((address_space(3))) void*)(p))

// ---------------------------------------------------------------------------
__global__ __launch_bounds__(256) void transpose_cast(
    const float* __restrict__ in, unsigned short* __restrict__ out, int R, int C,
    float scale) {
  __shared__ float tile[32][33];
  int bx = blockIdx.x * 32, by = blockIdx.y * 32;
  int tx = threadIdx.x, ty = threadIdx.y;  // 32 x 8
#pragma unroll
  for (int i = ty; i < 32; i += 8)
    tile[i][tx] = in[(size_t)(by + i) * C + bx + tx];
  __syncthreads();
#pragma unroll
  for (int i = ty; i < 32; i += 8)
    out[(size_t)(bx + i) * R + by + tx] = f2b(tile[tx][i] * scale);
}

// batched 1024x1024 transposes (one launch for all 8 square weights)
struct TCB { const float* in; unsigned short* out; float scale; };
struct TC8 { TCB m[8]; };
__global__ __launch_bounds__(256) void transpose_cast8(TC8 a) {
  __shared__ float tile[32][33];
  const float* in = a.m[blockIdx.z].in;
  unsigned short* out = a.m[blockIdx.z].out;
  float scale = a.m[blockIdx.z].scale;
  int bx = blockIdx.x * 32, by = blockIdx.y * 32;
  int tx = threadIdx.x, ty = threadIdx.y;  // 32 x 8
#pragma unroll
  for (int i = ty; i < 32; i += 8)
    tile[i][tx] = in[(size_t)(by + i) * 1024 + bx + tx];
  __syncthreads();
#pragma unroll
  for (int i = ty; i < 32; i += 8)
    out[(size_t)(bx + i) * 1024 + by + tx] = f2b(tile[tx][i] * scale);
}

__global__ __launch_bounds__(256) void cast_bf16(
    const float* __restrict__ in, unsigned short* __restrict__ out, int n) {
  int i = blockIdx.x * 256 + threadIdx.x;
  if (i < n) out[i] = f2b(in[i]);
}

__global__ __launch_bounds__(256) void rope_tab(
    const float* __restrict__ rope, float* __restrict__ cosT, float* __restrict__ sinT, int n) {
  int i = blockIdx.x * 256 + threadIdx.x;
  if (i < n) {
    float v = rope[i];
    cosT[i] = cosf(v);
    sinT[i] = sinf(v);
  }
}

// ---------------------------------------------------------------------------
__global__ __launch_bounds__(256) void mods_kernel(
    const float* __restrict__ te, const unsigned short* __restrict__ wmodT,
    const float* __restrict__ bmod, float* __restrict__ mods) {
  int w = blockIdx.x * 4 + (threadIdx.x >> 6);
  int lane = threadIdx.x & 63;
  int b = w / 6144, j = w % 6144;
  const unsigned short* wr = wmodT + (size_t)j * 1024;
  const float* ter = te + (size_t)b * 1024;
  int k0 = lane * 16;
  float sum = 0.f;
#pragma unroll
  for (int u = 0; u < 2; ++u) {
    short8 wv = *(const short8*)(wr + k0 + u * 8);
#pragma unroll
    for (int e = 0; e < 8; ++e)
      sum += b2f((unsigned short)wv[e]) * ter[k0 + u * 8 + e];
  }
#pragma unroll
  for (int off = 32; off >= 1; off >>= 1) sum += __shfl_down(sum, off);
  if (lane == 0) mods[(size_t)b * 6144 + j] = sum + bmod[j];
}

// ---------------------------------------------------------------------------
__global__ __launch_bounds__(256) void ln_mod(
    const float* __restrict__ x, const float* __restrict__ mods,
    unsigned short* __restrict__ out, int scale_ofs, int shift_ofs) {
  int row = blockIdx.x;
  int b = row >> 11;
  int tid = threadIdx.x;
  const float* xr = x + (size_t)row * 1024;
  float4 v = ((const float4*)xr)[tid];
  float s = v.x + v.y + v.z + v.w;
  float ss = v.x * v.x + v.y * v.y + v.z * v.z + v.w * v.w;
#pragma unroll
  for (int off = 32; off >= 1; off >>= 1) {
    s += __shfl_down(s, off);
    ss += __shfl_down(ss, off);
  }
  __shared__ float red[8];
  int wave = tid >> 6, lane = tid & 63;
  if (lane == 0) { red[wave] = s; red[4 + wave] = ss; }
  __syncthreads();
  if (tid == 0) {
    float S = red[0] + red[1] + red[2] + red[3];
    float SS = red[4] + red[5] + red[6] + red[7];
    float mu = S * (1.f / 1024.f);
    red[0] = mu;
    red[1] = SS * (1.f / 1024.f) - mu * mu;
  }
  __syncthreads();
  float mu = red[0];
  float rs = rsqrtf(red[1] + 1e-6f);
  float vv[4] = {v.x, v.y, v.z, v.w};
  unsigned short o[4];
#pragma unroll
  for (int c = 0; c < 4; ++c) {
    int col = tid * 4 + c;
    float nv = (vv[c] - mu) * rs;
    if (scale_ofs >= 0)
      nv = nv * (1.f + mods[(size_t)b * 6144 + scale_ofs + col]) +
           mods[(size_t)b * 6144 + shift_ofs + col];
    o[c] = f2b(nv);
  }
  *(ushort4*)(&out[(size_t)row * 1024 + tid * 4]) = *(const ushort4*)o;
}

// ---------------------------------------------------------------------------
__global__ __launch_bounds__(256) void rope_apply(
    unsigned short* __restrict__ qb, unsigned short* __restrict__ kb,
    const float* __restrict__ cosT, const float* __restrict__ sinT) {
  int idx = blockIdx.x * 256 + threadIdx.x;  // over [4096][16][32]
  unsigned short* buf = blockIdx.y ? kb : qb;
  int row = idx >> 9;
  int rem = idx & 511;
  int h = rem >> 5, d = rem & 31;
  int l = row & 2047;
  size_t base = (size_t)row * 1024 + h * 64 + d;
  float x1 = b2f(buf[base]), x2 = b2f(buf[base + 32]);
  float c1 = cosT[l * 64 + d], s1 = sinT[l * 64 + d];
  float c2 = cosT[l * 64 + d + 32], s2 = sinT[l * 64 + d + 32];
  buf[base] = f2b(x1 * c1 - x2 * s1);
  buf[base + 32] = f2b(x2 * c2 + x1 * s2);
}

// ---------------------------------------------------------------------------
// Shared GEMM epilogue.  EPI: 0 bf16; 1 bias+GELU bf16; 2 f32 residual
// src + gate*(acc+bias); 3 bf16 split-store (buffer = col>>10, row stride 1024,
// buffer stride 4096*1024).
// ---------------------------------------------------------------------------
template <int EPI, int MI, int NJ>
DEV void gemm_epilogue(f32x4 (&acc)[MI][NJ], void* Cout, const float* bias,
                       const float* mods, int gate_ofs, const float* src,
                       int N, int rowsPerB, int m0, int n0, int wm, int wn,
                       int g, int r) {
#pragma unroll
  for (int i = 0; i < MI; ++i) {
#pragma unroll
    for (int j = 0; j < NJ; ++j) {
#pragma unroll
      for (int q = 0; q < 4; ++q) {
        size_t grow = (size_t)(m0 + wm + i * 16 + g * 4 + q);
        size_t gcol = (size_t)(n0 + wn + j * 16 + r);
        float v = acc[i][j][q];
        if constexpr (EPI == 0) {
          ((unsigned short*)Cout)[grow * N + gcol] = f2b(v);
        } else if constexpr (EPI == 1) {
          v += bias[gcol];
          float ge = 0.5f * v * (1.0f + erff(v * 0.70710678f));
          ((unsigned short*)Cout)[grow * N + gcol] = f2b(ge);
        } else if constexpr (EPI == 3) {
          size_t buf = gcol >> 10;
          ((unsigned short*)Cout)[buf * (4096ull * 1024) + grow * 1024 + (gcol & 1023)] = f2b(v);
        } else {
          v += bias[gcol];
          float gate = 1.0f;
          if (gate_ofs >= 0)
            gate = mods[(grow / rowsPerB) * 6144 + gate_ofs + gcol];
          ((float*)Cout)[grow * N + gcol] = src[grow * N + gcol] + gate * v;
        }
      }
    }
  }
}

// ---------------------------------------------------------------------------
// GEMM (m97): 128x128, BK=32, implicit overlap.  For >=4 blocks/CU (mlp1).
// ---------------------------------------------------------------------------
template <int EPI>
__global__ __launch_bounds__(256, 2) void gemm_bt(
    const unsigned short* __restrict__ A, const unsigned short* __restrict__ Bt,
    void* __restrict__ Cout, const float* __restrict__ bias,
    const float* __restrict__ mods, int gate_ofs, const float* __restrict__ src,
    int M, int N, int K, int rowsPerB) {
  __shared__ unsigned short As[128 * 32];
  __shared__ unsigned short Bs[128 * 32];
  const int tid = threadIdx.x;
  const int wave = tid >> 6, lane = tid & 63;
  const int g = lane >> 4, r = lane & 15;
  const int m0 = blockIdx.y * 128, n0 = blockIdx.x * 128;
  const int wm = (wave >> 1) * 64, wn = (wave & 1) * 64;
  const int srow = lane >> 2;
  const int scol = (lane & 3) * 8;

  f32x4 acc[4][4] = {};

  for (int k0 = 0; k0 < K; k0 += 32) {
    __syncthreads();
#pragma unroll
    for (int cc = 0; cc < 4; ++cc) {
      int c = wave * 4 + cc;
      int isB = c >> 3;
      int cl = c & 7;
      int row = cl * 16 + srow;
      const unsigned short* gsrc =
          isB ? (Bt + (size_t)(n0 + row) * K + k0 + scol)
              : (A + (size_t)(m0 + row) * K + k0 + scol);
      unsigned short* ldst = (isB ? Bs : As) + cl * 512;
      __builtin_amdgcn_global_load_lds(GLB(gsrc), LDSP(ldst), 16, 0, 0);
    }
    __syncthreads();

    short8 bfr[4];
#pragma unroll
    for (int j = 0; j < 4; ++j)
      bfr[j] = *(const short8*)(&Bs[(wn + j * 16 + r) * 32 + g * 8]);
#pragma unroll
    for (int i = 0; i < 4; ++i) {
      short8 af = *(const short8*)(&As[(wm + i * 16 + r) * 32 + g * 8]);
#pragma unroll
      for (int j = 0; j < 4; ++j)
        acc[i][j] = __builtin_amdgcn_mfma_f32_16x16x32_bf16(af, bfr[j], acc[i][j], 0, 0, 0);
    }
  }
  gemm_epilogue<EPI, 4, 4>(acc, Cout, bias, mods, gate_ofs, src, N, rowsPerB,
                           m0, n0, wm, wn, g, r);
}

// ---------------------------------------------------------------------------
// GEMM (pipelined 128x128): BK=64, 4 LDS bufs, depth-3, counted vmcnt.
// For ~3 blocks/CU grids (QKV).  XCD-grouped decode via mshift.
// ---------------------------------------------------------------------------
template <int EPI>
__global__ __launch_bounds__(256) void gemm_pipe(
    const unsigned short* __restrict__ A, const unsigned short* __restrict__ Bt,
    void* __restrict__ Cout, const float* __restrict__ bias,
    const float* __restrict__ mods, int gate_ofs, const float* __restrict__ src,
    int M, int N, int K, int rowsPerB, int mshift) {
  __shared__ unsigned short lds[4 * 16384];
  const int tid = threadIdx.x;
  const int wave = tid >> 6, lane = tid & 63;
  const int g = lane >> 4, r = lane & 15;
  const int flat = blockIdx.x;
  const int xcd = flat & 7, idx = flat >> 3;
  const int mt = xcd * (1 << mshift) + (idx & ((1 << mshift) - 1));
  const int nt = idx >> mshift;
  const int m0 = mt * 128, n0 = nt * 128;
  const int wm = (wave >> 1) * 64, wn = (wave & 1) * 64;
  const int srow8 = lane >> 3;
  const int sck = (lane & 7) ^ srow8;

  f32x4 acc[4][4] = {};

  auto stage = [&](int t, int bufi) {
    const int k0 = t * 64;
#pragma unroll
    for (int i = 0; i < 8; ++i) {
      int u = wave * 8 + i;
      int isB = u >> 4;
      int uu = u & 15;
      int rl = uu * 8 + srow8;
      const unsigned short* gsrc =
          (isB ? (Bt + (size_t)(n0 + rl) * K) : (A + (size_t)(m0 + rl) * K)) +
          k0 + sck * 8;
      unsigned short* dst = (unsigned short*)lds + bufi * 16384 + isB * 8192 + uu * 512;
      __builtin_amdgcn_global_load_lds(GLB(gsrc), LDSP(dst), 16, 0, 0);
    }
  };

  const int nt_k = K / 64;
  stage(0, 0);
  stage(1, 1);
  stage(2, 2);

  for (int t = 0; t < nt_k; ++t) {
    int rem = nt_k - t;
    if (rem >= 3) {
      asm volatile("s_waitcnt vmcnt(16)" ::: "memory");
    } else if (rem == 2) {
      asm volatile("s_waitcnt vmcnt(8)" ::: "memory");
    } else {
      asm volatile("s_waitcnt vmcnt(0)" ::: "memory");
    }
    __builtin_amdgcn_sched_barrier(0);
    __builtin_amdgcn_s_barrier();
    __builtin_amdgcn_sched_barrier(0);
    if (t + 3 < nt_k) stage(t + 3, (t + 3) & 3);

    const unsigned short* Ab = (const unsigned short*)lds + (t & 3) * 16384;
    const unsigned short* Bb = Ab + 8192;
#pragma unroll
    for (int ks = 0; ks < 2; ++ks) {
      short8 bfr[4];
#pragma unroll
      for (int j = 0; j < 4; ++j) {
        int row = wn + j * 16 + r;
        bfr[j] = *(const short8*)&Bb[row * 64 + ((g + ks * 4) ^ (r & 7)) * 8];
      }
#pragma unroll
      for (int i = 0; i < 4; ++i) {
        int row = wm + i * 16 + r;
        short8 af = *(const short8*)&Ab[row * 64 + ((g + ks * 4) ^ (r & 7)) * 8];
#pragma unroll
        for (int j = 0; j < 4; ++j)
          acc[i][j] = __builtin_amdgcn_mfma_f32_16x16x32_bf16(af, bfr[j], acc[i][j], 0, 0, 0);
      }
    }
  }
  gemm_epilogue<EPI, 4, 4>(acc, Cout, bias, mods, gate_ofs, src, N, rowsPerB,
                           m0, n0, wm, wn, g, r);
}

// ---------------------------------------------------------------------------
// GEMM (64x128 tile, 2-blocks/CU): 4 waves of 32x64, BK=64, 3 LDS bufs (72KB),
// depth-2 counted vmcnt(6).  Grid = (M/64)*(N/128); nt = flat % ntn puts one
// B-panel per XCD when ntn==8.  For the grid-256-at-128x128 GEMMs.
// ---------------------------------------------------------------------------
template <int EPI>
__global__ __launch_bounds__(256) void gemm_p2(
    const unsigned short* __restrict__ A, const unsigned short* __restrict__ Bt,
    void* __restrict__ Cout, const float* __restrict__ bias,
    const float* __restrict__ mods, int gate_ofs, const float* __restrict__ src,
    int M, int N, int K, int rowsPerB, int ntn) {
  __shared__ unsigned short lds[3 * 12288];  // per buf: A 64x64 (8KB) | B 128x64 (16KB)
  const int tid = threadIdx.x;
  const int wave = tid >> 6, lane = tid & 63;
  const int g = lane >> 4, r = lane & 15;
  const int flat = blockIdx.x;
  const int nt = flat % ntn, mt = flat / ntn;
  const int m0 = mt * 64, n0 = nt * 128;
  const int wm = (wave >> 1) * 32, wn = (wave & 1) * 64;
  const int srow8 = lane >> 3;
  const int sck = (lane & 7) ^ srow8;

  f32x4 acc[2][4] = {};

  auto stage = [&](int t, int bufi) {
    const int k0 = t * 64;
    unsigned short* base = (unsigned short*)lds + bufi * 12288;
#pragma unroll
    for (int i = 0; i < 2; ++i) {  // A units: 8 of 64 rows
      int u = wave * 2 + i;
      int rl = u * 8 + srow8;
      const unsigned short* gsrc = A + (size_t)(m0 + rl) * K + k0 + sck * 8;
      __builtin_amdgcn_global_load_lds(GLB(gsrc), LDSP(base + u * 512), 16, 0, 0);
    }
#pragma unroll
    for (int i = 0; i < 4; ++i) {  // B units: 16 of 128 rows
      int u = wave * 4 + i;
      int rl = u * 8 + srow8;
      const unsigned short* gsrc = Bt + (size_t)(n0 + rl) * K + k0 + sck * 8;
      __builtin_amdgcn_global_load_lds(GLB(gsrc), LDSP(base + 4096 + u * 512), 16, 0, 0);
    }
  };

  const int ntk = K / 64;
  stage(0, 0);
  stage(1, 1);
  int cbuf = 0, sbuf = 2;

  for (int t = 0; t < ntk; ++t) {
    if (t < ntk - 1) {
      asm volatile("s_waitcnt vmcnt(6)" ::: "memory");
    } else {
      asm volatile("s_waitcnt vmcnt(0)" ::: "memory");
    }
    __builtin_amdgcn_sched_barrier(0);
    __builtin_amdgcn_s_barrier();
    __builtin_amdgcn_sched_barrier(0);
    if (t + 2 < ntk) {
      stage(t + 2, sbuf);
      sbuf = (sbuf == 2) ? 0 : sbuf + 1;
    }

    const unsigned short* Ab = (const unsigned short*)lds + cbuf * 12288;
    const unsigned short* Bb = Ab + 4096;
#pragma unroll
    for (int ks = 0; ks < 2; ++ks) {
      short8 bfr[4];
#pragma unroll
      for (int j = 0; j < 4; ++j) {
        int row = wn + j * 16 + r;
        bfr[j] = *(const short8*)&Bb[row * 64 + ((g + ks * 4) ^ (r & 7)) * 8];
      }
#pragma unroll
      for (int i = 0; i < 2; ++i) {
        int row = wm + i * 16 + r;
        short8 af = *(const short8*)&Ab[row * 64 + ((g + ks * 4) ^ (r & 7)) * 8];
#pragma unroll
        for (int j = 0; j < 4; ++j)
          acc[i][j] = __builtin_amdgcn_mfma_f32_16x16x32_bf16(af, bfr[j], acc[i][j], 0, 0, 0);
      }
    }
    cbuf = (cbuf == 2) ? 0 : cbuf + 1;
  }
  gemm_epilogue<EPI, 2, 4>(acc, Cout, bias, mods, gate_ofs, src, N, rowsPerB,
                           m0, n0, wm, wn, g, r);
}

// ---------------------------------------------------------------------------
// Flash attention v8: v7 + T15 two-tile software pipeline.
// While softmax(t) runs on the VALU, QK^T(t+1) runs on the MFMA pipe (fully
// independent register sets sA/sB, statically named via 2x-unrolled loop).
// K LDS goes 2->3 buffers (read t+1 while staging t+2); V keeps 2 buffers
// with the proven load-early/write-late reg split.  40KB LDS, 2 blocks/CU.
// No setprio around QK (setprio is a scheduling fence and would block the
// softmax<->QK interleave); kept around PV (m191).  max3 tree (T17).
// ---------------------------------------------------------------------------
__global__ __launch_bounds__(256, 2) void flash2(
    const unsigned short* __restrict__ Q, const unsigned short* __restrict__ Kv,
    const unsigned short* __restrict__ Vv, unsigned short* __restrict__ O,
    int Lk) {
  __shared__ unsigned short lds[20480];  // 40KB: K 3x8KB @0 | V^T 2x8KB @12288
  const int tid = threadIdx.x, wave = tid >> 6, lane = tid & 63;
  const int hi = lane >> 5, lq = lane & 31;
  const int flat = blockIdx.x;
  const int xcd = flat & 7, rr = flat >> 3;
  const int gl = rr >> 4, qt = rr & 15;
  const int g = xcd * 4 + gl;
  const int h = g & 15, b = g >> 4;
  const int Lq = 2048, D = 1024;

  const unsigned short* Qbase =
      Q + ((size_t)b * Lq + qt * 128 + wave * 32 + lq) * D + h * 64;
  const unsigned short* Kbase = Kv + (size_t)b * Lk * D + h * 64;
  const unsigned short* Vbase = Vv + (size_t)b * Lk * D + h * 64;

  short8 qf[4];
#pragma unroll
  for (int kb = 0; kb < 4; ++kb)
    qf[kb] = *(const short8*)(Qbase + kb * 16 + hi * 8);

  const short8 ones = {0x3F80, 0x3F80, 0x3F80, 0x3F80, 0x3F80, 0x3F80, 0x3F80, 0x3F80};

  const int kr0 = tid >> 3, kc0 = tid & 7;   // K stage: row, chunk
  const int kvp = tid >> 3, db = tid & 7;    // V stage: kv-pair, d-block
  const int kch0 = (kc0 ^ (kr0 & 7) ^ (kr0 >> 3)) & 7;
  const int kch1 = kch0 ^ 4;
  const int f0 = (lq & 7) ^ (lq >> 3);
  const int swz0 = f0 << 4, swz1 = swz0 ^ 64;

  // kt-invariant V^T write byte-offsets (per-thread constants, reg-resident)
  int vby[8];
#pragma unroll
  for (int e = 0; e < 8; ++e) {
    int d = db * 8 + e;
    vby[e] = d * 128 + ((kvp * 4) ^ (((e ^ db) & 7) << 4));
  }

  float m_run = -3.0e38f;
  f32x16 o0 = {}, o1 = {}, lacc = {};
  short8 vr0, vr1;
  short8 pbf[4];

  auto stageK = [&](int t, int bi) {
    const unsigned short* s0 = Kbase + (size_t)(t * 64 + kr0) * D + kch0 * 8;
    const unsigned short* s1 = Kbase + (size_t)(t * 64 + kr0 + 32) * D + kch1 * 8;
    __builtin_amdgcn_global_load_lds(GLB(s0), LDSP(&lds[bi * 4096 + wave * 512]), 16, 0, 0);
    __builtin_amdgcn_global_load_lds(GLB(s1), LDSP(&lds[bi * 4096 + 2048 + wave * 512]), 16, 0, 0);
  };
  auto loadV = [&](int t) {
    const unsigned short* v0 = Vbase + (size_t)(t * 64 + 2 * kvp) * D + db * 8;
    vr0 = *(const short8*)v0;
    vr1 = *(const short8*)(v0 + D);
  };
  auto writeV = [&](int t) {
    char* vt = (char*)&lds[12288 + (t & 1) * 4096];
#pragma unroll
    for (int e = 0; e < 8; ++e)
      *(unsigned int*)(vt + vby[e]) =
          (unsigned int)(unsigned short)vr0[e] |
          ((unsigned int)(unsigned short)vr1[e] << 16);
  };
  auto qk = [&](int bi, f32x16& sa0, f32x16& sa1) {
    const unsigned short* K0 = &lds[bi * 4096];
#pragma unroll
    for (int ks = 0; ks < 4; ++ks) {
      int lo = ks * 32 + hi * 16;
      short8 a0 = *(const short8*)&K0[lq * 64 + ((lo ^ swz0) >> 1)];
      short8 a1 = *(const short8*)&K0[(32 + lq) * 64 + ((lo ^ swz1) >> 1)];
      sa0 = __builtin_amdgcn_mfma_f32_32x32x16_bf16(a0, qf[ks], sa0, 0, 0, 0);
      sa1 = __builtin_amdgcn_mfma_f32_32x32x16_bf16(a1, qf[ks], sa1, 0, 0, 0);
    }
  };
  auto finish = [&](f32x16& s0a, f32x16& s1a) {
    float tm[8];
#pragma unroll
    for (int i = 0; i < 8; ++i)
      tm[i] = fmaxf(max3f(s0a[i], s0a[i + 8], s1a[i]), s1a[i + 8]);
    float x = max3f(tm[0], tm[1], tm[2]);
    float y = max3f(tm[3], tm[4], tm[5]);
    float pm = fmaxf(max3f(tm[6], tm[7], x), y);
    {
      unsigned int ua = __builtin_bit_cast(unsigned int, pm), ub = ua;
      vpsw(ua, ub);
      pm = fmaxf(__builtin_bit_cast(float, ua), __builtin_bit_cast(float, ub));
    }
    if (__any(pm - m_run > 8.0f)) {
      float mnew = fmaxf(m_run, pm);
      float alpha = exp2f(m_run - mnew);
      lacc[0] *= alpha;
#pragma unroll
      for (int i = 0; i < 16; ++i) { o0[i] *= alpha; o1[i] *= alpha; }
      m_run = mnew;
    }
    float mc = m_run;
#pragma unroll
    for (int i = 0; i < 16; ++i) s0a[i] = exp2f(s0a[i] - mc);
#pragma unroll
    for (int i = 0; i < 16; ++i) s1a[i] = exp2f(s1a[i] - mc);
#pragma unroll
    for (int kb = 0; kb < 4; ++kb) {
      int bb = (kb & 1) * 8;
      float p0, p1, p2, p3, p4, p5, p6, p7;
      if (kb < 2) {
        p0 = s0a[bb + 0]; p1 = s0a[bb + 1]; p2 = s0a[bb + 2]; p3 = s0a[bb + 3];
        p4 = s0a[bb + 4]; p5 = s0a[bb + 5]; p6 = s0a[bb + 6]; p7 = s0a[bb + 7];
      } else {
        p0 = s1a[bb + 0]; p1 = s1a[bb + 1]; p2 = s1a[bb + 2]; p3 = s1a[bb + 3];
        p4 = s1a[bb + 4]; p5 = s1a[bb + 5]; p6 = s1a[bb + 6]; p7 = s1a[bb + 7];
      }
      unsigned int u0 = pk2(p0, p1), u1 = pk2(p2, p3);
      unsigned int u2 = pk2(p4, p5), u3 = pk2(p6, p7);
      vpsw(u0, u2);
      vpsw(u1, u3);
      union { unsigned int u[4]; short8 s; } fr;
      fr.u[0] = u0; fr.u[1] = u1; fr.u[2] = u2; fr.u[3] = u3;
      pbf[kb] = fr.s;
    }
  };
  auto pv = [&](int t) {
    const unsigned short* V0 = &lds[12288 + (t & 1) * 4096];
    __builtin_amdgcn_s_setprio(1);
#pragma unroll
    for (int kb = 0; kb < 4; ++kb) {
      int lo = kb * 32 + hi * 16;
      short8 vf0 = *(const short8*)&V0[lq * 64 + ((lo ^ swz0) >> 1)];
      short8 vf1 = *(const short8*)&V0[(32 + lq) * 64 + ((lo ^ swz1) >> 1)];
      o0 = __builtin_amdgcn_mfma_f32_32x32x16_bf16(vf0, pbf[kb], o0, 0, 0, 0);
      o1 = __builtin_amdgcn_mfma_f32_32x32x16_bf16(vf1, pbf[kb], o1, 0, 0, 0);
      lacc = __builtin_amdgcn_mfma_f32_32x32x16_bf16(ones, pbf[kb], lacc, 0, 0, 0);
    }
    __builtin_amdgcn_s_setprio(0);
  };

  const int nkt = Lk / 64;  // even for both Lk=2048 (32) and Lk=512 (8)

  // prologue: K(0)->buf0, V(0)->Vbuf0, K(1)->buf1, then S(0)
  stageK(0, 0);
  loadV(0);
  writeV(0);
  stageK(1, 1);
  __syncthreads();

  f32x16 sA0 = {}, sA1 = {}, sB0, sB1;
  qk(0, sA0, sA1);

  // pipelined step: QK(t+1)->snew (MFMA) overlaps finish(sold) (VALU); PV(t)
  auto pstep = [&](int t, f32x16& n0, f32x16& n1, f32x16& p0, f32x16& p1) {
    const int tq = t + 1;
    if (tq < nkt) {
      loadV(tq);
      if (tq + 1 < nkt) stageK(tq + 1, (tq + 1) % 3);
      n0 = {}; n1 = {};
      qk(tq % 3, n0, n1);
    }
    finish(p0, p1);
    if (tq < nkt) writeV(tq);
    pv(t);
    __syncthreads();
  };

  for (int t = 0; t < nkt; t += 2) {
    pstep(t, sB0, sB1, sA0, sA1);
    pstep(t + 1, sA0, sA1, sB0, sB1);
  }

  // ---- epilogue: normalize, bounce through LDS, coalesced store ----
  float rl = 1.0f / lacc[0];
  unsigned short* os = &lds[wave * 2048];
#pragma unroll
  for (int t = 0; t < 2; ++t) {
#pragma unroll
    for (int c = 0; c < 4; ++c) {
      int dbase = 32 * t + 8 * c + 4 * hi;
      float v0 = (t ? o1[4 * c + 0] : o0[4 * c + 0]) * rl;
      float v1 = (t ? o1[4 * c + 1] : o0[4 * c + 1]) * rl;
      float v2 = (t ? o1[4 * c + 2] : o0[4 * c + 2]) * rl;
      float v3 = (t ? o1[4 * c + 3] : o0[4 * c + 3]) * rl;
      int by0 = lq * 128 + ((dbase * 2) ^ ((lq & 7) << 4));
      int by1 = lq * 128 + (((dbase + 2) * 2) ^ ((lq & 7) << 4));
      *(unsigned int*)((char*)os + by0) = pk2(v0, v1);
      *(unsigned int*)((char*)os + by1) = pk2(v2, v3);
    }
  }
  int q2 = lane >> 1;
  unsigned short* orow =
      O + ((size_t)b * Lq + qt * 128 + wave * 32 + q2) * D + h * 64;
#pragma unroll
  for (int j = 0; j < 4; ++j) {
    int j2 = (lane & 1) * 4 + j;
    int byr = q2 * 128 + ((j2 * 16) ^ ((q2 & 7) << 4));
    short8 vv = *(const short8*)((char*)os + byr);
    *(short8*)(orow + j2 * 8) = vv;
  }
}

// ---------------------------------------------------------------------------
// Host orchestration
// ---------------------------------------------------------------------------
extern "C" void kernel_launch(void* const* d_in, const int* in_sizes, int n_in,
                              void* d_out, int out_size, void* d_ws, size_t ws_size,
                              hipStream_t stream) {
  (void)in_sizes; (void)n_in; (void)out_size; (void)ws_size;
  const float* x_in = (const float*)d_in[0];
  const float* te   = (const float*)d_in[1];
  const float* ctx  = (const float*)d_in[2];
  const float* rope = (const float*)d_in[3];
  const float* wmod = (const float*)d_in[4];
  const float* bmod = (const float*)d_in[5];
  const float* wqs  = (const float*)d_in[6];
  const float* wks  = (const float*)d_in[7];
  const float* wvs  = (const float*)d_in[8];
  const float* wos  = (const float*)d_in[9];
  const float* bos  = (const float*)d_in[10];
  const float* wqc  = (const float*)d_in[11];
  const float* wkc  = (const float*)d_in[12];
  const float* wvc  = (const float*)d_in[13];
  const float* woc  = (const float*)d_in[14];
  const float* boc  = (const float*)d_in[15];
  const float* w1   = (const float*)d_in[16];
  const float* b1   = (const float*)d_in[17];
  const float* w2   = (const float*)d_in[18];
  const float* b2   = (const float*)d_in[19];
  float* out = (float*)d_out;

  char* w = (char*)d_ws;
  size_t o = 0;
  auto alloc = [&](size_t bytes) {
    char* p = w + o;
    o = (o + bytes + 255) & ~(size_t)255;
    return p;
  };
  unsigned short* wmodT = (unsigned short*)alloc(6144ull * 1024 * 2);
  // wqsT/wksT/wvsT adjacent (fused QKV); wkcT/wvcT adjacent (fused cross-KV).
  unsigned short* wqsT  = (unsigned short*)alloc(1024ull * 1024 * 2);
  unsigned short* wksT  = (unsigned short*)alloc(1024ull * 1024 * 2);
  unsigned short* wvsT  = (unsigned short*)alloc(1024ull * 1024 * 2);
  unsigned short* wosT  = (unsigned short*)alloc(1024ull * 1024 * 2);
  unsigned short* wqcT  = (unsigned short*)alloc(1024ull * 1024 * 2);
  unsigned short* wkcT  = (unsigned short*)alloc(1024ull * 1024 * 2);
  unsigned short* wvcT  = (unsigned short*)alloc(1024ull * 1024 * 2);
  unsigned short* wocT  = (unsigned short*)alloc(1024ull * 1024 * 2);
  unsigned short* w1T   = (unsigned short*)alloc(4096ull * 1024 * 2);
  unsigned short* w2T   = (unsigned short*)alloc(1024ull * 4096 * 2);
  float* modsb = (float*)alloc(2ull * 6144 * 4);
  float* cosT  = (float*)alloc(2048ull * 64 * 4);
  float* sinT  = (float*)alloc(2048ull * 64 * 4);
  unsigned short* nx   = (unsigned short*)alloc(4096ull * 1024 * 2);
  unsigned short* ctxb = (unsigned short*)alloc(1024ull * 1024 * 2);
  // qb/kb/vb adjacent: EPI3 buffer stride = 4096*1024 elems.
  unsigned short* qb = (unsigned short*)alloc(4096ull * 1024 * 2);
  unsigned short* kb = (unsigned short*)alloc(4096ull * 1024 * 2);
  unsigned short* vb = (unsigned short*)alloc(4096ull * 1024 * 2);
  unsigned short* ao = (unsigned short*)alloc(4096ull * 1024 * 2);
  float* xw = (float*)alloc(4096ull * 1024 * 4);
  unsigned short* hbuf = qb;  // reuse qb..ao contiguous 32MB for MLP hidden

  const float c1 = 0.125f * 1.4426950408889634f;  // scale * log2(e), folded into wqs/wkc

  dim3 tb(32, 8);
  transpose_cast<<<dim3(6144 / 32, 1024 / 32), tb, 0, stream>>>(wmod, wmodT, 1024, 6144, 1.0f);
  TC8 tc8;
  tc8.m[0] = {wqs, wqsT, c1};
  tc8.m[1] = {wks, wksT, 1.0f};
  tc8.m[2] = {wvs, wvsT, 1.0f};
  tc8.m[3] = {wos, wosT, 1.0f};
  tc8.m[4] = {wqc, wqcT, 1.0f};
  tc8.m[5] = {wkc, wkcT, c1};
  tc8.m[6] = {wvc, wvcT, 1.0f};
  tc8.m[7] = {woc, wocT, 1.0f};
  transpose_cast8<<<dim3(32, 32, 8), tb, 0, stream>>>(tc8);
  transpose_cast<<<dim3(4096 / 32, 1024 / 32), tb, 0, stream>>>(w1, w1T, 1024, 4096, 1.0f);
  transpose_cast<<<dim3(1024 / 32, 4096 / 32), tb, 0, stream>>>(w2, w2T, 4096, 1024, 1.0f);

  cast_bf16<<<4096, 256, 0, stream>>>(ctx, ctxb, 1024 * 1024);
  rope_tab<<<512, 256, 0, stream>>>(rope, cosT, sinT, 2048 * 64);
  mods_kernel<<<3072, 256, 0, stream>>>(te, wmodT, bmod, modsb);

  // --- self-attention ---
  ln_mod<<<4096, 256, 0, stream>>>(x_in, modsb, nx, 1024, 0);
  gemm_pipe<3><<<768, 256, 0, stream>>>(nx, wqsT, qb, nullptr, nullptr, -1, nullptr, 4096, 3072, 1024, 2048, 2);
  rope_apply<<<dim3(8192, 2), 256, 0, stream>>>(qb, kb, cosT, sinT);
  flash2<<<512, 256, 0, stream>>>(qb, kb, vb, ao, 2048);
  gemm_p2<2><<<512, 256, 0, stream>>>(ao, wosT, xw, bos, modsb, 2048, x_in, 4096, 1024, 1024, 2048, 8);

  // --- cross-attention ---
  ln_mod<<<4096, 256, 0, stream>>>(xw, modsb, nx, -1, -1);
  gemm_p2<0><<<512, 256, 0, stream>>>(nx, wqcT, qb, nullptr, nullptr, -1, nullptr, 4096, 1024, 1024, 2048, 8);
  gemm_p2<3><<<256, 256, 0, stream>>>(ctxb, wkcT, kb, nullptr, nullptr, -1, nullptr, 1024, 2048, 1024, 512, 16);
  flash2<<<512, 256, 0, stream>>>(qb, kb, vb, ao, 512);
  gemm_p2<2><<<512, 256, 0, stream>>>(ao, wocT, xw, boc, modsb, -1, xw, 4096, 1024, 1024, 2048, 8);

  // --- MLP ---
  ln_mod<<<4096, 256, 0, stream>>>(xw, modsb, nx, 4096, 3072);
  gemm_bt<1><<<dim3(32, 32), 256, 0, stream>>>(nx, w1T, hbuf, b1, nullptr, -1, nullptr, 4096, 4096, 1024, 2048);
  gemm_p2<2><<<512, 256, 0, stream>>>(hbuf, w2T, out, b2, modsb, 5120, xw, 4096, 1024, 4096, 2048, 8);
}

// Round 5
// 401.073 us; speedup vs baseline: 1.0909x; 1.0221x over previous
//
#include <hip/hip_runtime.h>
#include <hip/hip_bf16.h>

// ---------------------------------------------------------------------------
// CleanDITBlock: adaLN-modulated DiT block (self-attn w/ RoPE, cross-attn, MLP)
// B=2, L=2048, S=512, D=1024, H=16, HD=64, CTX=1024, HID=4096
// ---------------------------------------------------------------------------

typedef short short8 __attribute__((ext_vector_type(8)));
typedef float f32x4 __attribute__((ext_vector_type(4)));
typedef float f32x16 __attribute__((ext_vector_type(16)));

#define DEV __device__ __forceinline__

DEV unsigned short f2b(float f) {
  __hip_bfloat16 h = __float2bfloat16(f);
  return *reinterpret_cast<unsigned short*>(&h);
}
DEV float b2f(unsigned short u) {
  unsigned int x = ((unsigned int)u) << 16;
  return __builtin_bit_cast(float, x);
}
// single-instruction packed f32->bf16 pair (T12): D[15:0]=bf16(lo), D[31:16]=bf16(hi)
DEV unsigned int pk2(float lo, float hi) {
  unsigned int r;
  asm("v_cvt_pk_bf16_f32 %0, %1, %2" : "=v"(r) : "v"(lo), "v"(hi));
  return r;
}
// lane[i]<->lane[i+32] half-swap (VALU, no LDS)
DEV void vpsw(unsigned int& a, unsigned int& b) {
  asm("v_permlane32_swap_b32 %0, %1" : "+v"(a), "+v"(b));
}
// 3-input max (T17)
DEV float max3f(float a, float b, float c) {
  float r;
  asm("v_max3_f32 %0, %1, %2, %3" : "=v"(r) : "v"(a), "v"(b), "v"(c));
  return r;
}

#define GLB(p) ((const __attribute__((address_space(1))) void*)(p))
#define LDSP(p) ((__attribute__((address_space(3))) void*)(p))

// ---------------------------------------------------------------------------
__global__ __launch_bounds__(256) void transpose_cast(
    const float* __restrict__ in, unsigned short* __restrict__ out, int R, int C,
    float scale) {
  __shared__ float tile[32][33];
  int bx = blockIdx.x * 32, by = blockIdx.y * 32;
  int tx = threadIdx.x, ty = threadIdx.y;  // 32 x 8
#pragma unroll
  for (int i = ty; i < 32; i += 8)
    tile[i][tx] = in[(size_t)(by + i) * C + bx + tx];
  __syncthreads();
#pragma unroll
  for (int i = ty; i < 32; i += 8)
    out[(size_t)(bx + i) * R + by + tx] = f2b(tile[tx][i] * scale);
}

// batched 1024x1024 transposes (one launch for all 8 square weights)
struct TCB { const float* in; unsigned short* out; float scale; };
struct TC8 { TCB m[8]; };
__global__ __launch_bounds__(256) void transpose_cast8(TC8 a) {
  __shared__ float tile[32][33];
  const float* in = a.m[blockIdx.z].in;
  unsigned short* out = a.m[blockIdx.z].out;
  float scale = a.m[blockIdx.z].scale;
  int bx = blockIdx.x * 32, by = blockIdx.y * 32;
  int tx = threadIdx.x, ty = threadIdx.y;  // 32 x 8
#pragma unroll
  for (int i = ty; i < 32; i += 8)
    tile[i][tx] = in[(size_t)(by + i) * 1024 + bx + tx];
  __syncthreads();
#pragma unroll
  for (int i = ty; i < 32; i += 8)
    out[(size_t)(bx + i) * 1024 + by + tx] = f2b(tile[tx][i] * scale);
}

__global__ __launch_bounds__(256) void cast_bf16(
    const float* __restrict__ in, unsigned short* __restrict__ out, int n) {
  int i = blockIdx.x * 256 + threadIdx.x;
  if (i < n) out[i] = f2b(in[i]);
}

// interleaved (cos,sin) table for epilogue-fused RoPE
__global__ __launch_bounds__(256) void rope_tab(
    const float* __restrict__ rope, float2* __restrict__ cs, int n) {
  int i = blockIdx.x * 256 + threadIdx.x;
  if (i < n) {
    float v = rope[i];
    cs[i] = make_float2(cosf(v), sinf(v));
  }
}

// ---------------------------------------------------------------------------
__global__ __launch_bounds__(256) void mods_kernel(
    const float* __restrict__ te, const unsigned short* __restrict__ wmodT,
    const float* __restrict__ bmod, float* __restrict__ mods) {
  int w = blockIdx.x * 4 + (threadIdx.x >> 6);
  int lane = threadIdx.x & 63;
  int b = w / 6144, j = w % 6144;
  const unsigned short* wr = wmodT + (size_t)j * 1024;
  const float* ter = te + (size_t)b * 1024;
  int k0 = lane * 16;
  float sum = 0.f;
#pragma unroll
  for (int u = 0; u < 2; ++u) {
    short8 wv = *(const short8*)(wr + k0 + u * 8);
#pragma unroll
    for (int e = 0; e < 8; ++e)
      sum += b2f((unsigned short)wv[e]) * ter[k0 + u * 8 + e];
  }
#pragma unroll
  for (int off = 32; off >= 1; off >>= 1) sum += __shfl_down(sum, off);
  if (lane == 0) mods[(size_t)b * 6144 + j] = sum + bmod[j];
}

// ---------------------------------------------------------------------------
__global__ __launch_bounds__(256) void ln_mod(
    const float* __restrict__ x, const float* __restrict__ mods,
    unsigned short* __restrict__ out, int scale_ofs, int shift_ofs) {
  int row = blockIdx.x;
  int b = row >> 11;
  int tid = threadIdx.x;
  const float* xr = x + (size_t)row * 1024;
  float4 v = ((const float4*)xr)[tid];
  float s = v.x + v.y + v.z + v.w;
  float ss = v.x * v.x + v.y * v.y + v.z * v.z + v.w * v.w;
#pragma unroll
  for (int off = 32; off >= 1; off >>= 1) {
    s += __shfl_down(s, off);
    ss += __shfl_down(ss, off);
  }
  __shared__ float red[8];
  int wave = tid >> 6, lane = tid & 63;
  if (lane == 0) { red[wave] = s; red[4 + wave] = ss; }
  __syncthreads();
  if (tid == 0) {
    float S = red[0] + red[1] + red[2] + red[3];
    float SS = red[4] + red[5] + red[6] + red[7];
    float mu = S * (1.f / 1024.f);
    red[0] = mu;
    red[1] = SS * (1.f / 1024.f) - mu * mu;
  }
  __syncthreads();
  float mu = red[0];
  float rs = rsqrtf(red[1] + 1e-6f);
  float vv[4] = {v.x, v.y, v.z, v.w};
  unsigned short o[4];
#pragma unroll
  for (int c = 0; c < 4; ++c) {
    int col = tid * 4 + c;
    float nv = (vv[c] - mu) * rs;
    if (scale_ofs >= 0)
      nv = nv * (1.f + mods[(size_t)b * 6144 + scale_ofs + col]) +
           mods[(size_t)b * 6144 + shift_ofs + col];
    o[c] = f2b(nv);
  }
  *(ushort4*)(&out[(size_t)row * 1024 + tid * 4]) = *(const ushort4*)o;
}

// ---------------------------------------------------------------------------
// Shared GEMM epilogue.  EPI: 0 bf16; 1 bias+GELU bf16; 2 f32 residual
// src + gate*(acc+bias); 3 bf16 split-store (buffer = col>>10, row stride 1024,
// buffer stride 4096*1024).
// ---------------------------------------------------------------------------
template <int EPI, int MI, int NJ>
DEV void gemm_epilogue(f32x4 (&acc)[MI][NJ], void* Cout, const float* bias,
                       const float* mods, int gate_ofs, const float* src,
                       int N, int rowsPerB, int m0, int n0, int wm, int wn,
                       int g, int r) {
#pragma unroll
  for (int i = 0; i < MI; ++i) {
#pragma unroll
    for (int j = 0; j < NJ; ++j) {
#pragma unroll
      for (int q = 0; q < 4; ++q) {
        size_t grow = (size_t)(m0 + wm + i * 16 + g * 4 + q);
        size_t gcol = (size_t)(n0 + wn + j * 16 + r);
        float v = acc[i][j][q];
        if constexpr (EPI == 0) {
          ((unsigned short*)Cout)[grow * N + gcol] = f2b(v);
        } else if constexpr (EPI == 1) {
          v += bias[gcol];
          float ge = 0.5f * v * (1.0f + erff(v * 0.70710678f));
          ((unsigned short*)Cout)[grow * N + gcol] = f2b(ge);
        } else if constexpr (EPI == 3) {
          size_t buf = gcol >> 10;
          ((unsigned short*)Cout)[buf * (4096ull * 1024) + grow * 1024 + (gcol & 1023)] = f2b(v);
        } else {
          v += bias[gcol];
          float gate = 1.0f;
          if (gate_ofs >= 0)
            gate = mods[(grow / rowsPerB) * 6144 + gate_ofs + gcol];
          ((float*)Cout)[grow * N + gcol] = src[grow * N + gcol] + gate * v;
        }
      }
    }
  }
}

// ---------------------------------------------------------------------------
// QKV epilogue with fused RoPE (EPI 4).  j-tiles are head-aligned: d=j*16+r,
// rotation pair (d,d+32) = (acc[i][j], acc[i][j+2]) in the SAME lane.  Applies
// rope to buffers 0 (q) and 1 (k); buffer 2 (v) stored plain.  cs = interleaved
// (cos,sin)[l][d].  Replaces the separate rope_apply kernel (11us + 67MB RMW).
// ---------------------------------------------------------------------------
DEV void qkv_rope_epilogue(f32x4 (&acc)[4][4], unsigned short* Cout,
                           const float2* cs, int m0, int n0, int wm, int wn,
                           int g, int r) {
  const int buf = (n0 + wn) >> 10;      // wave-uniform
  const int colbase = (n0 + wn) & 1023;
  unsigned short* base = Cout + (size_t)buf * (4096ull * 1024);
#pragma unroll
  for (int i = 0; i < 4; ++i) {
#pragma unroll
    for (int q = 0; q < 4; ++q) {
      size_t grow = (size_t)(m0 + wm + i * 16 + g * 4 + q);
      unsigned short* orow = base + grow * 1024 + colbase + r;
      if (buf < 2) {
        int l = (int)(grow & 2047);
#pragma unroll
        for (int j = 0; j < 2; ++j) {
          int d = j * 16 + r;
          float2 a = cs[l * 64 + d];
          float2 bb = cs[l * 64 + d + 32];
          float x1 = acc[i][j][q], x2 = acc[i][j + 2][q];
          orow[j * 16] = f2b(x1 * a.x - x2 * a.y);
          orow[(j + 2) * 16] = f2b(x2 * bb.x + x1 * bb.y);
        }
      } else {
#pragma unroll
        for (int j = 0; j < 4; ++j) orow[j * 16] = f2b(acc[i][j][q]);
      }
    }
  }
}

// ---------------------------------------------------------------------------
// GEMM (m97): 128x128, BK=32, implicit overlap.  For >=4 blocks/CU (mlp1).
// ---------------------------------------------------------------------------
template <int EPI>
__global__ __launch_bounds__(256, 2) void gemm_bt(
    const unsigned short* __restrict__ A, const unsigned short* __restrict__ Bt,
    void* __restrict__ Cout, const float* __restrict__ bias,
    const float* __restrict__ mods, int gate_ofs, const float* __restrict__ src,
    int M, int N, int K, int rowsPerB) {
  __shared__ unsigned short As[128 * 32];
  __shared__ unsigned short Bs[128 * 32];
  const int tid = threadIdx.x;
  const int wave = tid >> 6, lane = tid & 63;
  const int g = lane >> 4, r = lane & 15;
  const int m0 = blockIdx.y * 128, n0 = blockIdx.x * 128;
  const int wm = (wave >> 1) * 64, wn = (wave & 1) * 64;
  const int srow = lane >> 2;
  const int scol = (lane & 3) * 8;

  f32x4 acc[4][4] = {};

  for (int k0 = 0; k0 < K; k0 += 32) {
    __syncthreads();
#pragma unroll
    for (int cc = 0; cc < 4; ++cc) {
      int c = wave * 4 + cc;
      int isB = c >> 3;
      int cl = c & 7;
      int row = cl * 16 + srow;
      const unsigned short* gsrc =
          isB ? (Bt + (size_t)(n0 + row) * K + k0 + scol)
              : (A + (size_t)(m0 + row) * K + k0 + scol);
      unsigned short* ldst = (isB ? Bs : As) + cl * 512;
      __builtin_amdgcn_global_load_lds(GLB(gsrc), LDSP(ldst), 16, 0, 0);
    }
    __syncthreads();

    short8 bfr[4];
#pragma unroll
    for (int j = 0; j < 4; ++j)
      bfr[j] = *(const short8*)(&Bs[(wn + j * 16 + r) * 32 + g * 8]);
#pragma unroll
    for (int i = 0; i < 4; ++i) {
      short8 af = *(const short8*)(&As[(wm + i * 16 + r) * 32 + g * 8]);
#pragma unroll
      for (int j = 0; j < 4; ++j)
        acc[i][j] = __builtin_amdgcn_mfma_f32_16x16x32_bf16(af, bfr[j], acc[i][j], 0, 0, 0);
    }
  }
  gemm_epilogue<EPI, 4, 4>(acc, Cout, bias, mods, gate_ofs, src, N, rowsPerB,
                           m0, n0, wm, wn, g, r);
}

// ---------------------------------------------------------------------------
// GEMM (pipelined 128x128): BK=64, 4 LDS bufs, depth-3, counted vmcnt.
// For ~3 blocks/CU grids (QKV).  XCD-grouped decode via mshift.
// EPI==4: fused-RoPE QKV epilogue (cs table passed via `bias`).
// ---------------------------------------------------------------------------
template <int EPI>
__global__ __launch_bounds__(256) void gemm_pipe(
    const unsigned short* __restrict__ A, const unsigned short* __restrict__ Bt,
    void* __restrict__ Cout, const float* __restrict__ bias,
    const float* __restrict__ mods, int gate_ofs, const float* __restrict__ src,
    int M, int N, int K, int rowsPerB, int mshift) {
  __shared__ unsigned short lds[4 * 16384];
  const int tid = threadIdx.x;
  const int wave = tid >> 6, lane = tid & 63;
  const int g = lane >> 4, r = lane & 15;
  const int flat = blockIdx.x;
  const int xcd = flat & 7, idx = flat >> 3;
  const int mt = xcd * (1 << mshift) + (idx & ((1 << mshift) - 1));
  const int nt = idx >> mshift;
  const int m0 = mt * 128, n0 = nt * 128;
  const int wm = (wave >> 1) * 64, wn = (wave & 1) * 64;
  const int srow8 = lane >> 3;
  const int sck = (lane & 7) ^ srow8;

  f32x4 acc[4][4] = {};

  auto stage = [&](int t, int bufi) {
    const int k0 = t * 64;
#pragma unroll
    for (int i = 0; i < 8; ++i) {
      int u = wave * 8 + i;
      int isB = u >> 4;
      int uu = u & 15;
      int rl = uu * 8 + srow8;
      const unsigned short* gsrc =
          (isB ? (Bt + (size_t)(n0 + rl) * K) : (A + (size_t)(m0 + rl) * K)) +
          k0 + sck * 8;
      unsigned short* dst = (unsigned short*)lds + bufi * 16384 + isB * 8192 + uu * 512;
      __builtin_amdgcn_global_load_lds(GLB(gsrc), LDSP(dst), 16, 0, 0);
    }
  };

  const int nt_k = K / 64;
  stage(0, 0);
  stage(1, 1);
  stage(2, 2);

  for (int t = 0; t < nt_k; ++t) {
    int rem = nt_k - t;
    if (rem >= 3) {
      asm volatile("s_waitcnt vmcnt(16)" ::: "memory");
    } else if (rem == 2) {
      asm volatile("s_waitcnt vmcnt(8)" ::: "memory");
    } else {
      asm volatile("s_waitcnt vmcnt(0)" ::: "memory");
    }
    __builtin_amdgcn_sched_barrier(0);
    __builtin_amdgcn_s_barrier();
    __builtin_amdgcn_sched_barrier(0);
    if (t + 3 < nt_k) stage(t + 3, (t + 3) & 3);

    const unsigned short* Ab = (const unsigned short*)lds + (t & 3) * 16384;
    const unsigned short* Bb = Ab + 8192;
#pragma unroll
    for (int ks = 0; ks < 2; ++ks) {
      short8 bfr[4];
#pragma unroll
      for (int j = 0; j < 4; ++j) {
        int row = wn + j * 16 + r;
        bfr[j] = *(const short8*)&Bb[row * 64 + ((g + ks * 4) ^ (r & 7)) * 8];
      }
#pragma unroll
      for (int i = 0; i < 4; ++i) {
        int row = wm + i * 16 + r;
        short8 af = *(const short8*)&Ab[row * 64 + ((g + ks * 4) ^ (r & 7)) * 8];
#pragma unroll
        for (int j = 0; j < 4; ++j)
          acc[i][j] = __builtin_amdgcn_mfma_f32_16x16x32_bf16(af, bfr[j], acc[i][j], 0, 0, 0);
      }
    }
  }
  if constexpr (EPI == 4) {
    qkv_rope_epilogue(acc, (unsigned short*)Cout, (const float2*)bias,
                      m0, n0, wm, wn, g, r);
  } else {
    gemm_epilogue<EPI, 4, 4>(acc, Cout, bias, mods, gate_ofs, src, N, rowsPerB,
                             m0, n0, wm, wn, g, r);
  }
}

// ---------------------------------------------------------------------------
// GEMM (64x128 tile, 2-blocks/CU): 4 waves of 32x64, BK=64, 3 LDS bufs (72KB),
// depth-2 counted vmcnt(6).  Grid = (M/64)*(N/128); nt = flat % ntn puts one
// B-panel per XCD when ntn==8.  For the grid-256-at-128x128 GEMMs.
// ---------------------------------------------------------------------------
template <int EPI>
__global__ __launch_bounds__(256) void gemm_p2(
    const unsigned short* __restrict__ A, const unsigned short* __restrict__ Bt,
    void* __restrict__ Cout, const float* __restrict__ bias,
    const float* __restrict__ mods, int gate_ofs, const float* __restrict__ src,
    int M, int N, int K, int rowsPerB, int ntn) {
  __shared__ unsigned short lds[3 * 12288];  // per buf: A 64x64 (8KB) | B 128x64 (16KB)
  const int tid = threadIdx.x;
  const int wave = tid >> 6, lane = tid & 63;
  const int g = lane >> 4, r = lane & 15;
  const int flat = blockIdx.x;
  const int nt = flat % ntn, mt = flat / ntn;
  const int m0 = mt * 64, n0 = nt * 128;
  const int wm = (wave >> 1) * 32, wn = (wave & 1) * 64;
  const int srow8 = lane >> 3;
  const int sck = (lane & 7) ^ srow8;

  f32x4 acc[2][4] = {};

  auto stage = [&](int t, int bufi) {
    const int k0 = t * 64;
    unsigned short* base = (unsigned short*)lds + bufi * 12288;
#pragma unroll
    for (int i = 0; i < 2; ++i) {  // A units: 8 of 64 rows
      int u = wave * 2 + i;
      int rl = u * 8 + srow8;
      const unsigned short* gsrc = A + (size_t)(m0 + rl) * K + k0 + sck * 8;
      __builtin_amdgcn_global_load_lds(GLB(gsrc), LDSP(base + u * 512), 16, 0, 0);
    }
#pragma unroll
    for (int i = 0; i < 4; ++i) {  // B units: 16 of 128 rows
      int u = wave * 4 + i;
      int rl = u * 8 + srow8;
      const unsigned short* gsrc = Bt + (size_t)(n0 + rl) * K + k0 + sck * 8;
      __builtin_amdgcn_global_load_lds(GLB(gsrc), LDSP(base + 4096 + u * 512), 16, 0, 0);
    }
  };

  const int ntk = K / 64;
  stage(0, 0);
  stage(1, 1);
  int cbuf = 0, sbuf = 2;

  for (int t = 0; t < ntk; ++t) {
    if (t < ntk - 1) {
      asm volatile("s_waitcnt vmcnt(6)" ::: "memory");
    } else {
      asm volatile("s_waitcnt vmcnt(0)" ::: "memory");
    }
    __builtin_amdgcn_sched_barrier(0);
    __builtin_amdgcn_s_barrier();
    __builtin_amdgcn_sched_barrier(0);
    if (t + 2 < ntk) {
      stage(t + 2, sbuf);
      sbuf = (sbuf == 2) ? 0 : sbuf + 1;
    }

    const unsigned short* Ab = (const unsigned short*)lds + cbuf * 12288;
    const unsigned short* Bb = Ab + 4096;
#pragma unroll
    for (int ks = 0; ks < 2; ++ks) {
      short8 bfr[4];
#pragma unroll
      for (int j = 0; j < 4; ++j) {
        int row = wn + j * 16 + r;
        bfr[j] = *(const short8*)&Bb[row * 64 + ((g + ks * 4) ^ (r & 7)) * 8];
      }
#pragma unroll
      for (int i = 0; i < 2; ++i) {
        int row = wm + i * 16 + r;
        short8 af = *(const short8*)&Ab[row * 64 + ((g + ks * 4) ^ (r & 7)) * 8];
#pragma unroll
        for (int j = 0; j < 4; ++j)
          acc[i][j] = __builtin_amdgcn_mfma_f32_16x16x32_bf16(af, bfr[j], acc[i][j], 0, 0, 0);
      }
    }
    cbuf = (cbuf == 2) ? 0 : cbuf + 1;
  }
  gemm_epilogue<EPI, 2, 4>(acc, Cout, bias, mods, gate_ofs, src, N, rowsPerB,
                           m0, n0, wm, wn, g, r);
}

// ---------------------------------------------------------------------------
// Flash attention v9: v8 structure + VALU-count cuts:
//   - persistent zero f32x16 as MFMA C-init (kills 32 v_mov/iter)
//   - v_perm_b32 V-pack (8 perms replace 16 and/shl/or)
// RoPE now fused upstream in the QKV GEMM epilogue.
// ---------------------------------------------------------------------------
__global__ __launch_bounds__(256, 2) void flash2(
    const unsigned short* __restrict__ Q, const unsigned short* __restrict__ Kv,
    const unsigned short* __restrict__ Vv, unsigned short* __restrict__ O,
    int Lk) {
  __shared__ unsigned short lds[20480];  // 40KB: K 3x8KB @0 | V^T 2x8KB @12288
  const int tid = threadIdx.x, wave = tid >> 6, lane = tid & 63;
  const int hi = lane >> 5, lq = lane & 31;
  const int flat = blockIdx.x;
  const int xcd = flat & 7, rr = flat >> 3;
  const int gl = rr >> 4, qt = rr & 15;
  const int g = xcd * 4 + gl;
  const int h = g & 15, b = g >> 4;
  const int Lq = 2048, D = 1024;

  const unsigned short* Qbase =
      Q + ((size_t)b * Lq + qt * 128 + wave * 32 + lq) * D + h * 64;
  const unsigned short* Kbase = Kv + (size_t)b * Lk * D + h * 64;
  const unsigned short* Vbase = Vv + (size_t)b * Lk * D + h * 64;

  short8 qf[4];
#pragma unroll
  for (int kb = 0; kb < 4; ++kb)
    qf[kb] = *(const short8*)(Qbase + kb * 16 + hi * 8);

  const short8 ones = {0x3F80, 0x3F80, 0x3F80, 0x3F80, 0x3F80, 0x3F80, 0x3F80, 0x3F80};
  const f32x16 z16 = {};  // persistent zero C-operand (16 VGPRs, loop-invariant)

  const int kr0 = tid >> 3, kc0 = tid & 7;   // K stage: row, chunk
  const int kvp = tid >> 3, db = tid & 7;    // V stage: kv-pair, d-block
  const int kch0 = (kc0 ^ (kr0 & 7) ^ (kr0 >> 3)) & 7;
  const int kch1 = kch0 ^ 4;
  const int f0 = (lq & 7) ^ (lq >> 3);
  const int swz0 = f0 << 4, swz1 = swz0 ^ 64;

  // kt-invariant V^T write byte-offsets (per-thread constants, reg-resident)
  int vby[8];
#pragma unroll
  for (int e = 0; e < 8; ++e) {
    int d = db * 8 + e;
    vby[e] = d * 128 + ((kvp * 4) ^ (((e ^ db) & 7) << 4));
  }

  float m_run = -3.0e38f;
  f32x16 o0 = {}, o1 = {}, lacc = {};
  short8 vr0, vr1;
  short8 pbf[4];

  auto stageK = [&](int t, int bi) {
    const unsigned short* s0 = Kbase + (size_t)(t * 64 + kr0) * D + kch0 * 8;
    const unsigned short* s1 = Kbase + (size_t)(t * 64 + kr0 + 32) * D + kch1 * 8;
    __builtin_amdgcn_global_load_lds(GLB(s0), LDSP(&lds[bi * 4096 + wave * 512]), 16, 0, 0);
    __builtin_amdgcn_global_load_lds(GLB(s1), LDSP(&lds[bi * 4096 + 2048 + wave * 512]), 16, 0, 0);
  };
  auto loadV = [&](int t) {
    const unsigned short* v0 = Vbase + (size_t)(t * 64 + 2 * kvp) * D + db * 8;
    vr0 = *(const short8*)v0;
    vr1 = *(const short8*)(v0 + D);
  };
  auto writeV = [&](int t) {
    char* vt = (char*)&lds[12288 + (t & 1) * 4096];
    union { short8 s; unsigned int u[4]; } a, c;
    a.s = vr0; c.s = vr1;
#pragma unroll
    for (int k = 0; k < 4; ++k) {
      *(unsigned int*)(vt + vby[2 * k]) =
          __builtin_amdgcn_perm(c.u[k], a.u[k], 0x05040100u);
      *(unsigned int*)(vt + vby[2 * k + 1]) =
          __builtin_amdgcn_perm(c.u[k], a.u[k], 0x07060302u);
    }
  };
  auto qk = [&](int bi, f32x16& sa0, f32x16& sa1) {
    const unsigned short* K0 = &lds[bi * 4096];
    {
      int lo = hi * 16;
      short8 a0 = *(const short8*)&K0[lq * 64 + ((lo ^ swz0) >> 1)];
      short8 a1 = *(const short8*)&K0[(32 + lq) * 64 + ((lo ^ swz1) >> 1)];
      sa0 = __builtin_amdgcn_mfma_f32_32x32x16_bf16(a0, qf[0], z16, 0, 0, 0);
      sa1 = __builtin_amdgcn_mfma_f32_32x32x16_bf16(a1, qf[0], z16, 0, 0, 0);
    }
#pragma unroll
    for (int ks = 1; ks < 4; ++ks) {
      int lo = ks * 32 + hi * 16;
      short8 a0 = *(const short8*)&K0[lq * 64 + ((lo ^ swz0) >> 1)];
      short8 a1 = *(const short8*)&K0[(32 + lq) * 64 + ((lo ^ swz1) >> 1)];
      sa0 = __builtin_amdgcn_mfma_f32_32x32x16_bf16(a0, qf[ks], sa0, 0, 0, 0);
      sa1 = __builtin_amdgcn_mfma_f32_32x32x16_bf16(a1, qf[ks], sa1, 0, 0, 0);
    }
  };
  auto finish = [&](f32x16& s0a, f32x16& s1a) {
    float tm[8];
#pragma unroll
    for (int i = 0; i < 8; ++i)
      tm[i] = fmaxf(max3f(s0a[i], s0a[i + 8], s1a[i]), s1a[i + 8]);
    float x = max3f(tm[0], tm[1], tm[2]);
    float y = max3f(tm[3], tm[4], tm[5]);
    float pm = fmaxf(max3f(tm[6], tm[7], x), y);
    {
      unsigned int ua = __builtin_bit_cast(unsigned int, pm), ub = ua;
      vpsw(ua, ub);
      pm = fmaxf(__builtin_bit_cast(float, ua), __builtin_bit_cast(float, ub));
    }
    if (__any(pm - m_run > 8.0f)) {
      float mnew = fmaxf(m_run, pm);
      float alpha = exp2f(m_run - mnew);
      lacc[0] *= alpha;
#pragma unroll
      for (int i = 0; i < 16; ++i) { o0[i] *= alpha; o1[i] *= alpha; }
      m_run = mnew;
    }
    float mc = m_run;
#pragma unroll
    for (int i = 0; i < 16; ++i) s0a[i] = exp2f(s0a[i] - mc);
#pragma unroll
    for (int i = 0; i < 16; ++i) s1a[i] = exp2f(s1a[i] - mc);
#pragma unroll
    for (int kb = 0; kb < 4; ++kb) {
      int bb = (kb & 1) * 8;
      float p0, p1, p2, p3, p4, p5, p6, p7;
      if (kb < 2) {
        p0 = s0a[bb + 0]; p1 = s0a[bb + 1]; p2 = s0a[bb + 2]; p3 = s0a[bb + 3];
        p4 = s0a[bb + 4]; p5 = s0a[bb + 5]; p6 = s0a[bb + 6]; p7 = s0a[bb + 7];
      } else {
        p0 = s1a[bb + 0]; p1 = s1a[bb + 1]; p2 = s1a[bb + 2]; p3 = s1a[bb + 3];
        p4 = s1a[bb + 4]; p5 = s1a[bb + 5]; p6 = s1a[bb + 6]; p7 = s1a[bb + 7];
      }
      unsigned int u0 = pk2(p0, p1), u1 = pk2(p2, p3);
      unsigned int u2 = pk2(p4, p5), u3 = pk2(p6, p7);
      vpsw(u0, u2);
      vpsw(u1, u3);
      union { unsigned int u[4]; short8 s; } fr;
      fr.u[0] = u0; fr.u[1] = u1; fr.u[2] = u2; fr.u[3] = u3;
      pbf[kb] = fr.s;
    }
  };
  auto pv = [&](int t) {
    const unsigned short* V0 = &lds[12288 + (t & 1) * 4096];
    __builtin_amdgcn_s_setprio(1);
#pragma unroll
    for (int kb = 0; kb < 4; ++kb) {
      int lo = kb * 32 + hi * 16;
      short8 vf0 = *(const short8*)&V0[lq * 64 + ((lo ^ swz0) >> 1)];
      short8 vf1 = *(const short8*)&V0[(32 + lq) * 64 + ((lo ^ swz1) >> 1)];
      o0 = __builtin_amdgcn_mfma_f32_32x32x16_bf16(vf0, pbf[kb], o0, 0, 0, 0);
      o1 = __builtin_amdgcn_mfma_f32_32x32x16_bf16(vf1, pbf[kb], o1, 0, 0, 0);
      lacc = __builtin_amdgcn_mfma_f32_32x32x16_bf16(ones, pbf[kb], lacc, 0, 0, 0);
    }
    __builtin_amdgcn_s_setprio(0);
  };

  const int nkt = Lk / 64;  // even for both Lk=2048 (32) and Lk=512 (8)

  // prologue: K(0)->buf0, V(0)->Vbuf0, K(1)->buf1, then S(0)
  stageK(0, 0);
  loadV(0);
  writeV(0);
  stageK(1, 1);
  __syncthreads();

  f32x16 sA0, sA1, sB0, sB1;
  qk(0, sA0, sA1);

  // pipelined step: QK(t+1)->snew (MFMA) overlaps finish(sold) (VALU); PV(t)
  auto pstep = [&](int t, f32x16& n0, f32x16& n1, f32x16& p0, f32x16& p1) {
    const int tq = t + 1;
    if (tq < nkt) {
      loadV(tq);
      if (tq + 1 < nkt) stageK(tq + 1, (tq + 1) % 3);
      qk(tq % 3, n0, n1);
    }
    finish(p0, p1);
    if (tq < nkt) writeV(tq);
    pv(t);
    __syncthreads();
  };

  for (int t = 0; t < nkt; t += 2) {
    pstep(t, sB0, sB1, sA0, sA1);
    pstep(t + 1, sA0, sA1, sB0, sB1);
  }

  // ---- epilogue: normalize, bounce through LDS, coalesced store ----
  float rl = 1.0f / lacc[0];
  unsigned short* os = &lds[wave * 2048];
#pragma unroll
  for (int t = 0; t < 2; ++t) {
#pragma unroll
    for (int c = 0; c < 4; ++c) {
      int dbase = 32 * t + 8 * c + 4 * hi;
      float v0 = (t ? o1[4 * c + 0] : o0[4 * c + 0]) * rl;
      float v1 = (t ? o1[4 * c + 1] : o0[4 * c + 1]) * rl;
      float v2 = (t ? o1[4 * c + 2] : o0[4 * c + 2]) * rl;
      float v3 = (t ? o1[4 * c + 3] : o0[4 * c + 3]) * rl;
      int by0 = lq * 128 + ((dbase * 2) ^ ((lq & 7) << 4));
      int by1 = lq * 128 + (((dbase + 2) * 2) ^ ((lq & 7) << 4));
      *(unsigned int*)((char*)os + by0) = pk2(v0, v1);
      *(unsigned int*)((char*)os + by1) = pk2(v2, v3);
    }
  }
  int q2 = lane >> 1;
  unsigned short* orow =
      O + ((size_t)b * Lq + qt * 128 + wave * 32 + q2) * D + h * 64;
#pragma unroll
  for (int j = 0; j < 4; ++j) {
    int j2 = (lane & 1) * 4 + j;
    int byr = q2 * 128 + ((j2 * 16) ^ ((q2 & 7) << 4));
    short8 vv = *(const short8*)((char*)os + byr);
    *(short8*)(orow + j2 * 8) = vv;
  }
}

// ---------------------------------------------------------------------------
// Host orchestration
// ---------------------------------------------------------------------------
extern "C" void kernel_launch(void* const* d_in, const int* in_sizes, int n_in,
                              void* d_out, int out_size, void* d_ws, size_t ws_size,
                              hipStream_t stream) {
  (void)in_sizes; (void)n_in; (void)out_size; (void)ws_size;
  const float* x_in = (const float*)d_in[0];
  const float* te   = (const float*)d_in[1];
  const float* ctx  = (const float*)d_in[2];
  const float* rope = (const float*)d_in[3];
  const float* wmod = (const float*)d_in[4];
  const float* bmod = (const float*)d_in[5];
  const float* wqs  = (const float*)d_in[6];
  const float* wks  = (const float*)d_in[7];
  const float* wvs  = (const float*)d_in[8];
  const float* wos  = (const float*)d_in[9];
  const float* bos  = (const float*)d_in[10];
  const float* wqc  = (const float*)d_in[11];
  const float* wkc  = (const float*)d_in[12];
  const float* wvc  = (const float*)d_in[13];
  const float* woc  = (const float*)d_in[14];
  const float* boc  = (const float*)d_in[15];
  const float* w1   = (const float*)d_in[16];
  const float* b1   = (const float*)d_in[17];
  const float* w2   = (const float*)d_in[18];
  const float* b2   = (const float*)d_in[19];
  float* out = (float*)d_out;

  char* w = (char*)d_ws;
  size_t o = 0;
  auto alloc = [&](size_t bytes) {
    char* p = w + o;
    o = (o + bytes + 255) & ~(size_t)255;
    return p;
  };
  unsigned short* wmodT = (unsigned short*)alloc(6144ull * 1024 * 2);
  // wqsT/wksT/wvsT adjacent (fused QKV); wkcT/wvcT adjacent (fused cross-KV).
  unsigned short* wqsT  = (unsigned short*)alloc(1024ull * 1024 * 2);
  unsigned short* wksT  = (unsigned short*)alloc(1024ull * 1024 * 2);
  unsigned short* wvsT  = (unsigned short*)alloc(1024ull * 1024 * 2);
  unsigned short* wosT  = (unsigned short*)alloc(1024ull * 1024 * 2);
  unsigned short* wqcT  = (unsigned short*)alloc(1024ull * 1024 * 2);
  unsigned short* wkcT  = (unsigned short*)alloc(1024ull * 1024 * 2);
  unsigned short* wvcT  = (unsigned short*)alloc(1024ull * 1024 * 2);
  unsigned short* wocT  = (unsigned short*)alloc(1024ull * 1024 * 2);
  unsigned short* w1T   = (unsigned short*)alloc(4096ull * 1024 * 2);
  unsigned short* w2T   = (unsigned short*)alloc(1024ull * 4096 * 2);
  float* modsb = (float*)alloc(2ull * 6144 * 4);
  float2* csT  = (float2*)alloc(2048ull * 64 * 8);
  unsigned short* nx   = (unsigned short*)alloc(4096ull * 1024 * 2);
  unsigned short* ctxb = (unsigned short*)alloc(1024ull * 1024 * 2);
  // qb/kb/vb adjacent: EPI3/EPI4 buffer stride = 4096*1024 elems.
  unsigned short* qb = (unsigned short*)alloc(4096ull * 1024 * 2);
  unsigned short* kb = (unsigned short*)alloc(4096ull * 1024 * 2);
  unsigned short* vb = (unsigned short*)alloc(4096ull * 1024 * 2);
  unsigned short* ao = (unsigned short*)alloc(4096ull * 1024 * 2);
  float* xw = (float*)alloc(4096ull * 1024 * 4);
  unsigned short* hbuf = qb;  // reuse qb..ao contiguous 32MB for MLP hidden

  const float c1 = 0.125f * 1.4426950408889634f;  // scale * log2(e), folded into wqs/wkc

  dim3 tb(32, 8);
  transpose_cast<<<dim3(6144 / 32, 1024 / 32), tb, 0, stream>>>(wmod, wmodT, 1024, 6144, 1.0f);
  TC8 tc8;
  tc8.m[0] = {wqs, wqsT, c1};
  tc8.m[1] = {wks, wksT, 1.0f};
  tc8.m[2] = {wvs, wvsT, 1.0f};
  tc8.m[3] = {wos, wosT, 1.0f};
  tc8.m[4] = {wqc, wqcT, 1.0f};
  tc8.m[5] = {wkc, wkcT, c1};
  tc8.m[6] = {wvc, wvcT, 1.0f};
  tc8.m[7] = {woc, wocT, 1.0f};
  transpose_cast8<<<dim3(32, 32, 8), tb, 0, stream>>>(tc8);
  transpose_cast<<<dim3(4096 / 32, 1024 / 32), tb, 0, stream>>>(w1, w1T, 1024, 4096, 1.0f);
  transpose_cast<<<dim3(1024 / 32, 4096 / 32), tb, 0, stream>>>(w2, w2T, 4096, 1024, 1.0f);

  cast_bf16<<<4096, 256, 0, stream>>>(ctx, ctxb, 1024 * 1024);
  rope_tab<<<512, 256, 0, stream>>>(rope, csT, 2048 * 64);
  mods_kernel<<<3072, 256, 0, stream>>>(te, wmodT, bmod, modsb);

  // --- self-attention (RoPE fused into QKV epilogue) ---
  ln_mod<<<4096, 256, 0, stream>>>(x_in, modsb, nx, 1024, 0);
  gemm_pipe<4><<<768, 256, 0, stream>>>(nx, wqsT, qb, (const float*)csT, nullptr, -1, nullptr, 4096, 3072, 1024, 2048, 2);
  flash2<<<512, 256, 0, stream>>>(qb, kb, vb, ao, 2048);
  gemm_p2<2><<<512, 256, 0, stream>>>(ao, wosT, xw, bos, modsb, 2048, x_in, 4096, 1024, 1024, 2048, 8);

  // --- cross-attention ---
  ln_mod<<<4096, 256, 0, stream>>>(xw, modsb, nx, -1, -1);
  gemm_p2<0><<<512, 256, 0, stream>>>(nx, wqcT, qb, nullptr, nullptr, -1, nullptr, 4096, 1024, 1024, 2048, 8);
  gemm_p2<3><<<256, 256, 0, stream>>>(ctxb, wkcT, kb, nullptr, nullptr, -1, nullptr, 1024, 2048, 1024, 512, 16);
  flash2<<<512, 256, 0, stream>>>(qb, kb, vb, ao, 512);
  gemm_p2<2><<<512, 256, 0, stream>>>(ao, wocT, xw, boc, modsb, -1, xw, 4096, 1024, 1024, 2048, 8);

  // --- MLP ---
  ln_mod<<<4096, 256, 0, stream>>>(xw, modsb, nx, 4096, 3072);
  gemm_bt<1><<<dim3(32, 32), 256, 0, stream>>>(nx, w1T, hbuf, b1, nullptr, -1, nullptr, 4096, 4096, 1024, 2048);
  gemm_p2<2><<<512, 256, 0, stream>>>(hbuf, w2T, out, b2, modsb, 5120, xw, 4096, 1024, 4096, 2048, 8);
}

// Round 6
// 386.270 us; speedup vs baseline: 1.1327x; 1.0383x over previous
//
#include <hip/hip_runtime.h>
#include <hip/hip_bf16.h>

// ---------------------------------------------------------------------------
// CleanDITBlock: adaLN-modulated DiT block (self-attn w/ RoPE, cross-attn, MLP)
// B=2, L=2048, S=512, D=1024, H=16, HD=64, CTX=1024, HID=4096
// ---------------------------------------------------------------------------

typedef short short8 __attribute__((ext_vector_type(8)));
typedef float f32x4 __attribute__((ext_vector_type(4)));
typedef float f32x16 __attribute__((ext_vector_type(16)));

#define DEV __device__ __forceinline__

DEV unsigned short f2b(float f) {
  __hip_bfloat16 h = __float2bfloat16(f);
  return *reinterpret_cast<unsigned short*>(&h);
}
DEV float b2f(unsigned short u) {
  unsigned int x = ((unsigned int)u) << 16;
  return __builtin_bit_cast(float, x);
}
// single-instruction packed f32->bf16 pair (T12): D[15:0]=bf16(lo), D[31:16]=bf16(hi)
DEV unsigned int pk2(float lo, float hi) {
  unsigned int r;
  asm("v_cvt_pk_bf16_f32 %0, %1, %2" : "=v"(r) : "v"(lo), "v"(hi));
  return r;
}
// lane[i]<->lane[i+32] half-swap (VALU, no LDS)
DEV void vpsw(unsigned int& a, unsigned int& b) {
  asm("v_permlane32_swap_b32 %0, %1" : "+v"(a), "+v"(b));
}
// 3-input max (T17)
DEV float max3f(float a, float b, float c) {
  float r;
  asm("v_max3_f32 %0, %1, %2, %3" : "=v"(r) : "v"(a), "v"(b), "v"(c));
  return r;
}

#define GLB(p) ((const __attribute__((address_space(1))) void*)(p))
#define LDSP(p) ((__attribute__((address_space(3))) void*)(p))

// ---------------------------------------------------------------------------
// prep: ALL preprocessing in one launch (flattened grid, range decode).
//   [0,6144)      wmod transpose  (1024x6144 -> 6144x1024)
//   [6144,14336)  8 square 1024^2 transposes (wq/wk/wv/wo self+cross)
//   [14336,18432) w1 transpose (1024x4096 -> 4096x1024)
//   [18432,22528) w2 transpose (4096x1024 -> 1024x4096)
//   [22528,26624) ctx f32->bf16 cast (1M elems)
//   [26624,27136) rope (cos,sin) table (131072 elems)
// ---------------------------------------------------------------------------
struct TCB { const float* in; unsigned short* out; float scale; };
struct PrepArgs {
  const float* wmod; unsigned short* wmodT;
  TCB sq[8];
  const float* w1; unsigned short* w1T;
  const float* w2; unsigned short* w2T;
  const float* ctx; unsigned short* ctxb;
  const float* rope; float2* cs;
};

__global__ __launch_bounds__(256) void prep(PrepArgs a) {
  __shared__ float t32[32][33];
  const int blk = blockIdx.x;
  const int tx = threadIdx.x & 31, ty = threadIdx.x >> 5;
  if (blk < 22528) {
    const float* in;
    unsigned short* out;
    int R, C, gx, tile;
    float scale;
    if (blk < 6144) {
      in = a.wmod; out = a.wmodT; R = 1024; C = 6144; gx = 192; tile = blk; scale = 1.f;
    } else if (blk < 14336) {
      int j = (blk - 6144) >> 10;
      tile = (blk - 6144) & 1023;
      in = a.sq[j].in; out = a.sq[j].out; scale = a.sq[j].scale;
      R = 1024; C = 1024; gx = 32;
    } else if (blk < 18432) {
      tile = blk - 14336;
      in = a.w1; out = a.w1T; R = 1024; C = 4096; gx = 128; scale = 1.f;
    } else {
      tile = blk - 18432;
      in = a.w2; out = a.w2T; R = 4096; C = 1024; gx = 32; scale = 1.f;
    }
    int bx = (tile % gx) * 32, by = (tile / gx) * 32;
#pragma unroll
    for (int i = ty; i < 32; i += 8)
      t32[i][tx] = in[(size_t)(by + i) * C + bx + tx];
    __syncthreads();
#pragma unroll
    for (int i = ty; i < 32; i += 8)
      out[(size_t)(bx + i) * R + by + tx] = f2b(t32[tx][i] * scale);
  } else if (blk < 26624) {
    int i = (blk - 22528) * 256 + threadIdx.x;
    a.ctxb[i] = f2b(a.ctx[i]);
  } else {
    int i = (blk - 26624) * 256 + threadIdx.x;
    float v = a.rope[i];
    a.cs[i] = make_float2(cosf(v), sinf(v));
  }
}

// ---------------------------------------------------------------------------
__global__ __launch_bounds__(256) void mods_kernel(
    const float* __restrict__ te, const unsigned short* __restrict__ wmodT,
    const float* __restrict__ bmod, float* __restrict__ mods) {
  int w = blockIdx.x * 4 + (threadIdx.x >> 6);
  int lane = threadIdx.x & 63;
  int b = w / 6144, j = w % 6144;
  const unsigned short* wr = wmodT + (size_t)j * 1024;
  const float* ter = te + (size_t)b * 1024;
  int k0 = lane * 16;
  float sum = 0.f;
#pragma unroll
  for (int u = 0; u < 2; ++u) {
    short8 wv = *(const short8*)(wr + k0 + u * 8);
#pragma unroll
    for (int e = 0; e < 8; ++e)
      sum += b2f((unsigned short)wv[e]) * ter[k0 + u * 8 + e];
  }
#pragma unroll
  for (int off = 32; off >= 1; off >>= 1) sum += __shfl_down(sum, off);
  if (lane == 0) mods[(size_t)b * 6144 + j] = sum + bmod[j];
}

// ---------------------------------------------------------------------------
__global__ __launch_bounds__(256) void ln_mod(
    const float* __restrict__ x, const float* __restrict__ mods,
    unsigned short* __restrict__ out, int scale_ofs, int shift_ofs) {
  int row = blockIdx.x;
  int b = row >> 11;
  int tid = threadIdx.x;
  const float* xr = x + (size_t)row * 1024;
  float4 v = ((const float4*)xr)[tid];
  float s = v.x + v.y + v.z + v.w;
  float ss = v.x * v.x + v.y * v.y + v.z * v.z + v.w * v.w;
#pragma unroll
  for (int off = 32; off >= 1; off >>= 1) {
    s += __shfl_down(s, off);
    ss += __shfl_down(ss, off);
  }
  __shared__ float red[8];
  int wave = tid >> 6, lane = tid & 63;
  if (lane == 0) { red[wave] = s; red[4 + wave] = ss; }
  __syncthreads();
  if (tid == 0) {
    float S = red[0] + red[1] + red[2] + red[3];
    float SS = red[4] + red[5] + red[6] + red[7];
    float mu = S * (1.f / 1024.f);
    red[0] = mu;
    red[1] = SS * (1.f / 1024.f) - mu * mu;
  }
  __syncthreads();
  float mu = red[0];
  float rs = rsqrtf(red[1] + 1e-6f);
  float vv[4] = {v.x, v.y, v.z, v.w};
  unsigned short o[4];
#pragma unroll
  for (int c = 0; c < 4; ++c) {
    int col = tid * 4 + c;
    float nv = (vv[c] - mu) * rs;
    if (scale_ofs >= 0)
      nv = nv * (1.f + mods[(size_t)b * 6144 + scale_ofs + col]) +
           mods[(size_t)b * 6144 + shift_ofs + col];
    o[c] = f2b(nv);
  }
  *(ushort4*)(&out[(size_t)row * 1024 + tid * 4]) = *(const ushort4*)o;
}

// ---------------------------------------------------------------------------
// Shared GEMM epilogue.  EPI: 0 bf16; 1 bias+GELU bf16; 2 f32 residual
// src + gate*(acc+bias); 3 bf16 split-store (buffer = col>>10, row stride 1024,
// buffer stride 4096*1024).
// ---------------------------------------------------------------------------
template <int EPI, int MI, int NJ>
DEV void gemm_epilogue(f32x4 (&acc)[MI][NJ], void* Cout, const float* bias,
                       const float* mods, int gate_ofs, const float* src,
                       int N, int rowsPerB, int m0, int n0, int wm, int wn,
                       int g, int r) {
#pragma unroll
  for (int i = 0; i < MI; ++i) {
#pragma unroll
    for (int j = 0; j < NJ; ++j) {
#pragma unroll
      for (int q = 0; q < 4; ++q) {
        size_t grow = (size_t)(m0 + wm + i * 16 + g * 4 + q);
        size_t gcol = (size_t)(n0 + wn + j * 16 + r);
        float v = acc[i][j][q];
        if constexpr (EPI == 0) {
          ((unsigned short*)Cout)[grow * N + gcol] = f2b(v);
        } else if constexpr (EPI == 1) {
          v += bias[gcol];
          float ge = 0.5f * v * (1.0f + erff(v * 0.70710678f));
          ((unsigned short*)Cout)[grow * N + gcol] = f2b(ge);
        } else if constexpr (EPI == 3) {
          size_t buf = gcol >> 10;
          ((unsigned short*)Cout)[buf * (4096ull * 1024) + grow * 1024 + (gcol & 1023)] = f2b(v);
        } else {
          v += bias[gcol];
          float gate = 1.0f;
          if (gate_ofs >= 0)
            gate = mods[(grow / rowsPerB) * 6144 + gate_ofs + gcol];
          ((float*)Cout)[grow * N + gcol] = src[grow * N + gcol] + gate * v;
        }
      }
    }
  }
}

// ---------------------------------------------------------------------------
// QKV epilogue with fused RoPE (EPI 4).  j-tiles are head-aligned: d=j*16+r,
// rotation pair (d,d+32) = (acc[i][j], acc[i][j+2]) in the SAME lane.  Applies
// rope to buffers 0 (q) and 1 (k); buffer 2 (v) stored plain.  cs = interleaved
// (cos,sin)[l][d].
// ---------------------------------------------------------------------------
DEV void qkv_rope_epilogue(f32x4 (&acc)[4][4], unsigned short* Cout,
                           const float2* cs, int m0, int n0, int wm, int wn,
                           int g, int r) {
  const int buf = (n0 + wn) >> 10;      // wave-uniform
  const int colbase = (n0 + wn) & 1023;
  unsigned short* base = Cout + (size_t)buf * (4096ull * 1024);
#pragma unroll
  for (int i = 0; i < 4; ++i) {
#pragma unroll
    for (int q = 0; q < 4; ++q) {
      size_t grow = (size_t)(m0 + wm + i * 16 + g * 4 + q);
      unsigned short* orow = base + grow * 1024 + colbase + r;
      if (buf < 2) {
        int l = (int)(grow & 2047);
#pragma unroll
        for (int j = 0; j < 2; ++j) {
          int d = j * 16 + r;
          float2 a = cs[l * 64 + d];
          float2 bb = cs[l * 64 + d + 32];
          float x1 = acc[i][j][q], x2 = acc[i][j + 2][q];
          orow[j * 16] = f2b(x1 * a.x - x2 * a.y);
          orow[(j + 2) * 16] = f2b(x2 * bb.x + x1 * bb.y);
        }
      } else {
#pragma unroll
        for (int j = 0; j < 4; ++j) orow[j * 16] = f2b(acc[i][j][q]);
      }
    }
  }
}

// ---------------------------------------------------------------------------
// GEMM (m97): 128x128, BK=32, implicit overlap.  For >=4 blocks/CU (mlp1).
// ---------------------------------------------------------------------------
template <int EPI>
__global__ __launch_bounds__(256, 2) void gemm_bt(
    const unsigned short* __restrict__ A, const unsigned short* __restrict__ Bt,
    void* __restrict__ Cout, const float* __restrict__ bias,
    const float* __restrict__ mods, int gate_ofs, const float* __restrict__ src,
    int M, int N, int K, int rowsPerB) {
  __shared__ unsigned short As[128 * 32];
  __shared__ unsigned short Bs[128 * 32];
  const int tid = threadIdx.x;
  const int wave = tid >> 6, lane = tid & 63;
  const int g = lane >> 4, r = lane & 15;
  const int m0 = blockIdx.y * 128, n0 = blockIdx.x * 128;
  const int wm = (wave >> 1) * 64, wn = (wave & 1) * 64;
  const int srow = lane >> 2;
  const int scol = (lane & 3) * 8;

  f32x4 acc[4][4] = {};

  for (int k0 = 0; k0 < K; k0 += 32) {
    __syncthreads();
#pragma unroll
    for (int cc = 0; cc < 4; ++cc) {
      int c = wave * 4 + cc;
      int isB = c >> 3;
      int cl = c & 7;
      int row = cl * 16 + srow;
      const unsigned short* gsrc =
          isB ? (Bt + (size_t)(n0 + row) * K + k0 + scol)
              : (A + (size_t)(m0 + row) * K + k0 + scol);
      unsigned short* ldst = (isB ? Bs : As) + cl * 512;
      __builtin_amdgcn_global_load_lds(GLB(gsrc), LDSP(ldst), 16, 0, 0);
    }
    __syncthreads();

    short8 bfr[4];
#pragma unroll
    for (int j = 0; j < 4; ++j)
      bfr[j] = *(const short8*)(&Bs[(wn + j * 16 + r) * 32 + g * 8]);
#pragma unroll
    for (int i = 0; i < 4; ++i) {
      short8 af = *(const short8*)(&As[(wm + i * 16 + r) * 32 + g * 8]);
#pragma unroll
      for (int j = 0; j < 4; ++j)
        acc[i][j] = __builtin_amdgcn_mfma_f32_16x16x32_bf16(af, bfr[j], acc[i][j], 0, 0, 0);
    }
  }
  gemm_epilogue<EPI, 4, 4>(acc, Cout, bias, mods, gate_ofs, src, N, rowsPerB,
                           m0, n0, wm, wn, g, r);
}

// ---------------------------------------------------------------------------
// GEMM (pipelined 128x128): BK=64, 4 LDS bufs, depth-3, counted vmcnt.
// For ~3 blocks/CU grids (QKV).  XCD-grouped decode via mshift.
// EPI==4: fused-RoPE QKV epilogue (cs table passed via `bias`).
// ---------------------------------------------------------------------------
template <int EPI>
__global__ __launch_bounds__(256) void gemm_pipe(
    const unsigned short* __restrict__ A, const unsigned short* __restrict__ Bt,
    void* __restrict__ Cout, const float* __restrict__ bias,
    const float* __restrict__ mods, int gate_ofs, const float* __restrict__ src,
    int M, int N, int K, int rowsPerB, int mshift) {
  __shared__ unsigned short lds[4 * 16384];
  const int tid = threadIdx.x;
  const int wave = tid >> 6, lane = tid & 63;
  const int g = lane >> 4, r = lane & 15;
  const int flat = blockIdx.x;
  const int xcd = flat & 7, idx = flat >> 3;
  const int mt = xcd * (1 << mshift) + (idx & ((1 << mshift) - 1));
  const int nt = idx >> mshift;
  const int m0 = mt * 128, n0 = nt * 128;
  const int wm = (wave >> 1) * 64, wn = (wave & 1) * 64;
  const int srow8 = lane >> 3;
  const int sck = (lane & 7) ^ srow8;

  f32x4 acc[4][4] = {};

  auto stage = [&](int t, int bufi) {
    const int k0 = t * 64;
#pragma unroll
    for (int i = 0; i < 8; ++i) {
      int u = wave * 8 + i;
      int isB = u >> 4;
      int uu = u & 15;
      int rl = uu * 8 + srow8;
      const unsigned short* gsrc =
          (isB ? (Bt + (size_t)(n0 + rl) * K) : (A + (size_t)(m0 + rl) * K)) +
          k0 + sck * 8;
      unsigned short* dst = (unsigned short*)lds + bufi * 16384 + isB * 8192 + uu * 512;
      __builtin_amdgcn_global_load_lds(GLB(gsrc), LDSP(dst), 16, 0, 0);
    }
  };

  const int nt_k = K / 64;
  stage(0, 0);
  stage(1, 1);
  stage(2, 2);

  for (int t = 0; t < nt_k; ++t) {
    int rem = nt_k - t;
    if (rem >= 3) {
      asm volatile("s_waitcnt vmcnt(16)" ::: "memory");
    } else if (rem == 2) {
      asm volatile("s_waitcnt vmcnt(8)" ::: "memory");
    } else {
      asm volatile("s_waitcnt vmcnt(0)" ::: "memory");
    }
    __builtin_amdgcn_sched_barrier(0);
    __builtin_amdgcn_s_barrier();
    __builtin_amdgcn_sched_barrier(0);
    if (t + 3 < nt_k) stage(t + 3, (t + 3) & 3);

    const unsigned short* Ab = (const unsigned short*)lds + (t & 3) * 16384;
    const unsigned short* Bb = Ab + 8192;
#pragma unroll
    for (int ks = 0; ks < 2; ++ks) {
      short8 bfr[4];
#pragma unroll
      for (int j = 0; j < 4; ++j) {
        int row = wn + j * 16 + r;
        bfr[j] = *(const short8*)&Bb[row * 64 + ((g + ks * 4) ^ (r & 7)) * 8];
      }
#pragma unroll
      for (int i = 0; i < 4; ++i) {
        int row = wm + i * 16 + r;
        short8 af = *(const short8*)&Ab[row * 64 + ((g + ks * 4) ^ (r & 7)) * 8];
#pragma unroll
        for (int j = 0; j < 4; ++j)
          acc[i][j] = __builtin_amdgcn_mfma_f32_16x16x32_bf16(af, bfr[j], acc[i][j], 0, 0, 0);
      }
    }
  }
  if constexpr (EPI == 4) {
    qkv_rope_epilogue(acc, (unsigned short*)Cout, (const float2*)bias,
                      m0, n0, wm, wn, g, r);
  } else {
    gemm_epilogue<EPI, 4, 4>(acc, Cout, bias, mods, gate_ofs, src, N, rowsPerB,
                             m0, n0, wm, wn, g, r);
  }
}

// ---------------------------------------------------------------------------
// GEMM (64x128 tile, 2-blocks/CU): 4 waves of 32x64, BK=64, 3 LDS bufs (72KB),
// depth-2 counted vmcnt(6).  Grid = (M/64)*(N/128); nt = flat % ntn puts one
// B-panel per XCD when ntn==8.  For the grid-256-at-128x128 GEMMs.
// ---------------------------------------------------------------------------
template <int EPI>
__global__ __launch_bounds__(256) void gemm_p2(
    const unsigned short* __restrict__ A, const unsigned short* __restrict__ Bt,
    void* __restrict__ Cout, const float* __restrict__ bias,
    const float* __restrict__ mods, int gate_ofs, const float* __restrict__ src,
    int M, int N, int K, int rowsPerB, int ntn) {
  __shared__ unsigned short lds[3 * 12288];  // per buf: A 64x64 (8KB) | B 128x64 (16KB)
  const int tid = threadIdx.x;
  const int wave = tid >> 6, lane = tid & 63;
  const int g = lane >> 4, r = lane & 15;
  const int flat = blockIdx.x;
  const int nt = flat % ntn, mt = flat / ntn;
  const int m0 = mt * 64, n0 = nt * 128;
  const int wm = (wave >> 1) * 32, wn = (wave & 1) * 64;
  const int srow8 = lane >> 3;
  const int sck = (lane & 7) ^ srow8;

  f32x4 acc[2][4] = {};

  auto stage = [&](int t, int bufi) {
    const int k0 = t * 64;
    unsigned short* base = (unsigned short*)lds + bufi * 12288;
#pragma unroll
    for (int i = 0; i < 2; ++i) {  // A units: 8 of 64 rows
      int u = wave * 2 + i;
      int rl = u * 8 + srow8;
      const unsigned short* gsrc = A + (size_t)(m0 + rl) * K + k0 + sck * 8;
      __builtin_amdgcn_global_load_lds(GLB(gsrc), LDSP(base + u * 512), 16, 0, 0);
    }
#pragma unroll
    for (int i = 0; i < 4; ++i) {  // B units: 16 of 128 rows
      int u = wave * 4 + i;
      int rl = u * 8 + srow8;
      const unsigned short* gsrc = Bt + (size_t)(n0 + rl) * K + k0 + sck * 8;
      __builtin_amdgcn_global_load_lds(GLB(gsrc), LDSP(base + 4096 + u * 512), 16, 0, 0);
    }
  };

  const int ntk = K / 64;
  stage(0, 0);
  stage(1, 1);
  int cbuf = 0, sbuf = 2;

  for (int t = 0; t < ntk; ++t) {
    if (t < ntk - 1) {
      asm volatile("s_waitcnt vmcnt(6)" ::: "memory");
    } else {
      asm volatile("s_waitcnt vmcnt(0)" ::: "memory");
    }
    __builtin_amdgcn_sched_barrier(0);
    __builtin_amdgcn_s_barrier();
    __builtin_amdgcn_sched_barrier(0);
    if (t + 2 < ntk) {
      stage(t + 2, sbuf);
      sbuf = (sbuf == 2) ? 0 : sbuf + 1;
    }

    const unsigned short* Ab = (const unsigned short*)lds + cbuf * 12288;
    const unsigned short* Bb = Ab + 4096;
#pragma unroll
    for (int ks = 0; ks < 2; ++ks) {
      short8 bfr[4];
#pragma unroll
      for (int j = 0; j < 4; ++j) {
        int row = wn + j * 16 + r;
        bfr[j] = *(const short8*)&Bb[row * 64 + ((g + ks * 4) ^ (r & 7)) * 8];
      }
#pragma unroll
      for (int i = 0; i < 2; ++i) {
        int row = wm + i * 16 + r;
        short8 af = *(const short8*)&Ab[row * 64 + ((g + ks * 4) ^ (r & 7)) * 8];
#pragma unroll
        for (int j = 0; j < 4; ++j)
          acc[i][j] = __builtin_amdgcn_mfma_f32_16x16x32_bf16(af, bfr[j], acc[i][j], 0, 0, 0);
      }
    }
    cbuf = (cbuf == 2) ? 0 : cbuf + 1;
  }
  gemm_epilogue<EPI, 2, 4>(acc, Cout, bias, mods, gate_ofs, src, N, rowsPerB,
                           m0, n0, wm, wn, g, r);
}

// ---------------------------------------------------------------------------
// gemm_cross: fused cross-attention Q-proj + KV-proj in ONE launch (768 blk).
//   blocks [0,512):   q = nx(4096x1024) @ wqcT,  N=1024, ntn=8  -> qb (bf16)
//   blocks [512,768): kv = ctxb(1024x1024) @ wkcT(+wvcT adj), N=2048, ntn=16
//                     -> kb/vb split-store (EPI3 layout)
// Same gemm_p2 64x128 structure; 3 blocks/CU occupancy (was 2 + 1 serial).
// ---------------------------------------------------------------------------
__global__ __launch_bounds__(256) void gemm_cross(
    const unsigned short* __restrict__ Anx, const unsigned short* __restrict__ Bq,
    unsigned short* __restrict__ Oq,
    const unsigned short* __restrict__ Actx, const unsigned short* __restrict__ Bkv,
    unsigned short* __restrict__ Okv) {
  __shared__ unsigned short lds[3 * 12288];
  const int tid = threadIdx.x;
  const int wave = tid >> 6, lane = tid & 63;
  const int g = lane >> 4, r = lane & 15;
  const bool iskv = blockIdx.x >= 512;
  const int flat = iskv ? (blockIdx.x - 512) : blockIdx.x;
  const int ntn = iskv ? 16 : 8;
  const unsigned short* A = iskv ? Actx : Anx;
  const unsigned short* Bt = iskv ? Bkv : Bq;
  const int nt = flat % ntn, mt = flat / ntn;
  const int m0 = mt * 64, n0 = nt * 128;
  const int K = 1024;
  const int wm = (wave >> 1) * 32, wn = (wave & 1) * 64;
  const int srow8 = lane >> 3;
  const int sck = (lane & 7) ^ srow8;

  f32x4 acc[2][4] = {};

  auto stage = [&](int t, int bufi) {
    const int k0 = t * 64;
    unsigned short* base = (unsigned short*)lds + bufi * 12288;
#pragma unroll
    for (int i = 0; i < 2; ++i) {
      int u = wave * 2 + i;
      int rl = u * 8 + srow8;
      const unsigned short* gsrc = A + (size_t)(m0 + rl) * K + k0 + sck * 8;
      __builtin_amdgcn_global_load_lds(GLB(gsrc), LDSP(base + u * 512), 16, 0, 0);
    }
#pragma unroll
    for (int i = 0; i < 4; ++i) {
      int u = wave * 4 + i;
      int rl = u * 8 + srow8;
      const unsigned short* gsrc = Bt + (size_t)(n0 + rl) * K + k0 + sck * 8;
      __builtin_amdgcn_global_load_lds(GLB(gsrc), LDSP(base + 4096 + u * 512), 16, 0, 0);
    }
  };

  const int ntk = K / 64;
  stage(0, 0);
  stage(1, 1);
  int cbuf = 0, sbuf = 2;

  for (int t = 0; t < ntk; ++t) {
    if (t < ntk - 1) {
      asm volatile("s_waitcnt vmcnt(6)" ::: "memory");
    } else {
      asm volatile("s_waitcnt vmcnt(0)" ::: "memory");
    }
    __builtin_amdgcn_sched_barrier(0);
    __builtin_amdgcn_s_barrier();
    __builtin_amdgcn_sched_barrier(0);
    if (t + 2 < ntk) {
      stage(t + 2, sbuf);
      sbuf = (sbuf == 2) ? 0 : sbuf + 1;
    }

    const unsigned short* Ab = (const unsigned short*)lds + cbuf * 12288;
    const unsigned short* Bb = Ab + 4096;
#pragma unroll
    for (int ks = 0; ks < 2; ++ks) {
      short8 bfr[4];
#pragma unroll
      for (int j = 0; j < 4; ++j) {
        int row = wn + j * 16 + r;
        bfr[j] = *(const short8*)&Bb[row * 64 + ((g + ks * 4) ^ (r & 7)) * 8];
      }
#pragma unroll
      for (int i = 0; i < 2; ++i) {
        int row = wm + i * 16 + r;
        short8 af = *(const short8*)&Ab[row * 64 + ((g + ks * 4) ^ (r & 7)) * 8];
#pragma unroll
        for (int j = 0; j < 4; ++j)
          acc[i][j] = __builtin_amdgcn_mfma_f32_16x16x32_bf16(af, bfr[j], acc[i][j], 0, 0, 0);
      }
    }
    cbuf = (cbuf == 2) ? 0 : cbuf + 1;
  }

#pragma unroll
  for (int i = 0; i < 2; ++i) {
#pragma unroll
    for (int j = 0; j < 4; ++j) {
#pragma unroll
      for (int q = 0; q < 4; ++q) {
        size_t grow = (size_t)(m0 + wm + i * 16 + g * 4 + q);
        size_t gcol = (size_t)(n0 + wn + j * 16 + r);
        float v = acc[i][j][q];
        if (iskv) {
          size_t buf = gcol >> 10;
          Okv[buf * (4096ull * 1024) + grow * 1024 + (gcol & 1023)] = f2b(v);
        } else {
          Oq[grow * 1024 + gcol] = f2b(v);
        }
      }
    }
  }
}

// ---------------------------------------------------------------------------
// Flash attention v9 (converged): 128 q/block, T15 pipeline, cvt_pk, max3,
// fused-scale, perm V-pack, setprio(PV).  Blind VALU edits exhausted — frozen.
// ---------------------------------------------------------------------------
__global__ __launch_bounds__(256, 2) void flash2(
    const unsigned short* __restrict__ Q, const unsigned short* __restrict__ Kv,
    const unsigned short* __restrict__ Vv, unsigned short* __restrict__ O,
    int Lk) {
  __shared__ unsigned short lds[20480];  // 40KB: K 3x8KB @0 | V^T 2x8KB @12288
  const int tid = threadIdx.x, wave = tid >> 6, lane = tid & 63;
  const int hi = lane >> 5, lq = lane & 31;
  const int flat = blockIdx.x;
  const int xcd = flat & 7, rr = flat >> 3;
  const int gl = rr >> 4, qt = rr & 15;
  const int g = xcd * 4 + gl;
  const int h = g & 15, b = g >> 4;
  const int Lq = 2048, D = 1024;

  const unsigned short* Qbase =
      Q + ((size_t)b * Lq + qt * 128 + wave * 32 + lq) * D + h * 64;
  const unsigned short* Kbase = Kv + (size_t)b * Lk * D + h * 64;
  const unsigned short* Vbase = Vv + (size_t)b * Lk * D + h * 64;

  short8 qf[4];
#pragma unroll
  for (int kb = 0; kb < 4; ++kb)
    qf[kb] = *(const short8*)(Qbase + kb * 16 + hi * 8);

  const short8 ones = {0x3F80, 0x3F80, 0x3F80, 0x3F80, 0x3F80, 0x3F80, 0x3F80, 0x3F80};
  const f32x16 z16 = {};  // persistent zero C-operand

  const int kr0 = tid >> 3, kc0 = tid & 7;   // K stage: row, chunk
  const int kvp = tid >> 3, db = tid & 7;    // V stage: kv-pair, d-block
  const int kch0 = (kc0 ^ (kr0 & 7) ^ (kr0 >> 3)) & 7;
  const int kch1 = kch0 ^ 4;
  const int f0 = (lq & 7) ^ (lq >> 3);
  const int swz0 = f0 << 4, swz1 = swz0 ^ 64;

  // kt-invariant V^T write byte-offsets (per-thread constants, reg-resident)
  int vby[8];
#pragma unroll
  for (int e = 0; e < 8; ++e) {
    int d = db * 8 + e;
    vby[e] = d * 128 + ((kvp * 4) ^ (((e ^ db) & 7) << 4));
  }

  float m_run = -3.0e38f;
  f32x16 o0 = {}, o1 = {}, lacc = {};
  short8 vr0, vr1;
  short8 pbf[4];

  auto stageK = [&](int t, int bi) {
    const unsigned short* s0 = Kbase + (size_t)(t * 64 + kr0) * D + kch0 * 8;
    const unsigned short* s1 = Kbase + (size_t)(t * 64 + kr0 + 32) * D + kch1 * 8;
    __builtin_amdgcn_global_load_lds(GLB(s0), LDSP(&lds[bi * 4096 + wave * 512]), 16, 0, 0);
    __builtin_amdgcn_global_load_lds(GLB(s1), LDSP(&lds[bi * 4096 + 2048 + wave * 512]), 16, 0, 0);
  };
  auto loadV = [&](int t) {
    const unsigned short* v0 = Vbase + (size_t)(t * 64 + 2 * kvp) * D + db * 8;
    vr0 = *(const short8*)v0;
    vr1 = *(const short8*)(v0 + D);
  };
  auto writeV = [&](int t) {
    char* vt = (char*)&lds[12288 + (t & 1) * 4096];
    union { short8 s; unsigned int u[4]; } a, c;
    a.s = vr0; c.s = vr1;
#pragma unroll
    for (int k = 0; k < 4; ++k) {
      *(unsigned int*)(vt + vby[2 * k]) =
          __builtin_amdgcn_perm(c.u[k], a.u[k], 0x05040100u);
      *(unsigned int*)(vt + vby[2 * k + 1]) =
          __builtin_amdgcn_perm(c.u[k], a.u[k], 0x07060302u);
    }
  };
  auto qk = [&](int bi, f32x16& sa0, f32x16& sa1) {
    const unsigned short* K0 = &lds[bi * 4096];
    {
      int lo = hi * 16;
      short8 a0 = *(const short8*)&K0[lq * 64 + ((lo ^ swz0) >> 1)];
      short8 a1 = *(const short8*)&K0[(32 + lq) * 64 + ((lo ^ swz1) >> 1)];
      sa0 = __builtin_amdgcn_mfma_f32_32x32x16_bf16(a0, qf[0], z16, 0, 0, 0);
      sa1 = __builtin_amdgcn_mfma_f32_32x32x16_bf16(a1, qf[0], z16, 0, 0, 0);
    }
#pragma unroll
    for (int ks = 1; ks < 4; ++ks) {
      int lo = ks * 32 + hi * 16;
      short8 a0 = *(const short8*)&K0[lq * 64 + ((lo ^ swz0) >> 1)];
      short8 a1 = *(const short8*)&K0[(32 + lq) * 64 + ((lo ^ swz1) >> 1)];
      sa0 = __builtin_amdgcn_mfma_f32_32x32x16_bf16(a0, qf[ks], sa0, 0, 0, 0);
      sa1 = __builtin_amdgcn_mfma_f32_32x32x16_bf16(a1, qf[ks], sa1, 0, 0, 0);
    }
  };
  auto finish = [&](f32x16& s0a, f32x16& s1a) {
    float tm[8];
#pragma unroll
    for (int i = 0; i < 8; ++i)
      tm[i] = fmaxf(max3f(s0a[i], s0a[i + 8], s1a[i]), s1a[i + 8]);
    float x = max3f(tm[0], tm[1], tm[2]);
    float y = max3f(tm[3], tm[4], tm[5]);
    float pm = fmaxf(max3f(tm[6], tm[7], x), y);
    {
      unsigned int ua = __builtin_bit_cast(unsigned int, pm), ub = ua;
      vpsw(ua, ub);
      pm = fmaxf(__builtin_bit_cast(float, ua), __builtin_bit_cast(float, ub));
    }
    if (__any(pm - m_run > 8.0f)) {
      float mnew = fmaxf(m_run, pm);
      float alpha = exp2f(m_run - mnew);
      lacc[0] *= alpha;
#pragma unroll
      for (int i = 0; i < 16; ++i) { o0[i] *= alpha; o1[i] *= alpha; }
      m_run = mnew;
    }
    float mc = m_run;
#pragma unroll
    for (int i = 0; i < 16; ++i) s0a[i] = exp2f(s0a[i] - mc);
#pragma unroll
    for (int i = 0; i < 16; ++i) s1a[i] = exp2f(s1a[i] - mc);
#pragma unroll
    for (int kb = 0; kb < 4; ++kb) {
      int bb = (kb & 1) * 8;
      float p0, p1, p2, p3, p4, p5, p6, p7;
      if (kb < 2) {
        p0 = s0a[bb + 0]; p1 = s0a[bb + 1]; p2 = s0a[bb + 2]; p3 = s0a[bb + 3];
        p4 = s0a[bb + 4]; p5 = s0a[bb + 5]; p6 = s0a[bb + 6]; p7 = s0a[bb + 7];
      } else {
        p0 = s1a[bb + 0]; p1 = s1a[bb + 1]; p2 = s1a[bb + 2]; p3 = s1a[bb + 3];
        p4 = s1a[bb + 4]; p5 = s1a[bb + 5]; p6 = s1a[bb + 6]; p7 = s1a[bb + 7];
      }
      unsigned int u0 = pk2(p0, p1), u1 = pk2(p2, p3);
      unsigned int u2 = pk2(p4, p5), u3 = pk2(p6, p7);
      vpsw(u0, u2);
      vpsw(u1, u3);
      union { unsigned int u[4]; short8 s; } fr;
      fr.u[0] = u0; fr.u[1] = u1; fr.u[2] = u2; fr.u[3] = u3;
      pbf[kb] = fr.s;
    }
  };
  auto pv = [&](int t) {
    const unsigned short* V0 = &lds[12288 + (t & 1) * 4096];
    __builtin_amdgcn_s_setprio(1);
#pragma unroll
    for (int kb = 0; kb < 4; ++kb) {
      int lo = kb * 32 + hi * 16;
      short8 vf0 = *(const short8*)&V0[lq * 64 + ((lo ^ swz0) >> 1)];
      short8 vf1 = *(const short8*)&V0[(32 + lq) * 64 + ((lo ^ swz1) >> 1)];
      o0 = __builtin_amdgcn_mfma_f32_32x32x16_bf16(vf0, pbf[kb], o0, 0, 0, 0);
      o1 = __builtin_amdgcn_mfma_f32_32x32x16_bf16(vf1, pbf[kb], o1, 0, 0, 0);
      lacc = __builtin_amdgcn_mfma_f32_32x32x16_bf16(ones, pbf[kb], lacc, 0, 0, 0);
    }
    __builtin_amdgcn_s_setprio(0);
  };

  const int nkt = Lk / 64;  // even for both Lk=2048 (32) and Lk=512 (8)

  // prologue: K(0)->buf0, V(0)->Vbuf0, K(1)->buf1, then S(0)
  stageK(0, 0);
  loadV(0);
  writeV(0);
  stageK(1, 1);
  __syncthreads();

  f32x16 sA0, sA1, sB0, sB1;
  qk(0, sA0, sA1);

  // pipelined step: QK(t+1)->snew (MFMA) overlaps finish(sold) (VALU); PV(t)
  auto pstep = [&](int t, f32x16& n0, f32x16& n1, f32x16& p0, f32x16& p1) {
    const int tq = t + 1;
    if (tq < nkt) {
      loadV(tq);
      if (tq + 1 < nkt) stageK(tq + 1, (tq + 1) % 3);
      qk(tq % 3, n0, n1);
    }
    finish(p0, p1);
    if (tq < nkt) writeV(tq);
    pv(t);
    __syncthreads();
  };

  for (int t = 0; t < nkt; t += 2) {
    pstep(t, sB0, sB1, sA0, sA1);
    pstep(t + 1, sA0, sA1, sB0, sB1);
  }

  // ---- epilogue: normalize, bounce through LDS, coalesced store ----
  float rl = 1.0f / lacc[0];
  unsigned short* os = &lds[wave * 2048];
#pragma unroll
  for (int t = 0; t < 2; ++t) {
#pragma unroll
    for (int c = 0; c < 4; ++c) {
      int dbase = 32 * t + 8 * c + 4 * hi;
      float v0 = (t ? o1[4 * c + 0] : o0[4 * c + 0]) * rl;
      float v1 = (t ? o1[4 * c + 1] : o0[4 * c + 1]) * rl;
      float v2 = (t ? o1[4 * c + 2] : o0[4 * c + 2]) * rl;
      float v3 = (t ? o1[4 * c + 3] : o0[4 * c + 3]) * rl;
      int by0 = lq * 128 + ((dbase * 2) ^ ((lq & 7) << 4));
      int by1 = lq * 128 + (((dbase + 2) * 2) ^ ((lq & 7) << 4));
      *(unsigned int*)((char*)os + by0) = pk2(v0, v1);
      *(unsigned int*)((char*)os + by1) = pk2(v2, v3);
    }
  }
  int q2 = lane >> 1;
  unsigned short* orow =
      O + ((size_t)b * Lq + qt * 128 + wave * 32 + q2) * D + h * 64;
#pragma unroll
  for (int j = 0; j < 4; ++j) {
    int j2 = (lane & 1) * 4 + j;
    int byr = q2 * 128 + ((j2 * 16) ^ ((q2 & 7) << 4));
    short8 vv = *(const short8*)((char*)os + byr);
    *(short8*)(orow + j2 * 8) = vv;
  }
}

// ---------------------------------------------------------------------------
// Host orchestration
// ---------------------------------------------------------------------------
extern "C" void kernel_launch(void* const* d_in, const int* in_sizes, int n_in,
                              void* d_out, int out_size, void* d_ws, size_t ws_size,
                              hipStream_t stream) {
  (void)in_sizes; (void)n_in; (void)out_size; (void)ws_size;
  const float* x_in = (const float*)d_in[0];
  const float* te   = (const float*)d_in[1];
  const float* ctx  = (const float*)d_in[2];
  const float* rope = (const float*)d_in[3];
  const float* wmod = (const float*)d_in[4];
  const float* bmod = (const float*)d_in[5];
  const float* wqs  = (const float*)d_in[6];
  const float* wks  = (const float*)d_in[7];
  const float* wvs  = (const float*)d_in[8];
  const float* wos  = (const float*)d_in[9];
  const float* bos  = (const float*)d_in[10];
  const float* wqc  = (const float*)d_in[11];
  const float* wkc  = (const float*)d_in[12];
  const float* wvc  = (const float*)d_in[13];
  const float* woc  = (const float*)d_in[14];
  const float* boc  = (const float*)d_in[15];
  const float* w1   = (const float*)d_in[16];
  const float* b1   = (const float*)d_in[17];
  const float* w2   = (const float*)d_in[18];
  const float* b2   = (const float*)d_in[19];
  float* out = (float*)d_out;

  char* w = (char*)d_ws;
  size_t o = 0;
  auto alloc = [&](size_t bytes) {
    char* p = w + o;
    o = (o + bytes + 255) & ~(size_t)255;
    return p;
  };
  unsigned short* wmodT = (unsigned short*)alloc(6144ull * 1024 * 2);
  // wqsT/wksT/wvsT adjacent (fused QKV); wkcT/wvcT adjacent (fused cross-KV).
  unsigned short* wqsT  = (unsigned short*)alloc(1024ull * 1024 * 2);
  unsigned short* wksT  = (unsigned short*)alloc(1024ull * 1024 * 2);
  unsigned short* wvsT  = (unsigned short*)alloc(1024ull * 1024 * 2);
  unsigned short* wosT  = (unsigned short*)alloc(1024ull * 1024 * 2);
  unsigned short* wqcT  = (unsigned short*)alloc(1024ull * 1024 * 2);
  unsigned short* wkcT  = (unsigned short*)alloc(1024ull * 1024 * 2);
  unsigned short* wvcT  = (unsigned short*)alloc(1024ull * 1024 * 2);
  unsigned short* wocT  = (unsigned short*)alloc(1024ull * 1024 * 2);
  unsigned short* w1T   = (unsigned short*)alloc(4096ull * 1024 * 2);
  unsigned short* w2T   = (unsigned short*)alloc(1024ull * 4096 * 2);
  float* modsb = (float*)alloc(2ull * 6144 * 4);
  float2* csT  = (float2*)alloc(2048ull * 64 * 8);
  unsigned short* nx   = (unsigned short*)alloc(4096ull * 1024 * 2);
  unsigned short* ctxb = (unsigned short*)alloc(1024ull * 1024 * 2);
  // qb/kb/vb adjacent: EPI3/EPI4 buffer stride = 4096*1024 elems.
  unsigned short* qb = (unsigned short*)alloc(4096ull * 1024 * 2);
  unsigned short* kb = (unsigned short*)alloc(4096ull * 1024 * 2);
  unsigned short* vb = (unsigned short*)alloc(4096ull * 1024 * 2);
  unsigned short* ao = (unsigned short*)alloc(4096ull * 1024 * 2);
  float* xw = (float*)alloc(4096ull * 1024 * 4);
  unsigned short* hbuf = qb;  // reuse qb..ao contiguous 32MB for MLP hidden

  const float c1 = 0.125f * 1.4426950408889634f;  // scale * log2(e), folded into wqs/wkc

  PrepArgs pa;
  pa.wmod = wmod; pa.wmodT = wmodT;
  pa.sq[0] = {wqs, wqsT, c1};
  pa.sq[1] = {wks, wksT, 1.0f};
  pa.sq[2] = {wvs, wvsT, 1.0f};
  pa.sq[3] = {wos, wosT, 1.0f};
  pa.sq[4] = {wqc, wqcT, 1.0f};
  pa.sq[5] = {wkc, wkcT, c1};
  pa.sq[6] = {wvc, wvcT, 1.0f};
  pa.sq[7] = {woc, wocT, 1.0f};
  pa.w1 = w1; pa.w1T = w1T;
  pa.w2 = w2; pa.w2T = w2T;
  pa.ctx = ctx; pa.ctxb = ctxb;
  pa.rope = rope; pa.cs = csT;
  prep<<<27136, 256, 0, stream>>>(pa);
  mods_kernel<<<3072, 256, 0, stream>>>(te, wmodT, bmod, modsb);

  // --- self-attention (RoPE fused into QKV epilogue) ---
  ln_mod<<<4096, 256, 0, stream>>>(x_in, modsb, nx, 1024, 0);
  gemm_pipe<4><<<768, 256, 0, stream>>>(nx, wqsT, qb, (const float*)csT, nullptr, -1, nullptr, 4096, 3072, 1024, 2048, 2);
  flash2<<<512, 256, 0, stream>>>(qb, kb, vb, ao, 2048);
  gemm_p2<2><<<512, 256, 0, stream>>>(ao, wosT, xw, bos, modsb, 2048, x_in, 4096, 1024, 1024, 2048, 8);

  // --- cross-attention (Q-proj + KV-proj fused in one launch) ---
  ln_mod<<<4096, 256, 0, stream>>>(xw, modsb, nx, -1, -1);
  gemm_cross<<<768, 256, 0, stream>>>(nx, wqcT, qb, ctxb, wkcT, kb);
  flash2<<<512, 256, 0, stream>>>(qb, kb, vb, ao, 512);
  gemm_p2<2><<<512, 256, 0, stream>>>(ao, wocT, xw, boc, modsb, -1, xw, 4096, 1024, 1024, 2048, 8);

  // --- MLP ---
  ln_mod<<<4096, 256, 0, stream>>>(xw, modsb, nx, 4096, 3072);
  gemm_bt<1><<<dim3(32, 32), 256, 0, stream>>>(nx, w1T, hbuf, b1, nullptr, -1, nullptr, 4096, 4096, 1024, 2048);
  gemm_p2<2><<<512, 256, 0, stream>>>(hbuf, w2T, out, b2, modsb, 5120, xw, 4096, 1024, 4096, 2048, 8);
}